// Round 1
// baseline (1018.522 us; speedup 1.0000x reference)
//
#include <hip/hip_runtime.h>
#include <math.h>

// Problem constants (from reference setup_inputs)
#define HDIM 1024
#define NHEAD 16
#define HD 64
#define LM 64          // NUM_LANDMARKS
#define MS 512         // memory slots
#define KSEL 32        // top_k
#define NB 2
#define NS 4096
#define NTOK (NB*NS)   // 8192

// ---------------------------------------------------------------------------
// K1: per-token importance (sum of squares; monotone in L2 norm) + gate scalar
// ---------------------------------------------------------------------------
__global__ __launch_bounds__(256) void imp_gate_kernel(
    const float* __restrict__ hs, const float* __restrict__ gw,
    const float* __restrict__ gb, float* __restrict__ imp,
    float* __restrict__ gate) {
  const int row = blockIdx.x;
  const int tid = threadIdx.x;
  const float4 hv = *(const float4*)(hs + (size_t)row*HDIM + tid*4);
  const float4 gv = *(const float4*)(gw + tid*4);
  float ss = hv.x*hv.x + hv.y*hv.y + hv.z*hv.z + hv.w*hv.w;
  float dg = hv.x*gv.x + hv.y*gv.y + hv.z*gv.z + hv.w*gv.w;
  __shared__ float sss[256], sdg[256];
  sss[tid] = ss; sdg[tid] = dg;
  __syncthreads();
  for (int s = 128; s > 0; s >>= 1) {
    if (tid < s) { sss[tid] += sss[tid+s]; sdg[tid] += sdg[tid+s]; }
    __syncthreads();
  }
  if (tid == 0) {
    imp[row] = sss[0];
    gate[row] = 1.f/(1.f + expf(-(sdg[0] + gb[0])));
  }
}

// ---------------------------------------------------------------------------
// K2: per-batch top-64 landmark indices (iterative argmax, tie -> lower idx),
//     then sorted ascending (matches sort(top_k_indices))
// ---------------------------------------------------------------------------
__global__ __launch_bounds__(256) void lm_topk_kernel(
    const float* __restrict__ imp, int* __restrict__ lm_idx) {
  const int b = blockIdx.x;
  const int tid = threadIdx.x;
  __shared__ float v[NS];
  __shared__ float rv[256];
  __shared__ int   ri[256];
  __shared__ int   sel[LM];
  for (int i = tid; i < NS; i += 256) v[i] = imp[b*NS + i];
  __syncthreads();
  for (int it = 0; it < LM; ++it) {
    float bv = -1e30f; int bi = 0x7fffffff;
    for (int j = 0; j < NS/256; ++j) {
      const int i = tid + j*256;
      const float x = v[i];
      if (x > bv) { bv = x; bi = i; }   // ascending scan keeps lowest idx on tie
    }
    rv[tid] = bv; ri[tid] = bi;
    __syncthreads();
    for (int s = 128; s > 0; s >>= 1) {
      if (tid < s) {
        const float ov = rv[tid+s]; const int oi = ri[tid+s];
        if (ov > rv[tid] || (ov == rv[tid] && oi < ri[tid])) { rv[tid] = ov; ri[tid] = oi; }
      }
      __syncthreads();
    }
    if (tid == 0) { sel[it] = ri[0]; v[ri[0]] = -1e30f; }
    __syncthreads();
  }
  if (tid == 0) {
    for (int i = 1; i < LM; ++i) {        // insertion sort ascending
      const int key = sel[i]; int j = i - 1;
      while (j >= 0 && sel[j] > key) { sel[j+1] = sel[j]; --j; }
      sel[j+1] = key;
    }
    for (int i = 0; i < LM; ++i) lm_idx[b*LM + i] = sel[i];
  }
}

// ---------------------------------------------------------------------------
// K3: gather landmark rows + K/V projection.
// grid (4 col-quarters, 8 landmark-groups, B); 8 rows staged in LDS per block.
// ---------------------------------------------------------------------------
__global__ __launch_bounds__(256) void kv_proj_kernel(
    const float* __restrict__ hs, const int* __restrict__ lm_idx,
    const float* __restrict__ Wk, const float* __restrict__ bk,
    const float* __restrict__ Wv, const float* __restrict__ bv,
    float* __restrict__ kbuf, float* __restrict__ vbuf) {
  const int cq = blockIdx.x, lg = blockIdx.y, b = blockIdx.z;
  const int tid = threadIdx.x;
  __shared__ float rows[8][HDIM];   // 32 KiB
  __shared__ int sidx[8];
  if (tid < 8) sidx[tid] = lm_idx[b*LM + lg*8 + tid];
  __syncthreads();
  for (int e = tid; e < 8*HDIM; e += 256) {
    const int r = e >> 10, d = e & 1023;
    rows[r][d] = hs[((size_t)b*NS + sidx[r])*HDIM + d];
  }
  __syncthreads();
  const int col = cq*256 + tid;
  float ak[8] = {0,0,0,0,0,0,0,0};
  float av[8] = {0,0,0,0,0,0,0,0};
  for (int k = 0; k < HDIM; ++k) {
    const float wk = Wk[(size_t)k*HDIM + col];
    const float wv = Wv[(size_t)k*HDIM + col];
#pragma unroll
    for (int r = 0; r < 8; ++r) {
      const float h = rows[r][k];
      ak[r] += h*wk;
      av[r] += h*wv;
    }
  }
  const float bkc = bk[col], bvc = bv[col];
#pragma unroll
  for (int r = 0; r < 8; ++r) {
    const size_t o = ((size_t)(b*LM + lg*8 + r))*HDIM + col;
    kbuf[o] = ak[r] + bkc;
    vbuf[o] = av[r] + bvc;
  }
}

// ---------------------------------------------------------------------------
// K4/K6/K7: tiled fp32 GEMM  C[M,N] = alpha*(A@B) (+ bias)
// B layout: TRANSB ? [N,K] : [K,N].  BM=BN=64, BK=16, 256 thr, 4x4/thread.
// ---------------------------------------------------------------------------
template<bool TRANSB, bool HASBIAS>
__global__ __launch_bounds__(256) void gemm_kernel(
    const float* __restrict__ A, const float* __restrict__ B,
    const float* __restrict__ bias, float* __restrict__ C,
    int M, int N, int K, float alpha) {
  __shared__ float As[16][68];
  __shared__ float Bs[16][68];
  const int tid = threadIdx.x;
  const int tx = tid & 15, ty = tid >> 4;
  const int row0 = blockIdx.y << 6, col0 = blockIdx.x << 6;
  float acc[4][4] = {{0.f}};
  const int ar = tid >> 2, ak = (tid & 3) << 2;
  for (int k0 = 0; k0 < K; k0 += 16) {
    const float4 a4 = *(const float4*)(A + (size_t)(row0 + ar)*K + k0 + ak);
    As[ak+0][ar] = a4.x; As[ak+1][ar] = a4.y; As[ak+2][ar] = a4.z; As[ak+3][ar] = a4.w;
    if (!TRANSB) {
      const int bn = (tid & 15) << 2, bk = tid >> 4;
      const float4 b4 = *(const float4*)(B + (size_t)(k0 + bk)*N + col0 + bn);
      *(float4*)&Bs[bk][bn] = b4;
    } else {
      const int bk = (tid & 3) << 2, bn = tid >> 2;
      const float4 b4 = *(const float4*)(B + (size_t)(col0 + bn)*K + k0 + bk);
      Bs[bk+0][bn] = b4.x; Bs[bk+1][bn] = b4.y; Bs[bk+2][bn] = b4.z; Bs[bk+3][bn] = b4.w;
    }
    __syncthreads();
#pragma unroll
    for (int kk = 0; kk < 16; ++kk) {
      const float4 avv = *(const float4*)&As[kk][ty << 2];
      const float4 bvv = *(const float4*)&Bs[kk][tx << 2];
      const float a_[4] = {avv.x, avv.y, avv.z, avv.w};
      const float b_[4] = {bvv.x, bvv.y, bvv.z, bvv.w};
#pragma unroll
      for (int i = 0; i < 4; ++i)
#pragma unroll
        for (int j = 0; j < 4; ++j)
          acc[i][j] += a_[i]*b_[j];
    }
    __syncthreads();
  }
#pragma unroll
  for (int i = 0; i < 4; ++i) {
    float4 o;
    o.x = acc[i][0]*alpha; o.y = acc[i][1]*alpha;
    o.z = acc[i][2]*alpha; o.w = acc[i][3]*alpha;
    if (HASBIAS) {
      const float* bp = bias + col0 + (tx << 2);
      o.x += bp[0]; o.y += bp[1]; o.z += bp[2]; o.w += bp[3];
    }
    *(float4*)(C + (size_t)(row0 + (ty << 2) + i)*N + col0 + (tx << 2)) = o;
  }
}

// ---------------------------------------------------------------------------
// K5: landmark attention. grid (S/256, NHEAD, B); one token-head per thread.
// K,V head slices (64x64 each) staged in LDS; broadcast reads.
// ---------------------------------------------------------------------------
__global__ __launch_bounds__(256) void attn_kernel(
    const float* __restrict__ qbuf, const float* __restrict__ kbuf,
    const float* __restrict__ vbuf, float* __restrict__ ctx) {
  const int tid = threadIdx.x;
  const int s = blockIdx.x*256 + tid;
  const int h = blockIdx.y, b = blockIdx.z;
  __shared__ float4 K4[LM*16];
  __shared__ float4 V4[LM*16];
  for (int e = tid; e < LM*16; e += 256) {
    const int l = e >> 4, d4 = e & 15;
    const size_t base = ((size_t)(b*LM + l)*NHEAD + h)*HD + (d4 << 2);
    K4[e] = *(const float4*)(kbuf + base);
    V4[e] = *(const float4*)(vbuf + base);
  }
  __syncthreads();

  const float* qp = qbuf + ((size_t)(b*NS + s)*NHEAD + h)*HD;
  float4 q[16];
#pragma unroll
  for (int i = 0; i < 16; ++i) q[i] = ((const float4*)qp)[i];

  float sc[LM];
#pragma unroll
  for (int l = 0; l < LM; ++l) {
    float a = 0.f;
#pragma unroll
    for (int i = 0; i < 16; ++i) {
      const float4 kv = K4[l*16 + i];
      a += q[i].x*kv.x + q[i].y*kv.y + q[i].z*kv.z + q[i].w*kv.w;
    }
    sc[l] = a * 0.125f;   // 1/sqrt(64)
  }
  float mx = sc[0];
#pragma unroll
  for (int l = 1; l < LM; ++l) mx = fmaxf(mx, sc[l]);
  float sum = 0.f;
#pragma unroll
  for (int l = 0; l < LM; ++l) { sc[l] = expf(sc[l] - mx); sum += sc[l]; }
  const float inv = 1.f/sum;

  float4 o[16];
#pragma unroll
  for (int i = 0; i < 16; ++i) o[i] = make_float4(0.f,0.f,0.f,0.f);
#pragma unroll
  for (int l = 0; l < LM; ++l) {
    const float a = sc[l]*inv;
#pragma unroll
    for (int i = 0; i < 16; ++i) {
      const float4 vv = V4[l*16 + i];
      o[i].x += a*vv.x; o[i].y += a*vv.y; o[i].z += a*vv.z; o[i].w += a*vv.w;
    }
  }
  float* cp = ctx + ((size_t)(b*NS + s)*NHEAD + h)*HD;
#pragma unroll
  for (int i = 0; i < 16; ++i) ((float4*)cp)[i] = o[i];
}

// ---------------------------------------------------------------------------
// K8: per-token top-32 over 512 memory scores + softmax + weighted gather;
//     out += gate * mem_out.  One block/token; wave 0 does selection.
// ---------------------------------------------------------------------------
__global__ __launch_bounds__(256) void mem_kernel(
    const float* __restrict__ msc, const float* __restrict__ mvals,
    const float* __restrict__ gate, float* __restrict__ out) {
  const int token = blockIdx.x;
  const int tid = threadIdx.x;
  __shared__ int   s_idx[KSEL];
  __shared__ float s_val[KSEL];
  __shared__ float s_w[KSEL];

  if (tid < 64) {
    const int lane = tid;
    float v[8];
#pragma unroll
    for (int j = 0; j < 8; ++j) v[j] = msc[(size_t)token*MS + j*64 + lane];
    for (int it = 0; it < KSEL; ++it) {
      float bvv = -1e30f; int bi = 0x7fffffff;
#pragma unroll
      for (int j = 0; j < 8; ++j) {
        if (v[j] > bvv) { bvv = v[j]; bi = j*64 + lane; }  // ascending idx scan
      }
#pragma unroll
      for (int off = 32; off > 0; off >>= 1) {
        const float ov = __shfl_xor(bvv, off);
        const int   oi = __shfl_xor(bi, off);
        if (ov > bvv || (ov == bvv && oi < bi)) { bvv = ov; bi = oi; }
      }
      if (lane == 0) { s_idx[it] = bi; s_val[it] = bvv; }
#pragma unroll
      for (int j = 0; j < 8; ++j) {
        if (j*64 + lane == bi) v[j] = -1e30f;
      }
    }
    // softmax over the 32 selected (s_val[0] is the global max)
    float e = 0.f;
    if (lane < KSEL) e = expf(s_val[lane] - s_val[0]);
    float tot = e;
#pragma unroll
    for (int off = 32; off > 0; off >>= 1) tot += __shfl_xor(tot, off);
    if (lane < KSEL) s_w[lane] = e / tot;
  }
  __syncthreads();

  const int d4 = tid << 2;
  float4 acc = make_float4(0.f,0.f,0.f,0.f);
  for (int it = 0; it < KSEL; ++it) {
    const int m = s_idx[it];
    const float w = s_w[it];
    const float4 mv = *(const float4*)(mvals + (size_t)m*HDIM + d4);
    acc.x += w*mv.x; acc.y += w*mv.y; acc.z += w*mv.z; acc.w += w*mv.w;
  }
  const float g = gate[token];
  float4 cur = *(float4*)(out + (size_t)token*HDIM + d4);
  cur.x += g*acc.x; cur.y += g*acc.y; cur.z += g*acc.z; cur.w += g*acc.w;
  *(float4*)(out + (size_t)token*HDIM + d4) = cur;
}

// ---------------------------------------------------------------------------
extern "C" void kernel_launch(void* const* d_in, const int* in_sizes, int n_in,
                              void* d_out, int out_size, void* d_ws, size_t ws_size,
                              hipStream_t stream) {
  const float* hs = (const float*)d_in[0];
  const float* Wq = (const float*)d_in[1];
  const float* bq = (const float*)d_in[2];
  const float* Wk = (const float*)d_in[3];
  const float* bk = (const float*)d_in[4];
  const float* Wv = (const float*)d_in[5];
  const float* bv = (const float*)d_in[6];
  const float* Wo = (const float*)d_in[7];
  const float* bo = (const float*)d_in[8];
  const float* mk = (const float*)d_in[9];
  const float* mv = (const float*)d_in[10];
  const float* gw = (const float*)d_in[11];
  const float* gb = (const float*)d_in[12];
  float* out = (float*)d_out;

  char* ws = (char*)d_ws;
  float* q    = (float*)ws;                           // 32 MiB [NTOK, HDIM]
  float* ctx  = (float*)(ws + ((size_t)32 << 20));    // 32 MiB [NTOK, HDIM]
  char*  ex   = ws + ((size_t)64 << 20);
  float* kbuf = (float*)ex;                           // 512 KiB [NB*LM, HDIM]
  float* vbuf = (float*)(ex + ((size_t)512 << 10));   // 512 KiB
  float* imp  = (float*)(ex + ((size_t)1024 << 10));  // 32 KiB [NTOK]
  float* gate = (float*)(ex + ((size_t)1056 << 10));  // 32 KiB [NTOK]
  int*   lmi  = (int*)  (ex + ((size_t)1088 << 10));  // 512 B  [NB*LM]
  float* msc  = q;  // mem scores [NTOK, MS] alias q (q dead after attn)

  imp_gate_kernel<<<dim3(NTOK), 256, 0, stream>>>(hs, gw, gb, imp, gate);
  lm_topk_kernel<<<dim3(NB), 256, 0, stream>>>(imp, lmi);
  kv_proj_kernel<<<dim3(4, 8, NB), 256, 0, stream>>>(hs, lmi, Wk, bk, Wv, bv, kbuf, vbuf);
  gemm_kernel<false, true><<<dim3(HDIM/64, NTOK/64), 256, 0, stream>>>(
      hs, Wq, bq, q, NTOK, HDIM, HDIM, 1.f);
  attn_kernel<<<dim3(NS/256, NHEAD, NB), 256, 0, stream>>>(q, kbuf, vbuf, ctx);
  gemm_kernel<false, true><<<dim3(HDIM/64, NTOK/64), 256, 0, stream>>>(
      ctx, Wo, bo, out, NTOK, HDIM, HDIM, 1.f);
  gemm_kernel<true, false><<<dim3(MS/64, NTOK/64), 256, 0, stream>>>(
      hs, mk, nullptr, msc, NTOK, MS, HDIM, 0.03125f);
  mem_kernel<<<dim3(NTOK), 256, 0, stream>>>(msc, mv, gate, out);
}

// Round 2
// 537.233 us; speedup vs baseline: 1.8959x; 1.8959x over previous
//
#include <hip/hip_runtime.h>
#include <math.h>

// Problem constants (from reference setup_inputs)
#define HDIM 1024
#define NHEAD 16
#define HD 64
#define LM 64          // NUM_LANDMARKS
#define MS 512         // memory slots
#define KSEL 32        // top_k
#define NB 2
#define NS 4096
#define NTOK (NB*NS)   // 8192

typedef __attribute__((ext_vector_type(8))) short short8;
typedef __attribute__((ext_vector_type(4))) float f32x4;
typedef __attribute__((ext_vector_type(4))) unsigned short us4;

__device__ __forceinline__ unsigned short f2bf(float f) {
  unsigned int u = __float_as_uint(f);
  unsigned int r = (u + 0x7fffu + ((u >> 16) & 1u)) >> 16;
  return (unsigned short)r;
}

__device__ __forceinline__ void gload_lds16(const unsigned short* g, unsigned short* l) {
  __builtin_amdgcn_global_load_lds(
      (const __attribute__((address_space(1))) unsigned int*)g,
      (__attribute__((address_space(3))) unsigned int*)l,
      16, 0, 0);
}

// ---------------------------------------------------------------------------
// K1: per-token importance (sum sq) + gate scalar + hs -> bf16 conversion
// ---------------------------------------------------------------------------
__global__ __launch_bounds__(256) void imp_gate_kernel(
    const float* __restrict__ hs, const float* __restrict__ gw,
    const float* __restrict__ gb, float* __restrict__ imp,
    float* __restrict__ gate, unsigned short* __restrict__ hsb) {
  const int row = blockIdx.x;
  const int tid = threadIdx.x;
  const float4 hv = *(const float4*)(hs + (size_t)row*HDIM + tid*4);
  const float4 gv = *(const float4*)(gw + tid*4);
  us4 hb;
  hb.x = f2bf(hv.x); hb.y = f2bf(hv.y); hb.z = f2bf(hv.z); hb.w = f2bf(hv.w);
  *(us4*)(hsb + (size_t)row*HDIM + tid*4) = hb;
  float ss = hv.x*hv.x + hv.y*hv.y + hv.z*hv.z + hv.w*hv.w;
  float dg = hv.x*gv.x + hv.y*gv.y + hv.z*gv.z + hv.w*gv.w;
  __shared__ float sss[256], sdg[256];
  sss[tid] = ss; sdg[tid] = dg;
  __syncthreads();
  for (int s = 128; s > 0; s >>= 1) {
    if (tid < s) { sss[tid] += sss[tid+s]; sdg[tid] += sdg[tid+s]; }
    __syncthreads();
  }
  if (tid == 0) {
    imp[row] = sss[0];
    gate[row] = 1.f/(1.f + expf(-(sdg[0] + gb[0])));
  }
}

// ---------------------------------------------------------------------------
// K2: per-batch top-64 landmark indices (register-resident iterative argmax,
//     tie -> lower idx), then sorted ascending
// ---------------------------------------------------------------------------
__global__ __launch_bounds__(256) void lm_topk_kernel(
    const float* __restrict__ imp, int* __restrict__ lm_idx) {
  const int b = blockIdx.x;
  const int tid = threadIdx.x;
  const int lane = tid & 63, wave = tid >> 6;
  const int base = tid * 16;
  float v[16];
#pragma unroll
  for (int j = 0; j < 16; ++j) v[j] = imp[b*NS + base + j];
  __shared__ float wv_s[4];
  __shared__ int   wi_s[4];
  __shared__ int   best_s;
  __shared__ int   sel[LM];
  for (int it = 0; it < LM; ++it) {
    float bv = -1e30f; int bi = 0x7fffffff;
#pragma unroll
    for (int j = 0; j < 16; ++j)
      if (v[j] > bv) { bv = v[j]; bi = base + j; }   // ascending keeps low idx
#pragma unroll
    for (int off = 32; off > 0; off >>= 1) {
      const float ov = __shfl_xor(bv, off);
      const int   oi = __shfl_xor(bi, off);
      if (ov > bv || (ov == bv && oi < bi)) { bv = ov; bi = oi; }
    }
    if (lane == 0) { wv_s[wave] = bv; wi_s[wave] = bi; }
    __syncthreads();
    if (tid == 0) {
      float fv = wv_s[0]; int fi = wi_s[0];
      for (int w = 1; w < 4; ++w)
        if (wv_s[w] > fv || (wv_s[w] == fv && wi_s[w] < fi)) { fv = wv_s[w]; fi = wi_s[w]; }
      sel[it] = fi; best_s = fi;
    }
    __syncthreads();
    const int wi = best_s;
    if (wi >= base && wi < base + 16) v[wi - base] = -1e30f;
  }
  if (tid == 0) {
    for (int i = 1; i < LM; ++i) {
      const int key = sel[i]; int j = i - 1;
      while (j >= 0 && sel[j] > key) { sel[j+1] = sel[j]; --j; }
      sel[j+1] = key;
    }
    for (int i = 0; i < LM; ++i) lm_idx[b*LM + i] = sel[i];
  }
}

// ---------------------------------------------------------------------------
// K3: gather landmark rows + K/V projection (fp32, tiny: 128 rows)
// ---------------------------------------------------------------------------
__global__ __launch_bounds__(256) void kv_proj_kernel(
    const float* __restrict__ hs, const int* __restrict__ lm_idx,
    const float* __restrict__ Wk, const float* __restrict__ bk,
    const float* __restrict__ Wv, const float* __restrict__ bv,
    float* __restrict__ kbuf, float* __restrict__ vbuf) {
  const int cq = blockIdx.x, lg = blockIdx.y, b = blockIdx.z;
  const int tid = threadIdx.x;
  __shared__ float rows[8][HDIM];   // 32 KiB
  __shared__ int sidx[8];
  if (tid < 8) sidx[tid] = lm_idx[b*LM + lg*8 + tid];
  __syncthreads();
  for (int e = tid; e < 8*HDIM; e += 256) {
    const int r = e >> 10, d = e & 1023;
    rows[r][d] = hs[((size_t)b*NS + sidx[r])*HDIM + d];
  }
  __syncthreads();
  const int col = cq*256 + tid;
  float ak[8] = {0,0,0,0,0,0,0,0};
  float av[8] = {0,0,0,0,0,0,0,0};
  for (int k = 0; k < HDIM; ++k) {
    const float wk = Wk[(size_t)k*HDIM + col];
    const float wv = Wv[(size_t)k*HDIM + col];
#pragma unroll
    for (int r = 0; r < 8; ++r) {
      const float h = rows[r][k];
      ak[r] += h*wk;
      av[r] += h*wv;
    }
  }
  const float bkc = bk[col], bvc = bv[col];
#pragma unroll
  for (int r = 0; r < 8; ++r) {
    const size_t o = ((size_t)(b*LM + lg*8 + r))*HDIM + col;
    kbuf[o] = ak[r] + bkc;
    vbuf[o] = av[r] + bvc;
  }
}

// ---------------------------------------------------------------------------
// Prep: transpose+convert weight W[K][N] fp32 -> Wt[N][K] bf16  (1024x1024)
// ---------------------------------------------------------------------------
__global__ __launch_bounds__(256) void wtrans_kernel(
    const float* __restrict__ W, unsigned short* __restrict__ Wt) {
  __shared__ float tile[32][33];
  const int tx = threadIdx.x & 31, ty = threadIdx.x >> 5;
  const int bx = blockIdx.x * 32, by = blockIdx.y * 32;
#pragma unroll
  for (int i = 0; i < 32; i += 8)
    tile[ty + i][tx] = W[(size_t)(by + ty + i)*HDIM + bx + tx];
  __syncthreads();
#pragma unroll
  for (int i = 0; i < 32; i += 8)
    Wt[(size_t)(bx + ty + i)*HDIM + by + tx] = f2bf(tile[tx][ty + i]);
}

// ---------------------------------------------------------------------------
// Prep: elementwise fp32 -> bf16 (mem_keys, already [N][K] layout)
// ---------------------------------------------------------------------------
__global__ __launch_bounds__(256) void conv_bf16_kernel(
    const float* __restrict__ in, unsigned short* __restrict__ out) {
  const int i = (blockIdx.x*256 + threadIdx.x)*4;
  const float4 v = *(const float4*)&in[i];
  us4 w;
  w.x = f2bf(v.x); w.y = f2bf(v.y); w.z = f2bf(v.z); w.w = f2bf(v.w);
  *(us4*)&out[i] = w;
}

// ---------------------------------------------------------------------------
// bf16 MFMA GEMM (m97 structure): C[M,N] = alpha*(A @ Bt^T) (+ bias)
// A [M,K] bf16 row-major, Bt [N,K] bf16 row-major, C fp32.
// 128x128 tile, BK=32, 4 waves -> 64x64/wave via 4x4 of 16x16x32 MFMA.
// ---------------------------------------------------------------------------
template<bool HASBIAS>
__global__ __launch_bounds__(256) void gemm_bf16_kernel(
    const unsigned short* __restrict__ A, const unsigned short* __restrict__ Bt,
    const float* __restrict__ bias, float* __restrict__ C,
    int M, int N, int K, float alpha) {
  __shared__ __align__(16) unsigned short As[128*32];
  __shared__ __align__(16) unsigned short Bs[128*32];
  const int tid = threadIdx.x;
  const int lane = tid & 63, wave = tid >> 6;
  const int wr = wave >> 1, wc = wave & 1;
  const int row0 = blockIdx.y << 7, col0 = blockIdx.x << 7;

  f32x4 acc[4][4];
#pragma unroll
  for (int m = 0; m < 4; ++m)
#pragma unroll
    for (int n = 0; n < 4; ++n)
      acc[m][n] = (f32x4)(0.f);

  const int srow = tid >> 2;            // 0..63
  const int sk   = (tid & 3) << 3;      // 0,8,16,24
  const unsigned short* gA = A  + (size_t)(row0 + srow)*K + sk;
  const unsigned short* gB = Bt + (size_t)(col0 + srow)*K + sk;
  const int fr = lane & 15;
  const int fk = (lane >> 4) << 3;      // 0,8,16,24
  const int fg = lane >> 4;

  for (int k0 = 0; k0 < K; k0 += 32) {
    gload_lds16(gA + k0,          As + tid*8);
    gload_lds16(gA + 64*K + k0,   As + 2048 + tid*8);
    gload_lds16(gB + k0,          Bs + tid*8);
    gload_lds16(gB + 64*K + k0,   Bs + 2048 + tid*8);
    __syncthreads();
    short8 af[4], bf[4];
#pragma unroll
    for (int m = 0; m < 4; ++m)
      af[m] = *(const short8*)&As[(wr*64 + m*16 + fr)*32 + fk];
#pragma unroll
    for (int n = 0; n < 4; ++n)
      bf[n] = *(const short8*)&Bs[(wc*64 + n*16 + fr)*32 + fk];
#pragma unroll
    for (int m = 0; m < 4; ++m)
#pragma unroll
      for (int n = 0; n < 4; ++n)
        acc[m][n] = __builtin_amdgcn_mfma_f32_16x16x32_bf16(af[m], bf[n], acc[m][n], 0, 0, 0);
    __syncthreads();
  }

#pragma unroll
  for (int m = 0; m < 4; ++m) {
#pragma unroll
    for (int n = 0; n < 4; ++n) {
      const int col = col0 + wc*64 + n*16 + fr;
      const float bb = HASBIAS ? bias[col] : 0.f;
#pragma unroll
      for (int r = 0; r < 4; ++r) {
        const int row = row0 + wr*64 + m*16 + fg*4 + r;
        C[(size_t)row*N + col] = acc[m][n][r]*alpha + bb;
      }
    }
  }
}

// ---------------------------------------------------------------------------
// K5: landmark attention (fp32 math), writes ctx as bf16.
// ---------------------------------------------------------------------------
__global__ __launch_bounds__(256) void attn_kernel(
    const float* __restrict__ qbuf, const float* __restrict__ kbuf,
    const float* __restrict__ vbuf, unsigned short* __restrict__ ctxb) {
  const int tid = threadIdx.x;
  const int s = blockIdx.x*256 + tid;
  const int h = blockIdx.y, b = blockIdx.z;
  __shared__ float4 K4[LM*16];
  __shared__ float4 V4[LM*16];
  for (int e = tid; e < LM*16; e += 256) {
    const int l = e >> 4, d4 = e & 15;
    const size_t base = ((size_t)(b*LM + l)*NHEAD + h)*HD + (d4 << 2);
    K4[e] = *(const float4*)(kbuf + base);
    V4[e] = *(const float4*)(vbuf + base);
  }
  __syncthreads();

  const float* qp = qbuf + ((size_t)(b*NS + s)*NHEAD + h)*HD;
  float4 q[16];
#pragma unroll
  for (int i = 0; i < 16; ++i) q[i] = ((const float4*)qp)[i];

  float sc[LM];
#pragma unroll
  for (int l = 0; l < LM; ++l) {
    float a = 0.f;
#pragma unroll
    for (int i = 0; i < 16; ++i) {
      const float4 kv = K4[l*16 + i];
      a += q[i].x*kv.x + q[i].y*kv.y + q[i].z*kv.z + q[i].w*kv.w;
    }
    sc[l] = a * 0.125f;
  }
  float mx = sc[0];
#pragma unroll
  for (int l = 1; l < LM; ++l) mx = fmaxf(mx, sc[l]);
  float sum = 0.f;
#pragma unroll
  for (int l = 0; l < LM; ++l) { sc[l] = expf(sc[l] - mx); sum += sc[l]; }
  const float inv = 1.f/sum;

  float4 o[16];
#pragma unroll
  for (int i = 0; i < 16; ++i) o[i] = make_float4(0.f,0.f,0.f,0.f);
#pragma unroll
  for (int l = 0; l < LM; ++l) {
    const float a = sc[l]*inv;
#pragma unroll
    for (int i = 0; i < 16; ++i) {
      const float4 vv = V4[l*16 + i];
      o[i].x += a*vv.x; o[i].y += a*vv.y; o[i].z += a*vv.z; o[i].w += a*vv.w;
    }
  }
  unsigned short* cp = ctxb + ((size_t)(b*NS + s)*NHEAD + h)*HD;
#pragma unroll
  for (int i = 0; i < 16; ++i) {
    us4 w;
    w.x = f2bf(o[i].x); w.y = f2bf(o[i].y); w.z = f2bf(o[i].z); w.w = f2bf(o[i].w);
    *(us4*)(cp + i*4) = w;
  }
}

// ---------------------------------------------------------------------------
// K8: per-token top-32 + softmax + weighted gather; out += gate * mem_out
// ---------------------------------------------------------------------------
__global__ __launch_bounds__(256) void mem_kernel(
    const float* __restrict__ msc, const float* __restrict__ mvals,
    const float* __restrict__ gate, float* __restrict__ out) {
  const int token = blockIdx.x;
  const int tid = threadIdx.x;
  __shared__ int   s_idx[KSEL];
  __shared__ float s_val[KSEL];
  __shared__ float s_w[KSEL];

  if (tid < 64) {
    const int lane = tid;
    float v[8];
#pragma unroll
    for (int j = 0; j < 8; ++j) v[j] = msc[(size_t)token*MS + j*64 + lane];
    for (int it = 0; it < KSEL; ++it) {
      float bvv = -1e30f; int bi = 0x7fffffff;
#pragma unroll
      for (int j = 0; j < 8; ++j) {
        if (v[j] > bvv) { bvv = v[j]; bi = j*64 + lane; }
      }
#pragma unroll
      for (int off = 32; off > 0; off >>= 1) {
        const float ov = __shfl_xor(bvv, off);
        const int   oi = __shfl_xor(bi, off);
        if (ov > bvv || (ov == bvv && oi < bi)) { bvv = ov; bi = oi; }
      }
      if (lane == 0) { s_idx[it] = bi; s_val[it] = bvv; }
#pragma unroll
      for (int j = 0; j < 8; ++j) {
        if (j*64 + lane == bi) v[j] = -1e30f;
      }
    }
    float e = 0.f;
    if (lane < KSEL) e = expf(s_val[lane] - s_val[0]);
    float tot = e;
#pragma unroll
    for (int off = 32; off > 0; off >>= 1) tot += __shfl_xor(tot, off);
    if (lane < KSEL) s_w[lane] = e / tot;
  }
  __syncthreads();

  const int d4 = tid << 2;
  float4 acc = make_float4(0.f,0.f,0.f,0.f);
  for (int it = 0; it < KSEL; ++it) {
    const int m = s_idx[it];
    const float w = s_w[it];
    const float4 mv = *(const float4*)(mvals + (size_t)m*HDIM + d4);
    acc.x += w*mv.x; acc.y += w*mv.y; acc.z += w*mv.z; acc.w += w*mv.w;
  }
  const float g = gate[token];
  float4 cur = *(float4*)(out + (size_t)token*HDIM + d4);
  cur.x += g*acc.x; cur.y += g*acc.y; cur.z += g*acc.z; cur.w += g*acc.w;
  *(float4*)(out + (size_t)token*HDIM + d4) = cur;
}

// ---------------------------------------------------------------------------
extern "C" void kernel_launch(void* const* d_in, const int* in_sizes, int n_in,
                              void* d_out, int out_size, void* d_ws, size_t ws_size,
                              hipStream_t stream) {
  const float* hs = (const float*)d_in[0];
  const float* Wq = (const float*)d_in[1];
  const float* bq = (const float*)d_in[2];
  const float* Wk = (const float*)d_in[3];
  const float* bk = (const float*)d_in[4];
  const float* Wv = (const float*)d_in[5];
  const float* bv = (const float*)d_in[6];
  const float* Wo = (const float*)d_in[7];
  const float* bo = (const float*)d_in[8];
  const float* mk = (const float*)d_in[9];
  const float* mv = (const float*)d_in[10];
  const float* gw = (const float*)d_in[11];
  const float* gb = (const float*)d_in[12];
  float* out = (float*)d_out;

  char* ws = (char*)d_ws;
  unsigned short* hsb  = (unsigned short*)(ws);                       // 16 MiB [NTOK,HDIM] bf16
  float*          q    = (float*)(ws + ((size_t)16 << 20));           // 32 MiB [NTOK,HDIM] fp32
  unsigned short* ctxb = (unsigned short*)(ws + ((size_t)48 << 20));  // 16 MiB [NTOK,HDIM] bf16
  unsigned short* Wqt  = (unsigned short*)(ws + ((size_t)64 << 20));  // 2 MiB [N,K] bf16
  unsigned short* Wot  = (unsigned short*)(ws + ((size_t)66 << 20));  // 2 MiB
  unsigned short* mkb  = (unsigned short*)(ws + ((size_t)68 << 20));  // 1 MiB [MS,HDIM] bf16
  float*          kbuf = (float*)(ws + ((size_t)69 << 20));           // 512 KiB
  float*          vbuf = (float*)(ws + ((size_t)69 << 20) + ((size_t)512 << 10));
  float*          imp  = (float*)(ws + ((size_t)70 << 20));           // 32 KiB
  float*          gate = (float*)(ws + ((size_t)70 << 20) + ((size_t)32 << 10));
  int*            lmi  = (int*)  (ws + ((size_t)70 << 20) + ((size_t)64 << 10));
  float*          msc  = q;  // mem scores [NTOK,MS] alias q (q dead after attn)

  imp_gate_kernel<<<dim3(NTOK), 256, 0, stream>>>(hs, gw, gb, imp, gate, hsb);
  lm_topk_kernel<<<dim3(NB), 256, 0, stream>>>(imp, lmi);
  kv_proj_kernel<<<dim3(4, 8, NB), 256, 0, stream>>>(hs, lmi, Wk, bk, Wv, bv, kbuf, vbuf);
  wtrans_kernel<<<dim3(32, 32), 256, 0, stream>>>(Wq, Wqt);
  wtrans_kernel<<<dim3(32, 32), 256, 0, stream>>>(Wo, Wot);
  conv_bf16_kernel<<<dim3(MS*HDIM/1024), 256, 0, stream>>>(mk, mkb);

  gemm_bf16_kernel<true><<<dim3(HDIM/128, NTOK/128), 256, 0, stream>>>(
      hsb, Wqt, bq, q, NTOK, HDIM, HDIM, 1.f);
  attn_kernel<<<dim3(NS/256, NHEAD, NB), 256, 0, stream>>>(q, kbuf, vbuf, ctxb);
  gemm_bf16_kernel<true><<<dim3(HDIM/128, NTOK/128), 256, 0, stream>>>(
      ctxb, Wot, bo, out, NTOK, HDIM, HDIM, 1.f);
  gemm_bf16_kernel<false><<<dim3(MS/128, NTOK/128), 256, 0, stream>>>(
      hsb, mkb, nullptr, msc, NTOK, MS, HDIM, 0.03125f);
  mem_kernel<<<dim3(NTOK), 256, 0, stream>>>(msc, mv, gate, out);
}

// Round 3
// 534.039 us; speedup vs baseline: 1.9072x; 1.0060x over previous
//
#include <hip/hip_runtime.h>
#include <math.h>

// Problem constants (from reference setup_inputs)
#define HDIM 1024
#define NHEAD 16
#define HD 64
#define LM 64          // NUM_LANDMARKS
#define MS 512         // memory slots
#define KSEL 32        // top_k
#define NB 2
#define NS 4096
#define NTOK (NB*NS)   // 8192

typedef __attribute__((ext_vector_type(8))) short short8;
typedef __attribute__((ext_vector_type(4))) float f32x4;
typedef __attribute__((ext_vector_type(4))) unsigned short us4;

__device__ __forceinline__ unsigned short f2bf(float f) {
  unsigned int u = __float_as_uint(f);
  unsigned int r = (u + 0x7fffu + ((u >> 16) & 1u)) >> 16;
  return (unsigned short)r;
}

__device__ __forceinline__ void gload_lds16(const unsigned short* g, unsigned short* l) {
  __builtin_amdgcn_global_load_lds(
      (const __attribute__((address_space(1))) unsigned int*)g,
      (__attribute__((address_space(3))) unsigned int*)l,
      16, 0, 0);
}

// ---------------------------------------------------------------------------
// K1: per-token importance (sum sq) + gate scalar + hs -> bf16 conversion
// ---------------------------------------------------------------------------
__global__ __launch_bounds__(256) void imp_gate_kernel(
    const float* __restrict__ hs, const float* __restrict__ gw,
    const float* __restrict__ gb, float* __restrict__ imp,
    float* __restrict__ gate, unsigned short* __restrict__ hsb) {
  const int row = blockIdx.x;
  const int tid = threadIdx.x;
  const float4 hv = *(const float4*)(hs + (size_t)row*HDIM + tid*4);
  const float4 gv = *(const float4*)(gw + tid*4);
  us4 hb;
  hb.x = f2bf(hv.x); hb.y = f2bf(hv.y); hb.z = f2bf(hv.z); hb.w = f2bf(hv.w);
  *(us4*)(hsb + (size_t)row*HDIM + tid*4) = hb;
  float ss = hv.x*hv.x + hv.y*hv.y + hv.z*hv.z + hv.w*hv.w;
  float dg = hv.x*gv.x + hv.y*gv.y + hv.z*gv.z + hv.w*gv.w;
  __shared__ float sss[256], sdg[256];
  sss[tid] = ss; sdg[tid] = dg;
  __syncthreads();
  for (int s = 128; s > 0; s >>= 1) {
    if (tid < s) { sss[tid] += sss[tid+s]; sdg[tid] += sdg[tid+s]; }
    __syncthreads();
  }
  if (tid == 0) {
    imp[row] = sss[0];
    gate[row] = 1.f/(1.f + expf(-(sdg[0] + gb[0])));
  }
}

// ---------------------------------------------------------------------------
// K2: landmark selection by exact rank (no iteration, no sorting).
// rank(i) = #{j : v[j] > v[i]  or  (v[j]==v[i] and j<i)}  (jax tie-break).
// Ranks are a total order -> unique; rank<64 => lm_idx[b][rank] = i.
// Landmark ORDER is irrelevant downstream (softmax+sum over all 64 is
// permutation-invariant), only the SET matters.
// grid (NS/256, NB) x 256 threads; imp is 16 KB -> L1/L2 resident.
// ---------------------------------------------------------------------------
__global__ __launch_bounds__(256) void lm_rank_kernel(
    const float* __restrict__ imp, int* __restrict__ lm_idx) {
  const int b = blockIdx.y;
  const int myidx = blockIdx.x*256 + threadIdx.x;
  const float* v = imp + b*NS;
  const float mine = v[myidx];
  int cnt = 0;
#pragma unroll 8
  for (int j = 0; j < NS; ++j) {
    const float x = v[j];   // wave-uniform address -> scalar/L1 broadcast
    cnt += (x > mine) || (x == mine && j < myidx);
  }
  if (cnt < LM) lm_idx[b*LM + cnt] = myidx;
}

// ---------------------------------------------------------------------------
// K3: gather landmark rows + K/V projection (fp32, tiny: 128 rows)
// ---------------------------------------------------------------------------
__global__ __launch_bounds__(256) void kv_proj_kernel(
    const float* __restrict__ hs, const int* __restrict__ lm_idx,
    const float* __restrict__ Wk, const float* __restrict__ bk,
    const float* __restrict__ Wv, const float* __restrict__ bv,
    float* __restrict__ kbuf, float* __restrict__ vbuf) {
  const int cq = blockIdx.x, lg = blockIdx.y, b = blockIdx.z;
  const int tid = threadIdx.x;
  __shared__ float rows[8][HDIM];   // 32 KiB
  __shared__ int sidx[8];
  if (tid < 8) sidx[tid] = lm_idx[b*LM + lg*8 + tid];
  __syncthreads();
  for (int e = tid; e < 8*HDIM; e += 256) {
    const int r = e >> 10, d = e & 1023;
    rows[r][d] = hs[((size_t)b*NS + sidx[r])*HDIM + d];
  }
  __syncthreads();
  const int col = cq*256 + tid;
  float ak[8] = {0,0,0,0,0,0,0,0};
  float av[8] = {0,0,0,0,0,0,0,0};
  for (int k = 0; k < HDIM; ++k) {
    const float wk = Wk[(size_t)k*HDIM + col];
    const float wv = Wv[(size_t)k*HDIM + col];
#pragma unroll
    for (int r = 0; r < 8; ++r) {
      const float h = rows[r][k];
      ak[r] += h*wk;
      av[r] += h*wv;
    }
  }
  const float bkc = bk[col], bvc = bv[col];
#pragma unroll
  for (int r = 0; r < 8; ++r) {
    const size_t o = ((size_t)(b*LM + lg*8 + r))*HDIM + col;
    kbuf[o] = ak[r] + bkc;
    vbuf[o] = av[r] + bvc;
  }
}

// ---------------------------------------------------------------------------
// Prep: transpose+convert weight W[K][N] fp32 -> Wt[N][K] bf16  (1024x1024)
// ---------------------------------------------------------------------------
__global__ __launch_bounds__(256) void wtrans_kernel(
    const float* __restrict__ W, unsigned short* __restrict__ Wt) {
  __shared__ float tile[32][33];
  const int tx = threadIdx.x & 31, ty = threadIdx.x >> 5;
  const int bx = blockIdx.x * 32, by = blockIdx.y * 32;
#pragma unroll
  for (int i = 0; i < 32; i += 8)
    tile[ty + i][tx] = W[(size_t)(by + ty + i)*HDIM + bx + tx];
  __syncthreads();
#pragma unroll
  for (int i = 0; i < 32; i += 8)
    Wt[(size_t)(bx + ty + i)*HDIM + by + tx] = f2bf(tile[tx][ty + i]);
}

// ---------------------------------------------------------------------------
// Prep: elementwise fp32 -> bf16 (mem_keys, already [N][K] layout)
// ---------------------------------------------------------------------------
__global__ __launch_bounds__(256) void conv_bf16_kernel(
    const float* __restrict__ in, unsigned short* __restrict__ out) {
  const int i = (blockIdx.x*256 + threadIdx.x)*4;
  const float4 v = *(const float4*)&in[i];
  us4 w;
  w.x = f2bf(v.x); w.y = f2bf(v.y); w.z = f2bf(v.z); w.w = f2bf(v.w);
  *(us4*)&out[i] = w;
}

// ---------------------------------------------------------------------------
// bf16 MFMA GEMM (m97 structure): C[M,N] = alpha*(A @ Bt^T) (+ bias)
// A [M,K] bf16 row-major, Bt [N,K] bf16 row-major, C fp32.
// 128x128 tile, BK=32, 4 waves -> 64x64/wave via 4x4 of 16x16x32 MFMA.
// ---------------------------------------------------------------------------
template<bool HASBIAS>
__global__ __launch_bounds__(256) void gemm_bf16_kernel(
    const unsigned short* __restrict__ A, const unsigned short* __restrict__ Bt,
    const float* __restrict__ bias, float* __restrict__ C,
    int M, int N, int K, float alpha) {
  __shared__ __align__(16) unsigned short As[128*32];
  __shared__ __align__(16) unsigned short Bs[128*32];
  const int tid = threadIdx.x;
  const int lane = tid & 63, wave = tid >> 6;
  const int wr = wave >> 1, wc = wave & 1;
  const int row0 = blockIdx.y << 7, col0 = blockIdx.x << 7;

  f32x4 acc[4][4];
#pragma unroll
  for (int m = 0; m < 4; ++m)
#pragma unroll
    for (int n = 0; n < 4; ++n)
      acc[m][n] = (f32x4)(0.f);

  const int srow = tid >> 2;            // 0..63
  const int sk   = (tid & 3) << 3;      // 0,8,16,24
  const unsigned short* gA = A  + (size_t)(row0 + srow)*K + sk;
  const unsigned short* gB = Bt + (size_t)(col0 + srow)*K + sk;
  const int fr = lane & 15;
  const int fk = (lane >> 4) << 3;      // 0,8,16,24
  const int fg = lane >> 4;

  for (int k0 = 0; k0 < K; k0 += 32) {
    gload_lds16(gA + k0,          As + tid*8);
    gload_lds16(gA + 64*K + k0,   As + 2048 + tid*8);
    gload_lds16(gB + k0,          Bs + tid*8);
    gload_lds16(gB + 64*K + k0,   Bs + 2048 + tid*8);
    __syncthreads();
    short8 af[4], bf[4];
#pragma unroll
    for (int m = 0; m < 4; ++m)
      af[m] = *(const short8*)&As[(wr*64 + m*16 + fr)*32 + fk];
#pragma unroll
    for (int n = 0; n < 4; ++n)
      bf[n] = *(const short8*)&Bs[(wc*64 + n*16 + fr)*32 + fk];
#pragma unroll
    for (int m = 0; m < 4; ++m)
#pragma unroll
      for (int n = 0; n < 4; ++n)
        acc[m][n] = __builtin_amdgcn_mfma_f32_16x16x32_bf16(af[m], bf[n], acc[m][n], 0, 0, 0);
    __syncthreads();
  }

#pragma unroll
  for (int m = 0; m < 4; ++m) {
#pragma unroll
    for (int n = 0; n < 4; ++n) {
      const int col = col0 + wc*64 + n*16 + fr;
      const float bb = HASBIAS ? bias[col] : 0.f;
#pragma unroll
      for (int r = 0; r < 4; ++r) {
        const int row = row0 + wr*64 + m*16 + fg*4 + r;
        C[(size_t)row*N + col] = acc[m][n][r]*alpha + bb;
      }
    }
  }
}

// ---------------------------------------------------------------------------
// K5: landmark attention (fp32 math), writes ctx as bf16.
// ---------------------------------------------------------------------------
__global__ __launch_bounds__(256) void attn_kernel(
    const float* __restrict__ qbuf, const float* __restrict__ kbuf,
    const float* __restrict__ vbuf, unsigned short* __restrict__ ctxb) {
  const int tid = threadIdx.x;
  const int s = blockIdx.x*256 + tid;
  const int h = blockIdx.y, b = blockIdx.z;
  __shared__ float4 K4[LM*16];
  __shared__ float4 V4[LM*16];
  for (int e = tid; e < LM*16; e += 256) {
    const int l = e >> 4, d4 = e & 15;
    const size_t base = ((size_t)(b*LM + l)*NHEAD + h)*HD + (d4 << 2);
    K4[e] = *(const float4*)(kbuf + base);
    V4[e] = *(const float4*)(vbuf + base);
  }
  __syncthreads();

  const float* qp = qbuf + ((size_t)(b*NS + s)*NHEAD + h)*HD;
  float4 q[16];
#pragma unroll
  for (int i = 0; i < 16; ++i) q[i] = ((const float4*)qp)[i];

  float sc[LM];
#pragma unroll
  for (int l = 0; l < LM; ++l) {
    float a = 0.f;
#pragma unroll
    for (int i = 0; i < 16; ++i) {
      const float4 kv = K4[l*16 + i];
      a += q[i].x*kv.x + q[i].y*kv.y + q[i].z*kv.z + q[i].w*kv.w;
    }
    sc[l] = a * 0.125f;
  }
  float mx = sc[0];
#pragma unroll
  for (int l = 1; l < LM; ++l) mx = fmaxf(mx, sc[l]);
  float sum = 0.f;
#pragma unroll
  for (int l = 0; l < LM; ++l) { sc[l] = expf(sc[l] - mx); sum += sc[l]; }
  const float inv = 1.f/sum;

  float4 o[16];
#pragma unroll
  for (int i = 0; i < 16; ++i) o[i] = make_float4(0.f,0.f,0.f,0.f);
#pragma unroll
  for (int l = 0; l < LM; ++l) {
    const float a = sc[l]*inv;
#pragma unroll
    for (int i = 0; i < 16; ++i) {
      const float4 vv = V4[l*16 + i];
      o[i].x += a*vv.x; o[i].y += a*vv.y; o[i].z += a*vv.z; o[i].w += a*vv.w;
    }
  }
  unsigned short* cp = ctxb + ((size_t)(b*NS + s)*NHEAD + h)*HD;
#pragma unroll
  for (int i = 0; i < 16; ++i) {
    us4 w;
    w.x = f2bf(o[i].x); w.y = f2bf(o[i].y); w.z = f2bf(o[i].z); w.w = f2bf(o[i].w);
    *(us4*)(cp + i*4) = w;
  }
}

// ---------------------------------------------------------------------------
// K8: per-token top-32 + softmax + weighted gather; out += gate * mem_out
// ---------------------------------------------------------------------------
__global__ __launch_bounds__(256) void mem_kernel(
    const float* __restrict__ msc, const float* __restrict__ mvals,
    const float* __restrict__ gate, float* __restrict__ out) {
  const int token = blockIdx.x;
  const int tid = threadIdx.x;
  __shared__ int   s_idx[KSEL];
  __shared__ float s_val[KSEL];
  __shared__ float s_w[KSEL];

  if (tid < 64) {
    const int lane = tid;
    float v[8];
#pragma unroll
    for (int j = 0; j < 8; ++j) v[j] = msc[(size_t)token*MS + j*64 + lane];
    for (int it = 0; it < KSEL; ++it) {
      float bvv = -1e30f; int bi = 0x7fffffff;
#pragma unroll
      for (int j = 0; j < 8; ++j) {
        if (v[j] > bvv) { bvv = v[j]; bi = j*64 + lane; }
      }
#pragma unroll
      for (int off = 32; off > 0; off >>= 1) {
        const float ov = __shfl_xor(bvv, off);
        const int   oi = __shfl_xor(bi, off);
        if (ov > bvv || (ov == bvv && oi < bi)) { bvv = ov; bi = oi; }
      }
      if (lane == 0) { s_idx[it] = bi; s_val[it] = bvv; }
#pragma unroll
      for (int j = 0; j < 8; ++j) {
        if (j*64 + lane == bi) v[j] = -1e30f;
      }
    }
    float e = 0.f;
    if (lane < KSEL) e = expf(s_val[lane] - s_val[0]);
    float tot = e;
#pragma unroll
    for (int off = 32; off > 0; off >>= 1) tot += __shfl_xor(tot, off);
    if (lane < KSEL) s_w[lane] = e / tot;
  }
  __syncthreads();

  const int d4 = tid << 2;
  float4 acc = make_float4(0.f,0.f,0.f,0.f);
  for (int it = 0; it < KSEL; ++it) {
    const int m = s_idx[it];
    const float w = s_w[it];
    const float4 mv = *(const float4*)(mvals + (size_t)m*HDIM + d4);
    acc.x += w*mv.x; acc.y += w*mv.y; acc.z += w*mv.z; acc.w += w*mv.w;
  }
  const float g = gate[token];
  float4 cur = *(float4*)(out + (size_t)token*HDIM + d4);
  cur.x += g*acc.x; cur.y += g*acc.y; cur.z += g*acc.z; cur.w += g*acc.w;
  *(float4*)(out + (size_t)token*HDIM + d4) = cur;
}

// ---------------------------------------------------------------------------
extern "C" void kernel_launch(void* const* d_in, const int* in_sizes, int n_in,
                              void* d_out, int out_size, void* d_ws, size_t ws_size,
                              hipStream_t stream) {
  const float* hs = (const float*)d_in[0];
  const float* Wq = (const float*)d_in[1];
  const float* bq = (const float*)d_in[2];
  const float* Wk = (const float*)d_in[3];
  const float* bk = (const float*)d_in[4];
  const float* Wv = (const float*)d_in[5];
  const float* bv = (const float*)d_in[6];
  const float* Wo = (const float*)d_in[7];
  const float* bo = (const float*)d_in[8];
  const float* mk = (const float*)d_in[9];
  const float* mv = (const float*)d_in[10];
  const float* gw = (const float*)d_in[11];
  const float* gb = (const float*)d_in[12];
  float* out = (float*)d_out;

  char* ws = (char*)d_ws;
  unsigned short* hsb  = (unsigned short*)(ws);                       // 16 MiB [NTOK,HDIM] bf16
  float*          q    = (float*)(ws + ((size_t)16 << 20));           // 32 MiB [NTOK,HDIM] fp32
  unsigned short* ctxb = (unsigned short*)(ws + ((size_t)48 << 20));  // 16 MiB [NTOK,HDIM] bf16
  unsigned short* Wqt  = (unsigned short*)(ws + ((size_t)64 << 20));  // 2 MiB [N,K] bf16
  unsigned short* Wot  = (unsigned short*)(ws + ((size_t)66 << 20));  // 2 MiB
  unsigned short* mkb  = (unsigned short*)(ws + ((size_t)68 << 20));  // 1 MiB [MS,HDIM] bf16
  float*          kbuf = (float*)(ws + ((size_t)69 << 20));           // 512 KiB
  float*          vbuf = (float*)(ws + ((size_t)69 << 20) + ((size_t)512 << 10));
  float*          imp  = (float*)(ws + ((size_t)70 << 20));           // 32 KiB
  float*          gate = (float*)(ws + ((size_t)70 << 20) + ((size_t)32 << 10));
  int*            lmi  = (int*)  (ws + ((size_t)70 << 20) + ((size_t)64 << 10));
  float*          msc  = q;  // mem scores [NTOK,MS] alias q (q dead after attn)

  imp_gate_kernel<<<dim3(NTOK), 256, 0, stream>>>(hs, gw, gb, imp, gate, hsb);
  lm_rank_kernel<<<dim3(NS/256, NB), 256, 0, stream>>>(imp, lmi);
  kv_proj_kernel<<<dim3(4, 8, NB), 256, 0, stream>>>(hs, lmi, Wk, bk, Wv, bv, kbuf, vbuf);
  wtrans_kernel<<<dim3(32, 32), 256, 0, stream>>>(Wq, Wqt);
  wtrans_kernel<<<dim3(32, 32), 256, 0, stream>>>(Wo, Wot);
  conv_bf16_kernel<<<dim3(MS*HDIM/1024), 256, 0, stream>>>(mk, mkb);

  gemm_bf16_kernel<true><<<dim3(HDIM/128, NTOK/128), 256, 0, stream>>>(
      hsb, Wqt, bq, q, NTOK, HDIM, HDIM, 1.f);
  attn_kernel<<<dim3(NS/256, NHEAD, NB), 256, 0, stream>>>(q, kbuf, vbuf, ctxb);
  gemm_bf16_kernel<true><<<dim3(HDIM/128, NTOK/128), 256, 0, stream>>>(
      ctxb, Wot, bo, out, NTOK, HDIM, HDIM, 1.f);
  gemm_bf16_kernel<false><<<dim3(MS/128, NTOK/128), 256, 0, stream>>>(
      hsb, mkb, nullptr, msc, NTOK, MS, HDIM, 0.03125f);
  mem_kernel<<<dim3(NTOK), 256, 0, stream>>>(msc, mv, gate, out);
}

// Round 4
// 368.096 us; speedup vs baseline: 2.7670x; 1.4508x over previous
//
#include <hip/hip_runtime.h>
#include <math.h>

// Problem constants (from reference setup_inputs)
#define HDIM 1024
#define NHEAD 16
#define HD 64
#define LM 64          // NUM_LANDMARKS
#define MS 512         // memory slots
#define KSEL 32        // top_k
#define NB 2
#define NS 4096
#define NTOK (NB*NS)   // 8192

typedef __attribute__((ext_vector_type(8))) short short8;
typedef __attribute__((ext_vector_type(4))) float f32x4;
typedef __attribute__((ext_vector_type(4))) unsigned short us4;

__device__ __forceinline__ unsigned short f2bf(float f) {
  unsigned int u = __float_as_uint(f);
  unsigned int r = (u + 0x7fffu + ((u >> 16) & 1u)) >> 16;
  return (unsigned short)r;
}

__device__ __forceinline__ void gload_lds16(const unsigned short* g, unsigned short* l) {
  __builtin_amdgcn_global_load_lds(
      (const __attribute__((address_space(1))) unsigned int*)g,
      (__attribute__((address_space(3))) unsigned int*)l,
      16, 0, 0);
}

// ---------------------------------------------------------------------------
// K1: per-token importance (sum sq) + gate scalar + hs -> bf16 conversion
// ---------------------------------------------------------------------------
__global__ __launch_bounds__(256) void imp_gate_kernel(
    const float* __restrict__ hs, const float* __restrict__ gw,
    const float* __restrict__ gb, float* __restrict__ imp,
    float* __restrict__ gate, unsigned short* __restrict__ hsb) {
  const int row = blockIdx.x;
  const int tid = threadIdx.x;
  const float4 hv = *(const float4*)(hs + (size_t)row*HDIM + tid*4);
  const float4 gv = *(const float4*)(gw + tid*4);
  us4 hb;
  hb.x = f2bf(hv.x); hb.y = f2bf(hv.y); hb.z = f2bf(hv.z); hb.w = f2bf(hv.w);
  *(us4*)(hsb + (size_t)row*HDIM + tid*4) = hb;
  float ss = hv.x*hv.x + hv.y*hv.y + hv.z*hv.z + hv.w*hv.w;
  float dg = hv.x*gv.x + hv.y*gv.y + hv.z*gv.z + hv.w*gv.w;
  __shared__ float sss[256], sdg[256];
  sss[tid] = ss; sdg[tid] = dg;
  __syncthreads();
  for (int s = 128; s > 0; s >>= 1) {
    if (tid < s) { sss[tid] += sss[tid+s]; sdg[tid] += sdg[tid+s]; }
    __syncthreads();
  }
  if (tid == 0) {
    imp[row] = sss[0];
    gate[row] = 1.f/(1.f + expf(-(sdg[0] + gb[0])));
  }
}

// ---------------------------------------------------------------------------
// K2a: rank counting, parallel over (candidate, j-chunk).
// rank(i) = #{j : v[j] > v[i]  or  (v[j]==v[i] and j<i)}  (jax tie-break).
// Each block stages a 1024-elem j-chunk in LDS; each thread accumulates its
// candidate's partial count, then one atomicAdd. grid (NS/256, 4, NB).
// ---------------------------------------------------------------------------
__global__ __launch_bounds__(256) void lm_count_kernel(
    const float* __restrict__ imp, int* __restrict__ cnt) {
  const int b = blockIdx.z;
  const int jc = blockIdx.y;
  const int i = blockIdx.x*256 + threadIdx.x;
  const float* v = imp + b*NS;
  const float mine = v[i];
  __shared__ float tile[1024];
  const int j0 = jc*1024;
  *(float4*)&tile[threadIdx.x*4] = *(const float4*)&v[j0 + threadIdx.x*4];
  __syncthreads();
  int c = 0;
#pragma unroll 8
  for (int p = 0; p < 1024; p += 4) {
    const float4 t = *(const float4*)&tile[p];
    c += (t.x > mine) || (t.x == mine && (j0+p+0) < i);
    c += (t.y > mine) || (t.y == mine && (j0+p+1) < i);
    c += (t.z > mine) || (t.z == mine && (j0+p+2) < i);
    c += (t.w > mine) || (t.w == mine && (j0+p+3) < i);
  }
  atomicAdd(&cnt[b*NS + i], c);
}

// K2b: scatter selected candidates. Landmark ORDER is irrelevant downstream
// (softmax+sum over all 64 is permutation-invariant); only the SET matters.
__global__ __launch_bounds__(256) void lm_sel_kernel(
    const int* __restrict__ cnt, int* __restrict__ lm_idx) {
  const int b = blockIdx.y;
  const int i = blockIdx.x*256 + threadIdx.x;
  const int c = cnt[b*NS + i];
  if (c < LM) lm_idx[b*LM + c] = i;
}

// ---------------------------------------------------------------------------
// K3a: gather + K/V projection, K-split into 8 chunks of 128 for parallelism.
// grid (4 col-quarters, 8 lm-groups, 16 = b*8+ksplit); fp32 partials.
// ---------------------------------------------------------------------------
__global__ __launch_bounds__(256) void kv_proj_part_kernel(
    const float* __restrict__ hs, const int* __restrict__ lm_idx,
    const float* __restrict__ Wk, const float* __restrict__ Wv,
    float* __restrict__ partK, float* __restrict__ partV) {
  const int cq = blockIdx.x, lg = blockIdx.y, zz = blockIdx.z;
  const int b = zz >> 3, s = zz & 7;
  const int tid = threadIdx.x;
  __shared__ float rows[8][128];   // 4 KiB k-slice of the 8 gathered rows
  __shared__ int sidx[8];
  if (tid < 8) sidx[tid] = lm_idx[b*LM + lg*8 + tid];
  __syncthreads();
  for (int e = tid; e < 8*128; e += 256) {
    const int r = e >> 7, kk = e & 127;
    rows[r][kk] = hs[((size_t)b*NS + sidx[r])*HDIM + s*128 + kk];
  }
  __syncthreads();
  const int col = cq*256 + tid;
  float ak[8] = {0,0,0,0,0,0,0,0};
  float av[8] = {0,0,0,0,0,0,0,0};
#pragma unroll 4
  for (int kk = 0; kk < 128; ++kk) {
    const float wk = Wk[(size_t)(s*128 + kk)*HDIM + col];
    const float wv = Wv[(size_t)(s*128 + kk)*HDIM + col];
#pragma unroll
    for (int r = 0; r < 8; ++r) {
      const float h = rows[r][kk];
      ak[r] += h*wk;
      av[r] += h*wv;
    }
  }
#pragma unroll
  for (int r = 0; r < 8; ++r) {
    const size_t o = ((size_t)zz*LM + lg*8 + r)*HDIM + col;
    partK[o] = ak[r];
    partV[o] = av[r];
  }
}

// K3b: reduce the 8 K-split partials + bias -> kbuf/vbuf. grid (4, LM, NB).
__global__ __launch_bounds__(256) void kv_reduce_kernel(
    const float* __restrict__ partK, const float* __restrict__ partV,
    const float* __restrict__ bk, const float* __restrict__ bv,
    float* __restrict__ kbuf, float* __restrict__ vbuf) {
  const int cq = blockIdx.x, l = blockIdx.y, b = blockIdx.z;
  const int col = cq*256 + threadIdx.x;
  float sk = bk[col], sv = bv[col];
#pragma unroll
  for (int s = 0; s < 8; ++s) {
    const size_t o = ((size_t)(b*8 + s)*LM + l)*HDIM + col;
    sk += partK[o];
    sv += partV[o];
  }
  const size_t o = ((size_t)b*LM + l)*HDIM + col;
  kbuf[o] = sk;
  vbuf[o] = sv;
}

// ---------------------------------------------------------------------------
// Prep: transpose+convert weight W[K][N] fp32 -> Wt[N][K] bf16  (1024x1024)
// ---------------------------------------------------------------------------
__global__ __launch_bounds__(256) void wtrans_kernel(
    const float* __restrict__ W, unsigned short* __restrict__ Wt) {
  __shared__ float tile[32][33];
  const int tx = threadIdx.x & 31, ty = threadIdx.x >> 5;
  const int bx = blockIdx.x * 32, by = blockIdx.y * 32;
#pragma unroll
  for (int i = 0; i < 32; i += 8)
    tile[ty + i][tx] = W[(size_t)(by + ty + i)*HDIM + bx + tx];
  __syncthreads();
#pragma unroll
  for (int i = 0; i < 32; i += 8)
    Wt[(size_t)(bx + ty + i)*HDIM + by + tx] = f2bf(tile[tx][ty + i]);
}

// ---------------------------------------------------------------------------
// Prep: elementwise fp32 -> bf16 (mem_keys, already [N][K] layout)
// ---------------------------------------------------------------------------
__global__ __launch_bounds__(256) void conv_bf16_kernel(
    const float* __restrict__ in, unsigned short* __restrict__ out) {
  const int i = (blockIdx.x*256 + threadIdx.x)*4;
  const float4 v = *(const float4*)&in[i];
  us4 w;
  w.x = f2bf(v.x); w.y = f2bf(v.y); w.z = f2bf(v.z); w.w = f2bf(v.w);
  *(us4*)&out[i] = w;
}

// ---------------------------------------------------------------------------
// bf16 MFMA GEMM (m97 structure): C[M,N] = alpha*(A @ Bt^T) (+ bias)
// A [M,K] bf16 row-major, Bt [N,K] bf16 row-major, C fp32.
// 128x128 tile, BK=32, 4 waves -> 64x64/wave via 4x4 of 16x16x32 MFMA.
// ---------------------------------------------------------------------------
template<bool HASBIAS>
__global__ __launch_bounds__(256) void gemm_bf16_kernel(
    const unsigned short* __restrict__ A, const unsigned short* __restrict__ Bt,
    const float* __restrict__ bias, float* __restrict__ C,
    int M, int N, int K, float alpha) {
  __shared__ __align__(16) unsigned short As[128*32];
  __shared__ __align__(16) unsigned short Bs[128*32];
  const int tid = threadIdx.x;
  const int lane = tid & 63, wave = tid >> 6;
  const int wr = wave >> 1, wc = wave & 1;
  const int row0 = blockIdx.y << 7, col0 = blockIdx.x << 7;

  f32x4 acc[4][4];
#pragma unroll
  for (int m = 0; m < 4; ++m)
#pragma unroll
    for (int n = 0; n < 4; ++n)
      acc[m][n] = (f32x4)(0.f);

  const int srow = tid >> 2;            // 0..63
  const int sk   = (tid & 3) << 3;      // 0,8,16,24
  const unsigned short* gA = A  + (size_t)(row0 + srow)*K + sk;
  const unsigned short* gB = Bt + (size_t)(col0 + srow)*K + sk;
  const int fr = lane & 15;
  const int fk = (lane >> 4) << 3;      // 0,8,16,24
  const int fg = lane >> 4;

  for (int k0 = 0; k0 < K; k0 += 32) {
    gload_lds16(gA + k0,          As + tid*8);
    gload_lds16(gA + 64*K + k0,   As + 2048 + tid*8);
    gload_lds16(gB + k0,          Bs + tid*8);
    gload_lds16(gB + 64*K + k0,   Bs + 2048 + tid*8);
    __syncthreads();
    short8 af[4], bf[4];
#pragma unroll
    for (int m = 0; m < 4; ++m)
      af[m] = *(const short8*)&As[(wr*64 + m*16 + fr)*32 + fk];
#pragma unroll
    for (int n = 0; n < 4; ++n)
      bf[n] = *(const short8*)&Bs[(wc*64 + n*16 + fr)*32 + fk];
#pragma unroll
    for (int m = 0; m < 4; ++m)
#pragma unroll
      for (int n = 0; n < 4; ++n)
        acc[m][n] = __builtin_amdgcn_mfma_f32_16x16x32_bf16(af[m], bf[n], acc[m][n], 0, 0, 0);
    __syncthreads();
  }

#pragma unroll
  for (int m = 0; m < 4; ++m) {
#pragma unroll
    for (int n = 0; n < 4; ++n) {
      const int col = col0 + wc*64 + n*16 + fr;
      const float bb = HASBIAS ? bias[col] : 0.f;
#pragma unroll
      for (int r = 0; r < 4; ++r) {
        const int row = row0 + wr*64 + m*16 + fg*4 + r;
        C[(size_t)row*N + col] = acc[m][n][r]*alpha + bb;
      }
    }
  }
}

// ---------------------------------------------------------------------------
// K5: landmark attention (fp32 math), writes ctx as bf16.
// ---------------------------------------------------------------------------
__global__ __launch_bounds__(256) void attn_kernel(
    const float* __restrict__ qbuf, const float* __restrict__ kbuf,
    const float* __restrict__ vbuf, unsigned short* __restrict__ ctxb) {
  const int tid = threadIdx.x;
  const int s = blockIdx.x*256 + tid;
  const int h = blockIdx.y, b = blockIdx.z;
  __shared__ float4 K4[LM*16];
  __shared__ float4 V4[LM*16];
  for (int e = tid; e < LM*16; e += 256) {
    const int l = e >> 4, d4 = e & 15;
    const size_t base = ((size_t)(b*LM + l)*NHEAD + h)*HD + (d4 << 2);
    K4[e] = *(const float4*)(kbuf + base);
    V4[e] = *(const float4*)(vbuf + base);
  }
  __syncthreads();

  const float* qp = qbuf + ((size_t)(b*NS + s)*NHEAD + h)*HD;
  float4 q[16];
#pragma unroll
  for (int i = 0; i < 16; ++i) q[i] = ((const float4*)qp)[i];

  float sc[LM];
#pragma unroll
  for (int l = 0; l < LM; ++l) {
    float a = 0.f;
#pragma unroll
    for (int i = 0; i < 16; ++i) {
      const float4 kv = K4[l*16 + i];
      a += q[i].x*kv.x + q[i].y*kv.y + q[i].z*kv.z + q[i].w*kv.w;
    }
    sc[l] = a * 0.125f;
  }
  float mx = sc[0];
#pragma unroll
  for (int l = 1; l < LM; ++l) mx = fmaxf(mx, sc[l]);
  float sum = 0.f;
#pragma unroll
  for (int l = 0; l < LM; ++l) { sc[l] = expf(sc[l] - mx); sum += sc[l]; }
  const float inv = 1.f/sum;

  float4 o[16];
#pragma unroll
  for (int i = 0; i < 16; ++i) o[i] = make_float4(0.f,0.f,0.f,0.f);
#pragma unroll
  for (int l = 0; l < LM; ++l) {
    const float a = sc[l]*inv;
#pragma unroll
    for (int i = 0; i < 16; ++i) {
      const float4 vv = V4[l*16 + i];
      o[i].x += a*vv.x; o[i].y += a*vv.y; o[i].z += a*vv.z; o[i].w += a*vv.w;
    }
  }
  unsigned short* cp = ctxb + ((size_t)(b*NS + s)*NHEAD + h)*HD;
#pragma unroll
  for (int i = 0; i < 16; ++i) {
    us4 w;
    w.x = f2bf(o[i].x); w.y = f2bf(o[i].y); w.z = f2bf(o[i].z); w.w = f2bf(o[i].w);
    *(us4*)(cp + i*4) = w;
  }
}

// ---------------------------------------------------------------------------
// K8: per-token top-32 + softmax + weighted gather; out += gate * mem_out
// ---------------------------------------------------------------------------
__global__ __launch_bounds__(256) void mem_kernel(
    const float* __restrict__ msc, const float* __restrict__ mvals,
    const float* __restrict__ gate, float* __restrict__ out) {
  const int token = blockIdx.x;
  const int tid = threadIdx.x;
  __shared__ int   s_idx[KSEL];
  __shared__ float s_val[KSEL];
  __shared__ float s_w[KSEL];

  if (tid < 64) {
    const int lane = tid;
    float v[8];
#pragma unroll
    for (int j = 0; j < 8; ++j) v[j] = msc[(size_t)token*MS + j*64 + lane];
    for (int it = 0; it < KSEL; ++it) {
      float bvv = -1e30f; int bi = 0x7fffffff;
#pragma unroll
      for (int j = 0; j < 8; ++j) {
        if (v[j] > bvv) { bvv = v[j]; bi = j*64 + lane; }
      }
#pragma unroll
      for (int off = 32; off > 0; off >>= 1) {
        const float ov = __shfl_xor(bvv, off);
        const int   oi = __shfl_xor(bi, off);
        if (ov > bvv || (ov == bvv && oi < bi)) { bvv = ov; bi = oi; }
      }
      if (lane == 0) { s_idx[it] = bi; s_val[it] = bvv; }
#pragma unroll
      for (int j = 0; j < 8; ++j) {
        if (j*64 + lane == bi) v[j] = -1e30f;
      }
    }
    float e = 0.f;
    if (lane < KSEL) e = expf(s_val[lane] - s_val[0]);
    float tot = e;
#pragma unroll
    for (int off = 32; off > 0; off >>= 1) tot += __shfl_xor(tot, off);
    if (lane < KSEL) s_w[lane] = e / tot;
  }
  __syncthreads();

  const int d4 = tid << 2;
  float4 acc = make_float4(0.f,0.f,0.f,0.f);
  for (int it = 0; it < KSEL; ++it) {
    const int m = s_idx[it];
    const float w = s_w[it];
    const float4 mv = *(const float4*)(mvals + (size_t)m*HDIM + d4);
    acc.x += w*mv.x; acc.y += w*mv.y; acc.z += w*mv.z; acc.w += w*mv.w;
  }
  const float g = gate[token];
  float4 cur = *(float4*)(out + (size_t)token*HDIM + d4);
  cur.x += g*acc.x; cur.y += g*acc.y; cur.z += g*acc.z; cur.w += g*acc.w;
  *(float4*)(out + (size_t)token*HDIM + d4) = cur;
}

// ---------------------------------------------------------------------------
extern "C" void kernel_launch(void* const* d_in, const int* in_sizes, int n_in,
                              void* d_out, int out_size, void* d_ws, size_t ws_size,
                              hipStream_t stream) {
  const float* hs = (const float*)d_in[0];
  const float* Wq = (const float*)d_in[1];
  const float* bq = (const float*)d_in[2];
  const float* Wk = (const float*)d_in[3];
  const float* bk = (const float*)d_in[4];
  const float* Wv = (const float*)d_in[5];
  const float* bv = (const float*)d_in[6];
  const float* Wo = (const float*)d_in[7];
  const float* bo = (const float*)d_in[8];
  const float* mk = (const float*)d_in[9];
  const float* mv = (const float*)d_in[10];
  const float* gw = (const float*)d_in[11];
  const float* gb = (const float*)d_in[12];
  float* out = (float*)d_out;

  char* ws = (char*)d_ws;
  unsigned short* hsb  = (unsigned short*)(ws);                       // 16 MiB [NTOK,HDIM] bf16
  float*          q    = (float*)(ws + ((size_t)16 << 20));           // 32 MiB [NTOK,HDIM] fp32
  unsigned short* ctxb = (unsigned short*)(ws + ((size_t)48 << 20));  // 16 MiB [NTOK,HDIM] bf16
  unsigned short* Wqt  = (unsigned short*)(ws + ((size_t)64 << 20));  // 2 MiB [N,K] bf16
  unsigned short* Wot  = (unsigned short*)(ws + ((size_t)66 << 20));  // 2 MiB
  unsigned short* mkb  = (unsigned short*)(ws + ((size_t)68 << 20));  // 1 MiB [MS,HDIM] bf16
  float*          kbuf = (float*)(ws + ((size_t)69 << 20));           // 512 KiB
  float*          vbuf = (float*)(ws + ((size_t)69 << 20) + ((size_t)512 << 10));
  float*          imp  = (float*)(ws + ((size_t)70 << 20));           // 32 KiB
  float*          gate = (float*)(ws + ((size_t)70 << 20) + ((size_t)32 << 10));
  int*            lmi  = (int*)  (ws + ((size_t)70 << 20) + ((size_t)64 << 10)); // 4 KiB
  int*            cnt  = (int*)  (ws + ((size_t)70 << 20) + ((size_t)68 << 10)); // 32 KiB
  float*          msc  = q;  // mem scores [NTOK,MS] alias q (q dead after attn)
  // K-split partials live in the q region (dead until gemm Q writes it):
  float*          partK = q;                        // 4 MiB [NB*8][LM][HDIM]
  float*          partV = q + (size_t)NB*8*LM*HDIM; // 4 MiB

  imp_gate_kernel<<<dim3(NTOK), 256, 0, stream>>>(hs, gw, gb, imp, gate, hsb);
  hipMemsetAsync(cnt, 0, NB*NS*sizeof(int), stream);
  lm_count_kernel<<<dim3(NS/256, 4, NB), 256, 0, stream>>>(imp, cnt);
  lm_sel_kernel<<<dim3(NS/256, NB), 256, 0, stream>>>(cnt, lmi);
  kv_proj_part_kernel<<<dim3(4, 8, 16), 256, 0, stream>>>(hs, lmi, Wk, Wv, partK, partV);
  kv_reduce_kernel<<<dim3(4, LM, NB), 256, 0, stream>>>(partK, partV, bk, bv, kbuf, vbuf);
  wtrans_kernel<<<dim3(32, 32), 256, 0, stream>>>(Wq, Wqt);
  wtrans_kernel<<<dim3(32, 32), 256, 0, stream>>>(Wo, Wot);
  conv_bf16_kernel<<<dim3(MS*HDIM/1024), 256, 0, stream>>>(mk, mkb);

  gemm_bf16_kernel<true><<<dim3(HDIM/128, NTOK/128), 256, 0, stream>>>(
      hsb, Wqt, bq, q, NTOK, HDIM, HDIM, 1.f);
  attn_kernel<<<dim3(NS/256, NHEAD, NB), 256, 0, stream>>>(q, kbuf, vbuf, ctxb);
  gemm_bf16_kernel<true><<<dim3(HDIM/128, NTOK/128), 256, 0, stream>>>(
      ctxb, Wot, bo, out, NTOK, HDIM, HDIM, 1.f);
  gemm_bf16_kernel<false><<<dim3(MS/128, NTOK/128), 256, 0, stream>>>(
      hsb, mkb, nullptr, msc, NTOK, MS, HDIM, 0.03125f);
  mem_kernel<<<dim3(NTOK), 256, 0, stream>>>(msc, mv, gate, out);
}

// Round 5
// 294.224 us; speedup vs baseline: 3.4617x; 1.2511x over previous
//
#include <hip/hip_runtime.h>
#include <math.h>

// Problem constants (from reference setup_inputs)
#define HDIM 1024
#define NHEAD 16
#define HD 64
#define LM 64          // NUM_LANDMARKS
#define MS 512         // memory slots
#define KSEL 32        // top_k
#define NB 2
#define NS 4096
#define NTOK (NB*NS)   // 8192

typedef __attribute__((ext_vector_type(8))) short short8;
typedef __attribute__((ext_vector_type(4))) float f32x4;
typedef __attribute__((ext_vector_type(4))) unsigned short us4;

__device__ __forceinline__ unsigned short f2bf(float f) {
  unsigned int u = __float_as_uint(f);
  unsigned int r = (u + 0x7fffu + ((u >> 16) & 1u)) >> 16;
  return (unsigned short)r;
}

__device__ __forceinline__ void gload_lds16(const unsigned short* g, unsigned short* l) {
  __builtin_amdgcn_global_load_lds(
      (const __attribute__((address_space(1))) unsigned int*)g,
      (__attribute__((address_space(3))) unsigned int*)l,
      16, 0, 0);
}

// ---------------------------------------------------------------------------
// K1: per-token importance (sum sq) + gate scalar + hs -> bf16 conversion
// ---------------------------------------------------------------------------
__global__ __launch_bounds__(256) void imp_gate_kernel(
    const float* __restrict__ hs, const float* __restrict__ gw,
    const float* __restrict__ gb, float* __restrict__ imp,
    float* __restrict__ gate, unsigned short* __restrict__ hsb) {
  const int row = blockIdx.x;
  const int tid = threadIdx.x;
  const float4 hv = *(const float4*)(hs + (size_t)row*HDIM + tid*4);
  const float4 gv = *(const float4*)(gw + tid*4);
  us4 hb;
  hb.x = f2bf(hv.x); hb.y = f2bf(hv.y); hb.z = f2bf(hv.z); hb.w = f2bf(hv.w);
  *(us4*)(hsb + (size_t)row*HDIM + tid*4) = hb;
  float ss = hv.x*hv.x + hv.y*hv.y + hv.z*hv.z + hv.w*hv.w;
  float dg = hv.x*gv.x + hv.y*gv.y + hv.z*gv.z + hv.w*gv.w;
  __shared__ float sss[256], sdg[256];
  sss[tid] = ss; sdg[tid] = dg;
  __syncthreads();
  for (int s = 128; s > 0; s >>= 1) {
    if (tid < s) { sss[tid] += sss[tid+s]; sdg[tid] += sdg[tid+s]; }
    __syncthreads();
  }
  if (tid == 0) {
    imp[row] = sss[0];
    gate[row] = 1.f/(1.f + expf(-(sdg[0] + gb[0])));
  }
}

// ---------------------------------------------------------------------------
// K2a: rank counting, parallel over (candidate, j-chunk).
// rank(i) = #{j : v[j] > v[i]  or  (v[j]==v[i] and j<i)}  (jax tie-break).
// ---------------------------------------------------------------------------
__global__ __launch_bounds__(256) void lm_count_kernel(
    const float* __restrict__ imp, int* __restrict__ cnt) {
  const int b = blockIdx.z;
  const int jc = blockIdx.y;
  const int i = blockIdx.x*256 + threadIdx.x;
  const float* v = imp + b*NS;
  const float mine = v[i];
  __shared__ float tile[1024];
  const int j0 = jc*1024;
  *(float4*)&tile[threadIdx.x*4] = *(const float4*)&v[j0 + threadIdx.x*4];
  __syncthreads();
  int c = 0;
#pragma unroll 8
  for (int p = 0; p < 1024; p += 4) {
    const float4 t = *(const float4*)&tile[p];
    c += (t.x > mine) || (t.x == mine && (j0+p+0) < i);
    c += (t.y > mine) || (t.y == mine && (j0+p+1) < i);
    c += (t.z > mine) || (t.z == mine && (j0+p+2) < i);
    c += (t.w > mine) || (t.w == mine && (j0+p+3) < i);
  }
  atomicAdd(&cnt[b*NS + i], c);
}

// K2b: scatter selected candidates (set only; order irrelevant downstream).
__global__ __launch_bounds__(256) void lm_sel_kernel(
    const int* __restrict__ cnt, int* __restrict__ lm_idx) {
  const int b = blockIdx.y;
  const int i = blockIdx.x*256 + threadIdx.x;
  const int c = cnt[b*NS + i];
  if (c < LM) lm_idx[b*LM + c] = i;
}

// ---------------------------------------------------------------------------
// K3a: gather + K/V projection, K-split into 8 chunks of 128 for parallelism.
// ---------------------------------------------------------------------------
__global__ __launch_bounds__(256) void kv_proj_part_kernel(
    const float* __restrict__ hs, const int* __restrict__ lm_idx,
    const float* __restrict__ Wk, const float* __restrict__ Wv,
    float* __restrict__ partK, float* __restrict__ partV) {
  const int cq = blockIdx.x, lg = blockIdx.y, zz = blockIdx.z;
  const int b = zz >> 3, s = zz & 7;
  const int tid = threadIdx.x;
  __shared__ float rows[8][128];
  __shared__ int sidx[8];
  if (tid < 8) sidx[tid] = lm_idx[b*LM + lg*8 + tid];
  __syncthreads();
  for (int e = tid; e < 8*128; e += 256) {
    const int r = e >> 7, kk = e & 127;
    rows[r][kk] = hs[((size_t)b*NS + sidx[r])*HDIM + s*128 + kk];
  }
  __syncthreads();
  const int col = cq*256 + tid;
  float ak[8] = {0,0,0,0,0,0,0,0};
  float av[8] = {0,0,0,0,0,0,0,0};
#pragma unroll 4
  for (int kk = 0; kk < 128; ++kk) {
    const float wk = Wk[(size_t)(s*128 + kk)*HDIM + col];
    const float wv = Wv[(size_t)(s*128 + kk)*HDIM + col];
#pragma unroll
    for (int r = 0; r < 8; ++r) {
      const float h = rows[r][kk];
      ak[r] += h*wk;
      av[r] += h*wv;
    }
  }
#pragma unroll
  for (int r = 0; r < 8; ++r) {
    const size_t o = ((size_t)zz*LM + lg*8 + r)*HDIM + col;
    partK[o] = ak[r];
    partV[o] = av[r];
  }
}

// K3b: reduce the 8 K-split partials + bias -> kbuf/vbuf. grid (4, LM, NB).
__global__ __launch_bounds__(256) void kv_reduce_kernel(
    const float* __restrict__ partK, const float* __restrict__ partV,
    const float* __restrict__ bk, const float* __restrict__ bv,
    float* __restrict__ kbuf, float* __restrict__ vbuf) {
  const int cq = blockIdx.x, l = blockIdx.y, b = blockIdx.z;
  const int col = cq*256 + threadIdx.x;
  float sk = bk[col], sv = bv[col];
#pragma unroll
  for (int s = 0; s < 8; ++s) {
    const size_t o = ((size_t)(b*8 + s)*LM + l)*HDIM + col;
    sk += partK[o];
    sv += partV[o];
  }
  const size_t o = ((size_t)b*LM + l)*HDIM + col;
  kbuf[o] = sk;
  vbuf[o] = sv;
}

// ---------------------------------------------------------------------------
// Prep: transpose+convert weight W[K][N] fp32 -> Wt[N][K] bf16  (1024x1024)
// ---------------------------------------------------------------------------
__global__ __launch_bounds__(256) void wtrans_kernel(
    const float* __restrict__ W, unsigned short* __restrict__ Wt) {
  __shared__ float tile[32][33];
  const int tx = threadIdx.x & 31, ty = threadIdx.x >> 5;
  const int bx = blockIdx.x * 32, by = blockIdx.y * 32;
#pragma unroll
  for (int i = 0; i < 32; i += 8)
    tile[ty + i][tx] = W[(size_t)(by + ty + i)*HDIM + bx + tx];
  __syncthreads();
#pragma unroll
  for (int i = 0; i < 32; i += 8)
    Wt[(size_t)(bx + ty + i)*HDIM + by + tx] = f2bf(tile[tx][ty + i]);
}

// ---------------------------------------------------------------------------
// Prep: elementwise fp32 -> bf16 (mem_keys, already [N][K] layout)
// ---------------------------------------------------------------------------
__global__ __launch_bounds__(256) void conv_bf16_kernel(
    const float* __restrict__ in, unsigned short* __restrict__ out) {
  const int i = (blockIdx.x*256 + threadIdx.x)*4;
  const float4 v = *(const float4*)&in[i];
  us4 w;
  w.x = f2bf(v.x); w.y = f2bf(v.y); w.z = f2bf(v.z); w.w = f2bf(v.w);
  *(us4*)&out[i] = w;
}

// ---------------------------------------------------------------------------
// bf16 MFMA GEMM (m97 structure): C[M,N] = alpha*(A @ Bt^T) (+ bias)
// ---------------------------------------------------------------------------
template<bool HASBIAS>
__global__ __launch_bounds__(256) void gemm_bf16_kernel(
    const unsigned short* __restrict__ A, const unsigned short* __restrict__ Bt,
    const float* __restrict__ bias, float* __restrict__ C,
    int M, int N, int K, float alpha) {
  __shared__ __align__(16) unsigned short As[128*32];
  __shared__ __align__(16) unsigned short Bs[128*32];
  const int tid = threadIdx.x;
  const int lane = tid & 63, wave = tid >> 6;
  const int wr = wave >> 1, wc = wave & 1;
  const int row0 = blockIdx.y << 7, col0 = blockIdx.x << 7;

  f32x4 acc[4][4];
#pragma unroll
  for (int m = 0; m < 4; ++m)
#pragma unroll
    for (int n = 0; n < 4; ++n)
      acc[m][n] = (f32x4)(0.f);

  const int srow = tid >> 2;
  const int sk   = (tid & 3) << 3;
  const unsigned short* gA = A  + (size_t)(row0 + srow)*K + sk;
  const unsigned short* gB = Bt + (size_t)(col0 + srow)*K + sk;
  const int fr = lane & 15;
  const int fk = (lane >> 4) << 3;
  const int fg = lane >> 4;

  for (int k0 = 0; k0 < K; k0 += 32) {
    gload_lds16(gA + k0,          As + tid*8);
    gload_lds16(gA + 64*K + k0,   As + 2048 + tid*8);
    gload_lds16(gB + k0,          Bs + tid*8);
    gload_lds16(gB + 64*K + k0,   Bs + 2048 + tid*8);
    __syncthreads();
    short8 af[4], bf[4];
#pragma unroll
    for (int m = 0; m < 4; ++m)
      af[m] = *(const short8*)&As[(wr*64 + m*16 + fr)*32 + fk];
#pragma unroll
    for (int n = 0; n < 4; ++n)
      bf[n] = *(const short8*)&Bs[(wc*64 + n*16 + fr)*32 + fk];
#pragma unroll
    for (int m = 0; m < 4; ++m)
#pragma unroll
      for (int n = 0; n < 4; ++n)
        acc[m][n] = __builtin_amdgcn_mfma_f32_16x16x32_bf16(af[m], bf[n], acc[m][n], 0, 0, 0);
    __syncthreads();
  }

#pragma unroll
  for (int m = 0; m < 4; ++m) {
#pragma unroll
    for (int n = 0; n < 4; ++n) {
      const int col = col0 + wc*64 + n*16 + fr;
      const float bb = HASBIAS ? bias[col] : 0.f;
#pragma unroll
      for (int r = 0; r < 4; ++r) {
        const int row = row0 + wr*64 + m*16 + fg*4 + r;
        C[(size_t)row*N + col] = acc[m][n][r]*alpha + bb;
      }
    }
  }
}

// ---------------------------------------------------------------------------
// K5: landmark attention (fp32 math), writes ctx as bf16.
// ---------------------------------------------------------------------------
__global__ __launch_bounds__(256) void attn_kernel(
    const float* __restrict__ qbuf, const float* __restrict__ kbuf,
    const float* __restrict__ vbuf, unsigned short* __restrict__ ctxb) {
  const int tid = threadIdx.x;
  const int s = blockIdx.x*256 + tid;
  const int h = blockIdx.y, b = blockIdx.z;
  __shared__ float4 K4[LM*16];
  __shared__ float4 V4[LM*16];
  for (int e = tid; e < LM*16; e += 256) {
    const int l = e >> 4, d4 = e & 15;
    const size_t base = ((size_t)(b*LM + l)*NHEAD + h)*HD + (d4 << 2);
    K4[e] = *(const float4*)(kbuf + base);
    V4[e] = *(const float4*)(vbuf + base);
  }
  __syncthreads();

  const float* qp = qbuf + ((size_t)(b*NS + s)*NHEAD + h)*HD;
  float4 q[16];
#pragma unroll
  for (int i = 0; i < 16; ++i) q[i] = ((const float4*)qp)[i];

  float sc[LM];
#pragma unroll
  for (int l = 0; l < LM; ++l) {
    float a = 0.f;
#pragma unroll
    for (int i = 0; i < 16; ++i) {
      const float4 kv = K4[l*16 + i];
      a += q[i].x*kv.x + q[i].y*kv.y + q[i].z*kv.z + q[i].w*kv.w;
    }
    sc[l] = a * 0.125f;
  }
  float mx = sc[0];
#pragma unroll
  for (int l = 1; l < LM; ++l) mx = fmaxf(mx, sc[l]);
  float sum = 0.f;
#pragma unroll
  for (int l = 0; l < LM; ++l) { sc[l] = expf(sc[l] - mx); sum += sc[l]; }
  const float inv = 1.f/sum;

  float4 o[16];
#pragma unroll
  for (int i = 0; i < 16; ++i) o[i] = make_float4(0.f,0.f,0.f,0.f);
#pragma unroll
  for (int l = 0; l < LM; ++l) {
    const float a = sc[l]*inv;
#pragma unroll
    for (int i = 0; i < 16; ++i) {
      const float4 vv = V4[l*16 + i];
      o[i].x += a*vv.x; o[i].y += a*vv.y; o[i].z += a*vv.z; o[i].w += a*vv.w;
    }
  }
  unsigned short* cp = ctxb + ((size_t)(b*NS + s)*NHEAD + h)*HD;
#pragma unroll
  for (int i = 0; i < 16; ++i) {
    us4 w;
    w.x = f2bf(o[i].x); w.y = f2bf(o[i].y); w.z = f2bf(o[i].z); w.w = f2bf(o[i].w);
    *(us4*)(cp + i*4) = w;
  }
}

// ---------------------------------------------------------------------------
// K8: per-token top-32 via 256-bin histogram selection (one block = one token,
// all 256 threads active) + softmax + weighted gather; out += gate * mem_out.
// Exact (value desc, idx asc) jax semantics: bins>B are definite members;
// boundary bin resolved by packed-key argmax for the remaining slots.
// ---------------------------------------------------------------------------
__global__ __launch_bounds__(256) void mem_kernel(
    const float* __restrict__ msc, const float* __restrict__ mvals,
    const float* __restrict__ gate, float* __restrict__ out) {
  const int token = blockIdx.x;
  const int tid = threadIdx.x;
  const int lane = tid & 63, wave = tid >> 6;

  __shared__ float s_wmax[4], s_wmin[4];
  __shared__ float s_maxv, s_minv, s_scale;
  __shared__ int   s_hist[256];
  __shared__ int   s_sfx[256];     // suffix counts: s_sfx[b] = #vals in bins >= b
  __shared__ int   s_B, s_cnt, s_nlist;
  __shared__ unsigned long long s_list[MS];
  __shared__ int   s_midx[KSEL];
  __shared__ float s_mval[KSEL];
  __shared__ float s_w[KSEL];

  const float v0 = msc[(size_t)token*MS + tid];
  const float v1 = msc[(size_t)token*MS + 256 + tid];

  // block min/max
  float mx = fmaxf(v0, v1), mn = fminf(v0, v1);
#pragma unroll
  for (int off = 32; off > 0; off >>= 1) {
    mx = fmaxf(mx, __shfl_xor(mx, off));
    mn = fminf(mn, __shfl_xor(mn, off));
  }
  if (lane == 0) { s_wmax[wave] = mx; s_wmin[wave] = mn; }
  s_hist[tid] = 0;
  __syncthreads();
  if (tid == 0) {
    float M = s_wmax[0], m = s_wmin[0];
    for (int w = 1; w < 4; ++w) { M = fmaxf(M, s_wmax[w]); m = fminf(m, s_wmin[w]); }
    s_maxv = M; s_minv = m;
    const float range = M - m;
    s_scale = (range > 1e-20f) ? 255.0f / range : 0.0f;
    s_cnt = 0; s_nlist = 0;
  }
  __syncthreads();
  const float scale = s_scale, smin = s_minv, smax = s_maxv;
  int b0 = (int)((v0 - smin) * scale); b0 = b0 > 255 ? 255 : b0;
  int b1 = (int)((v1 - smin) * scale); b1 = b1 > 255 ? 255 : b1;
  atomicAdd(&s_hist[b0], 1);
  atomicAdd(&s_hist[b1], 1);
  __syncthreads();
  // suffix sums (Hillis-Steele)
  s_sfx[tid] = s_hist[tid];
  __syncthreads();
  for (int s = 1; s < 256; s <<= 1) {
    const int t = (tid + s < 256) ? s_sfx[tid + s] : 0;
    __syncthreads();
    s_sfx[tid] += t;
    __syncthreads();
  }
  // crossing bin B: sfx[B] >= 32 > sfx[B+1]  (unique; sfx monotone nonincreasing)
  if (s_sfx[tid] >= KSEL && (tid == 255 || s_sfx[tid + 1] < KSEL)) s_B = tid;
  __syncthreads();
  const int B = s_B;
  // definite members (bins > B) -> selection; boundary bin -> candidate list
  const unsigned int u0 = __float_as_uint(v0);
  const unsigned int k0 = (u0 & 0x80000000u) ? ~u0 : (u0 | 0x80000000u);
  const unsigned int u1 = __float_as_uint(v1);
  const unsigned int k1 = (u1 & 0x80000000u) ? ~u1 : (u1 | 0x80000000u);
  if (b0 > B) {
    const int p = atomicAdd(&s_cnt, 1); s_midx[p] = tid; s_mval[p] = v0;
  } else if (b0 == B) {
    const int p = atomicAdd(&s_nlist, 1);
    s_list[p] = ((unsigned long long)k0 << 32) | (unsigned int)~tid;
  }
  if (b1 > B) {
    const int p = atomicAdd(&s_cnt, 1); s_midx[p] = 256 + tid; s_mval[p] = v1;
  } else if (b1 == B) {
    const int p = atomicAdd(&s_nlist, 1);
    s_list[p] = ((unsigned long long)k1 << 32) | (unsigned int)~(256u + tid);
  }
  __syncthreads();
  // wave 0 extracts the remaining (32 - above) largest from the boundary list
  if (wave == 0) {
    const int nl = s_nlist;
    const int above = s_cnt;
    const int rem = KSEL - above;
    for (int r = 0; r < rem; ++r) {
      unsigned long long best = 0; int pos = -1;
      for (int i = lane; i < nl; i += 64)
        if (s_list[i] > best) { best = s_list[i]; pos = i; }
#pragma unroll
      for (int off = 32; off > 0; off >>= 1) {
        const unsigned long long ob = __shfl_xor(best, off);
        const int op = __shfl_xor(pos, off);
        if (ob > best) { best = ob; pos = op; }
      }
      if (lane == 0) {
        s_list[pos] = 0;
        const unsigned int key = (unsigned int)(best >> 32);
        const unsigned int ub = (key & 0x80000000u) ? (key & 0x7fffffffu) : ~key;
        s_midx[above + r] = (int)(~(unsigned int)(best & 0xffffffffu));
        s_mval[above + r] = __uint_as_float(ub);
      }
    }
  }
  __syncthreads();
  // softmax over the 32 selected (smax = global max = rank-0 member)
  if (tid < KSEL) {
    const float e = expf(s_mval[tid] - smax);
    float tot = e;
#pragma unroll
    for (int off = 16; off > 0; off >>= 1) tot += __shfl_xor(tot, off);
    s_w[tid] = e / tot;
  }
  __syncthreads();
  // gather + epilogue
  const int d4 = tid << 2;
  float4 acc = make_float4(0.f, 0.f, 0.f, 0.f);
  for (int it = 0; it < KSEL; ++it) {
    const int m = s_midx[it];
    const float w = s_w[it];
    const float4 mv = *(const float4*)(mvals + (size_t)m*HDIM + d4);
    acc.x += w*mv.x; acc.y += w*mv.y; acc.z += w*mv.z; acc.w += w*mv.w;
  }
  const float g = gate[token];
  float4 cur = *(float4*)(out + (size_t)token*HDIM + d4);
  cur.x += g*acc.x; cur.y += g*acc.y; cur.z += g*acc.z; cur.w += g*acc.w;
  *(float4*)(out + (size_t)token*HDIM + d4) = cur;
}

// ---------------------------------------------------------------------------
extern "C" void kernel_launch(void* const* d_in, const int* in_sizes, int n_in,
                              void* d_out, int out_size, void* d_ws, size_t ws_size,
                              hipStream_t stream) {
  const float* hs = (const float*)d_in[0];
  const float* Wq = (const float*)d_in[1];
  const float* bq = (const float*)d_in[2];
  const float* Wk = (const float*)d_in[3];
  const float* bk = (const float*)d_in[4];
  const float* Wv = (const float*)d_in[5];
  const float* bv = (const float*)d_in[6];
  const float* Wo = (const float*)d_in[7];
  const float* bo = (const float*)d_in[8];
  const float* mk = (const float*)d_in[9];
  const float* mv = (const float*)d_in[10];
  const float* gw = (const float*)d_in[11];
  const float* gb = (const float*)d_in[12];
  float* out = (float*)d_out;

  char* ws = (char*)d_ws;
  unsigned short* hsb  = (unsigned short*)(ws);                       // 16 MiB [NTOK,HDIM] bf16
  float*          q    = (float*)(ws + ((size_t)16 << 20));           // 32 MiB [NTOK,HDIM] fp32
  unsigned short* ctxb = (unsigned short*)(ws + ((size_t)48 << 20));  // 16 MiB [NTOK,HDIM] bf16
  unsigned short* Wqt  = (unsigned short*)(ws + ((size_t)64 << 20));  // 2 MiB [N,K] bf16
  unsigned short* Wot  = (unsigned short*)(ws + ((size_t)66 << 20));  // 2 MiB
  unsigned short* mkb  = (unsigned short*)(ws + ((size_t)68 << 20));  // 1 MiB [MS,HDIM] bf16
  float*          kbuf = (float*)(ws + ((size_t)69 << 20));           // 512 KiB
  float*          vbuf = (float*)(ws + ((size_t)69 << 20) + ((size_t)512 << 10));
  float*          imp  = (float*)(ws + ((size_t)70 << 20));           // 32 KiB
  float*          gate = (float*)(ws + ((size_t)70 << 20) + ((size_t)32 << 10));
  int*            lmi  = (int*)  (ws + ((size_t)70 << 20) + ((size_t)64 << 10)); // 4 KiB
  int*            cnt  = (int*)  (ws + ((size_t)70 << 20) + ((size_t)68 << 10)); // 32 KiB
  float*          msc  = q;  // mem scores [NTOK,MS] alias q (q dead after attn)
  // K-split partials live in the q region (dead until gemm Q writes it):
  float*          partK = q;                        // 4 MiB [NB*8][LM][HDIM]
  float*          partV = q + (size_t)NB*8*LM*HDIM; // 4 MiB

  imp_gate_kernel<<<dim3(NTOK), 256, 0, stream>>>(hs, gw, gb, imp, gate, hsb);
  hipMemsetAsync(cnt, 0, NB*NS*sizeof(int), stream);
  lm_count_kernel<<<dim3(NS/256, 4, NB), 256, 0, stream>>>(imp, cnt);
  lm_sel_kernel<<<dim3(NS/256, NB), 256, 0, stream>>>(cnt, lmi);
  kv_proj_part_kernel<<<dim3(4, 8, 16), 256, 0, stream>>>(hs, lmi, Wk, Wv, partK, partV);
  kv_reduce_kernel<<<dim3(4, LM, NB), 256, 0, stream>>>(partK, partV, bk, bv, kbuf, vbuf);
  wtrans_kernel<<<dim3(32, 32), 256, 0, stream>>>(Wq, Wqt);
  wtrans_kernel<<<dim3(32, 32), 256, 0, stream>>>(Wo, Wot);
  conv_bf16_kernel<<<dim3(MS*HDIM/1024), 256, 0, stream>>>(mk, mkb);

  gemm_bf16_kernel<true><<<dim3(HDIM/128, NTOK/128), 256, 0, stream>>>(
      hsb, Wqt, bq, q, NTOK, HDIM, HDIM, 1.f);
  attn_kernel<<<dim3(NS/256, NHEAD, NB), 256, 0, stream>>>(q, kbuf, vbuf, ctxb);
  gemm_bf16_kernel<true><<<dim3(HDIM/128, NTOK/128), 256, 0, stream>>>(
      ctxb, Wot, bo, out, NTOK, HDIM, HDIM, 1.f);
  gemm_bf16_kernel<false><<<dim3(MS/128, NTOK/128), 256, 0, stream>>>(
      hsb, mkb, nullptr, msc, NTOK, MS, HDIM, 0.03125f);
  mem_kernel<<<dim3(NTOK), 256, 0, stream>>>(msc, mv, gate, out);
}

// Round 6
// 252.949 us; speedup vs baseline: 4.0266x; 1.1632x over previous
//
#include <hip/hip_runtime.h>
#include <math.h>

// Problem constants (from reference setup_inputs)
#define HDIM 1024
#define NHEAD 16
#define HD 64
#define LM 64          // NUM_LANDMARKS
#define MS 512         // memory slots
#define KSEL 32        // top_k
#define NB 2
#define NS 4096
#define NTOK (NB*NS)   // 8192

typedef __attribute__((ext_vector_type(8))) short short8;
typedef __attribute__((ext_vector_type(4))) float f32x4;
typedef __attribute__((ext_vector_type(4))) unsigned short us4;

__device__ __forceinline__ unsigned short f2bf(float f) {
  unsigned int u = __float_as_uint(f);
  unsigned int r = (u + 0x7fffu + ((u >> 16) & 1u)) >> 16;
  return (unsigned short)r;
}

__device__ __forceinline__ void gload_lds16(const unsigned short* g, unsigned short* l) {
  __builtin_amdgcn_global_load_lds(
      (const __attribute__((address_space(1))) unsigned int*)g,
      (__attribute__((address_space(3))) unsigned int*)l,
      16, 0, 0);
}

// ---------------------------------------------------------------------------
// K1: per-token importance (sum sq) + gate scalar + hs -> bf16 conversion
// ---------------------------------------------------------------------------
__global__ __launch_bounds__(256) void imp_gate_kernel(
    const float* __restrict__ hs, const float* __restrict__ gw,
    const float* __restrict__ gb, float* __restrict__ imp,
    float* __restrict__ gate, unsigned short* __restrict__ hsb) {
  const int row = blockIdx.x;
  const int tid = threadIdx.x;
  const float4 hv = *(const float4*)(hs + (size_t)row*HDIM + tid*4);
  const float4 gv = *(const float4*)(gw + tid*4);
  us4 hb;
  hb.x = f2bf(hv.x); hb.y = f2bf(hv.y); hb.z = f2bf(hv.z); hb.w = f2bf(hv.w);
  *(us4*)(hsb + (size_t)row*HDIM + tid*4) = hb;
  float ss = hv.x*hv.x + hv.y*hv.y + hv.z*hv.z + hv.w*hv.w;
  float dg = hv.x*gv.x + hv.y*gv.y + hv.z*gv.z + hv.w*gv.w;
  __shared__ float sss[256], sdg[256];
  sss[tid] = ss; sdg[tid] = dg;
  __syncthreads();
  for (int s = 128; s > 0; s >>= 1) {
    if (tid < s) { sss[tid] += sss[tid+s]; sdg[tid] += sdg[tid+s]; }
    __syncthreads();
  }
  if (tid == 0) {
    imp[row] = sss[0];
    gate[row] = 1.f/(1.f + expf(-(sdg[0] + gb[0])));
  }
}

// ---------------------------------------------------------------------------
// K2a: rank counting, parallel over (candidate, j-chunk).
// rank(i) = #{j : v[j] > v[i]  or  (v[j]==v[i] and j<i)}  (jax tie-break).
// ---------------------------------------------------------------------------
__global__ __launch_bounds__(256) void lm_count_kernel(
    const float* __restrict__ imp, int* __restrict__ cnt) {
  const int b = blockIdx.z;
  const int jc = blockIdx.y;
  const int i = blockIdx.x*256 + threadIdx.x;
  const float* v = imp + b*NS;
  const float mine = v[i];
  __shared__ float tile[1024];
  const int j0 = jc*1024;
  *(float4*)&tile[threadIdx.x*4] = *(const float4*)&v[j0 + threadIdx.x*4];
  __syncthreads();
  int c = 0;
#pragma unroll 8
  for (int p = 0; p < 1024; p += 4) {
    const float4 t = *(const float4*)&tile[p];
    c += (t.x > mine) || (t.x == mine && (j0+p+0) < i);
    c += (t.y > mine) || (t.y == mine && (j0+p+1) < i);
    c += (t.z > mine) || (t.z == mine && (j0+p+2) < i);
    c += (t.w > mine) || (t.w == mine && (j0+p+3) < i);
  }
  atomicAdd(&cnt[b*NS + i], c);
}

// K2b: scatter selected candidates (set only; order irrelevant downstream).
__global__ __launch_bounds__(256) void lm_sel_kernel(
    const int* __restrict__ cnt, int* __restrict__ lm_idx) {
  const int b = blockIdx.y;
  const int i = blockIdx.x*256 + threadIdx.x;
  const int c = cnt[b*NS + i];
  if (c < LM) lm_idx[b*LM + c] = i;
}

// ---------------------------------------------------------------------------
// K3a: gather + K/V projection, K-split into 8 chunks of 128 for parallelism.
// ---------------------------------------------------------------------------
__global__ __launch_bounds__(256) void kv_proj_part_kernel(
    const float* __restrict__ hs, const int* __restrict__ lm_idx,
    const float* __restrict__ Wk, const float* __restrict__ Wv,
    float* __restrict__ partK, float* __restrict__ partV) {
  const int cq = blockIdx.x, lg = blockIdx.y, zz = blockIdx.z;
  const int b = zz >> 3, s = zz & 7;
  const int tid = threadIdx.x;
  __shared__ float rows[8][128];
  __shared__ int sidx[8];
  if (tid < 8) sidx[tid] = lm_idx[b*LM + lg*8 + tid];
  __syncthreads();
  for (int e = tid; e < 8*128; e += 256) {
    const int r = e >> 7, kk = e & 127;
    rows[r][kk] = hs[((size_t)b*NS + sidx[r])*HDIM + s*128 + kk];
  }
  __syncthreads();
  const int col = cq*256 + tid;
  float ak[8] = {0,0,0,0,0,0,0,0};
  float av[8] = {0,0,0,0,0,0,0,0};
#pragma unroll 4
  for (int kk = 0; kk < 128; ++kk) {
    const float wk = Wk[(size_t)(s*128 + kk)*HDIM + col];
    const float wv = Wv[(size_t)(s*128 + kk)*HDIM + col];
#pragma unroll
    for (int r = 0; r < 8; ++r) {
      const float h = rows[r][kk];
      ak[r] += h*wk;
      av[r] += h*wv;
    }
  }
#pragma unroll
  for (int r = 0; r < 8; ++r) {
    const size_t o = ((size_t)zz*LM + lg*8 + r)*HDIM + col;
    partK[o] = ak[r];
    partV[o] = av[r];
  }
}

// K3b: reduce the 8 K-split partials + bias -> kbuf/vbuf. grid (4, LM, NB).
__global__ __launch_bounds__(256) void kv_reduce_kernel(
    const float* __restrict__ partK, const float* __restrict__ partV,
    const float* __restrict__ bk, const float* __restrict__ bv,
    float* __restrict__ kbuf, float* __restrict__ vbuf) {
  const int cq = blockIdx.x, l = blockIdx.y, b = blockIdx.z;
  const int col = cq*256 + threadIdx.x;
  float sk = bk[col], sv = bv[col];
#pragma unroll
  for (int s = 0; s < 8; ++s) {
    const size_t o = ((size_t)(b*8 + s)*LM + l)*HDIM + col;
    sk += partK[o];
    sv += partV[o];
  }
  const size_t o = ((size_t)b*LM + l)*HDIM + col;
  kbuf[o] = sk;
  vbuf[o] = sv;
}

// ---------------------------------------------------------------------------
// Prep: transpose+convert weight W[K][N] fp32 -> Wt[N][K] bf16  (1024x1024)
// ---------------------------------------------------------------------------
__global__ __launch_bounds__(256) void wtrans_kernel(
    const float* __restrict__ W, unsigned short* __restrict__ Wt) {
  __shared__ float tile[32][33];
  const int tx = threadIdx.x & 31, ty = threadIdx.x >> 5;
  const int bx = blockIdx.x * 32, by = blockIdx.y * 32;
#pragma unroll
  for (int i = 0; i < 32; i += 8)
    tile[ty + i][tx] = W[(size_t)(by + ty + i)*HDIM + bx + tx];
  __syncthreads();
#pragma unroll
  for (int i = 0; i < 32; i += 8)
    Wt[(size_t)(bx + ty + i)*HDIM + by + tx] = f2bf(tile[tx][ty + i]);
}

// ---------------------------------------------------------------------------
// Prep: elementwise fp32 -> bf16 (mem_keys, already [N][K] layout)
// ---------------------------------------------------------------------------
__global__ __launch_bounds__(256) void conv_bf16_kernel(
    const float* __restrict__ in, unsigned short* __restrict__ out) {
  const int i = (blockIdx.x*256 + threadIdx.x)*4;
  const float4 v = *(const float4*)&in[i];
  us4 w;
  w.x = f2bf(v.x); w.y = f2bf(v.y); w.z = f2bf(v.z); w.w = f2bf(v.w);
  *(us4*)&out[i] = w;
}

// ---------------------------------------------------------------------------
// bf16 MFMA GEMM (m97 structure): C[M,N] = alpha*(A @ Bt^T) (+ bias)
// OUTBF: write C as bf16 instead of fp32.
// ---------------------------------------------------------------------------
template<bool HASBIAS, bool OUTBF>
__global__ __launch_bounds__(256) void gemm_bf16_kernel(
    const unsigned short* __restrict__ A, const unsigned short* __restrict__ Bt,
    const float* __restrict__ bias, void* __restrict__ Cv,
    int M, int N, int K, float alpha) {
  __shared__ __align__(16) unsigned short As[128*32];
  __shared__ __align__(16) unsigned short Bs[128*32];
  const int tid = threadIdx.x;
  const int lane = tid & 63, wave = tid >> 6;
  const int wr = wave >> 1, wc = wave & 1;
  const int row0 = blockIdx.y << 7, col0 = blockIdx.x << 7;

  f32x4 acc[4][4];
#pragma unroll
  for (int m = 0; m < 4; ++m)
#pragma unroll
    for (int n = 0; n < 4; ++n)
      acc[m][n] = (f32x4)(0.f);

  const int srow = tid >> 2;
  const int sk   = (tid & 3) << 3;
  const unsigned short* gA = A  + (size_t)(row0 + srow)*K + sk;
  const unsigned short* gB = Bt + (size_t)(col0 + srow)*K + sk;
  const int fr = lane & 15;
  const int fk = (lane >> 4) << 3;
  const int fg = lane >> 4;

  for (int k0 = 0; k0 < K; k0 += 32) {
    gload_lds16(gA + k0,          As + tid*8);
    gload_lds16(gA + 64*K + k0,   As + 2048 + tid*8);
    gload_lds16(gB + k0,          Bs + tid*8);
    gload_lds16(gB + 64*K + k0,   Bs + 2048 + tid*8);
    __syncthreads();
    short8 af[4], bf[4];
#pragma unroll
    for (int m = 0; m < 4; ++m)
      af[m] = *(const short8*)&As[(wr*64 + m*16 + fr)*32 + fk];
#pragma unroll
    for (int n = 0; n < 4; ++n)
      bf[n] = *(const short8*)&Bs[(wc*64 + n*16 + fr)*32 + fk];
#pragma unroll
    for (int m = 0; m < 4; ++m)
#pragma unroll
      for (int n = 0; n < 4; ++n)
        acc[m][n] = __builtin_amdgcn_mfma_f32_16x16x32_bf16(af[m], bf[n], acc[m][n], 0, 0, 0);
    __syncthreads();
  }

#pragma unroll
  for (int m = 0; m < 4; ++m) {
#pragma unroll
    for (int n = 0; n < 4; ++n) {
      const int col = col0 + wc*64 + n*16 + fr;
      const float bb = HASBIAS ? bias[col] : 0.f;
#pragma unroll
      for (int r = 0; r < 4; ++r) {
        const int row = row0 + wr*64 + m*16 + fg*4 + r;
        const float val = acc[m][n][r]*alpha + bb;
        if (OUTBF) ((unsigned short*)Cv)[(size_t)row*N + col] = f2bf(val);
        else       ((float*)Cv)[(size_t)row*N + col] = val;
      }
    }
  }
}

// ---------------------------------------------------------------------------
// K5: MFMA landmark attention. Block = 128 tokens x 1 head; 4 waves x 32 rows.
// QK^T and PV on matrix cores (bf16 in, fp32 accum); softmax in-register via
// 16-lane shfl groups (C/D layout: col=lane&15, row=(lane>>4)*4+reg).
// ---------------------------------------------------------------------------
__global__ __launch_bounds__(256) void attn_mfma_kernel(
    const unsigned short* __restrict__ qb, const float* __restrict__ kbuf,
    const float* __restrict__ vbuf, unsigned short* __restrict__ ctxb) {
  const int tb = blockIdx.x, h = blockIdx.y, b = blockIdx.z;
  const int tid = threadIdx.x;
  const int lane = tid & 63, wave = tid >> 6;
  __shared__ __align__(16) unsigned short Qs[128*64];  // 16 KiB
  __shared__ __align__(16) unsigned short Ks[64*64];   //  8 KiB
  __shared__ __align__(16) unsigned short Vt[64*64];   //  8 KiB [d][l]
  __shared__ __align__(16) unsigned short Ps[128*64];  // 16 KiB

  const int tok0 = b*NS + tb*128;
  // stage Q (bf16): lane-linear LDS dest (idx*8 elements = idx*16 bytes)
#pragma unroll
  for (int it = 0; it < 4; ++it) {
    const int idx = it*256 + tid;
    gload_lds16(qb + (size_t)(tok0 + (idx >> 3))*HDIM + h*64 + (idx & 7)*8,
                Qs + idx*8);
  }
  // stage K and V^T (fp32 -> bf16); coalesced float4 reads
#pragma unroll
  for (int it = 0; it < 4; ++it) {
    const int i = it*256 + tid;              // float4 index, 0..1023
    const int l = i >> 4, d0 = (i & 15) << 2;
    const size_t base = (size_t)(b*LM + l)*HDIM + h*64 + d0;
    const float4 kv = *(const float4*)(kbuf + base);
    const float4 vv = *(const float4*)(vbuf + base);
    us4 k4; k4.x = f2bf(kv.x); k4.y = f2bf(kv.y); k4.z = f2bf(kv.z); k4.w = f2bf(kv.w);
    *(us4*)&Ks[l*64 + d0] = k4;
    Vt[(d0+0)*64 + l] = f2bf(vv.x);
    Vt[(d0+1)*64 + l] = f2bf(vv.y);
    Vt[(d0+2)*64 + l] = f2bf(vv.z);
    Vt[(d0+3)*64 + l] = f2bf(vv.w);
  }
  __syncthreads();

  const int fr = lane & 15;
  const int fg = lane >> 4;
  const int fk = fg << 3;
  const int wrow = wave*32;

  // QK^T: scores [32 rows][64 landmarks] per wave
  f32x4 acc[2][4];
#pragma unroll
  for (int m = 0; m < 2; ++m)
#pragma unroll
    for (int n = 0; n < 4; ++n) acc[m][n] = (f32x4)(0.f);
#pragma unroll
  for (int ks = 0; ks < 2; ++ks) {
    short8 af[2], bf[4];
#pragma unroll
    for (int m = 0; m < 2; ++m)
      af[m] = *(const short8*)&Qs[(wrow + m*16 + fr)*64 + ks*32 + fk];
#pragma unroll
    for (int n = 0; n < 4; ++n)
      bf[n] = *(const short8*)&Ks[(n*16 + fr)*64 + ks*32 + fk];
#pragma unroll
    for (int m = 0; m < 2; ++m)
#pragma unroll
      for (int n = 0; n < 4; ++n)
        acc[m][n] = __builtin_amdgcn_mfma_f32_16x16x32_bf16(af[m], bf[n], acc[m][n], 0, 0, 0);
  }

  // in-register row softmax; write P (bf16) to LDS
#pragma unroll
  for (int m = 0; m < 2; ++m) {
#pragma unroll
    for (int r = 0; r < 4; ++r) {
      float p0 = acc[m][0][r]*0.125f, p1 = acc[m][1][r]*0.125f;
      float p2 = acc[m][2][r]*0.125f, p3 = acc[m][3][r]*0.125f;
      float mx = fmaxf(fmaxf(p0, p1), fmaxf(p2, p3));
#pragma unroll
      for (int off = 1; off < 16; off <<= 1) mx = fmaxf(mx, __shfl_xor(mx, off));
      p0 = expf(p0 - mx); p1 = expf(p1 - mx); p2 = expf(p2 - mx); p3 = expf(p3 - mx);
      float sm = p0 + p1 + p2 + p3;
#pragma unroll
      for (int off = 1; off < 16; off <<= 1) sm += __shfl_xor(sm, off);
      const float inv = 1.f/sm;
      const int prow = (wrow + m*16 + fg*4 + r)*64;
      Ps[prow + 0*16 + fr] = f2bf(p0*inv);
      Ps[prow + 1*16 + fr] = f2bf(p1*inv);
      Ps[prow + 2*16 + fr] = f2bf(p2*inv);
      Ps[prow + 3*16 + fr] = f2bf(p3*inv);
    }
  }
  __syncthreads();

  // PV: ctx [32 rows][64 dims] per wave
  f32x4 occ[2][4];
#pragma unroll
  for (int m = 0; m < 2; ++m)
#pragma unroll
    for (int n = 0; n < 4; ++n) occ[m][n] = (f32x4)(0.f);
#pragma unroll
  for (int ks = 0; ks < 2; ++ks) {
    short8 af[2], bf[4];
#pragma unroll
    for (int m = 0; m < 2; ++m)
      af[m] = *(const short8*)&Ps[(wrow + m*16 + fr)*64 + ks*32 + fk];
#pragma unroll
    for (int n = 0; n < 4; ++n)
      bf[n] = *(const short8*)&Vt[(n*16 + fr)*64 + ks*32 + fk];
#pragma unroll
    for (int m = 0; m < 2; ++m)
#pragma unroll
      for (int n = 0; n < 4; ++n)
        occ[m][n] = __builtin_amdgcn_mfma_f32_16x16x32_bf16(af[m], bf[n], occ[m][n], 0, 0, 0);
  }
#pragma unroll
  for (int m = 0; m < 2; ++m)
#pragma unroll
    for (int n = 0; n < 4; ++n)
#pragma unroll
      for (int r = 0; r < 4; ++r)
        ctxb[(size_t)(tok0 + wrow + m*16 + fg*4 + r)*HDIM + h*64 + n*16 + fr] =
            f2bf(occ[m][n][r]);
}

// ---------------------------------------------------------------------------
// K8: per-token top-32 via 256-bin histogram selection + softmax + gather;
// out += gate * mem_out.
// ---------------------------------------------------------------------------
__global__ __launch_bounds__(256) void mem_kernel(
    const float* __restrict__ msc, const float* __restrict__ mvals,
    const float* __restrict__ gate, float* __restrict__ out) {
  const int token = blockIdx.x;
  const int tid = threadIdx.x;
  const int lane = tid & 63, wave = tid >> 6;

  __shared__ float s_wmax[4], s_wmin[4];
  __shared__ float s_maxv, s_minv, s_scale;
  __shared__ int   s_hist[256];
  __shared__ int   s_sfx[256];
  __shared__ int   s_B, s_cnt, s_nlist;
  __shared__ unsigned long long s_list[MS];
  __shared__ int   s_midx[KSEL];
  __shared__ float s_mval[KSEL];
  __shared__ float s_w[KSEL];

  const float v0 = msc[(size_t)token*MS + tid];
  const float v1 = msc[(size_t)token*MS + 256 + tid];

  float mx = fmaxf(v0, v1), mn = fminf(v0, v1);
#pragma unroll
  for (int off = 32; off > 0; off >>= 1) {
    mx = fmaxf(mx, __shfl_xor(mx, off));
    mn = fminf(mn, __shfl_xor(mn, off));
  }
  if (lane == 0) { s_wmax[wave] = mx; s_wmin[wave] = mn; }
  s_hist[tid] = 0;
  __syncthreads();
  if (tid == 0) {
    float M = s_wmax[0], m = s_wmin[0];
    for (int w = 1; w < 4; ++w) { M = fmaxf(M, s_wmax[w]); m = fminf(m, s_wmin[w]); }
    s_maxv = M; s_minv = m;
    const float range = M - m;
    s_scale = (range > 1e-20f) ? 255.0f / range : 0.0f;
    s_cnt = 0; s_nlist = 0;
  }
  __syncthreads();
  const float scale = s_scale, smin = s_minv, smax = s_maxv;
  int b0 = (int)((v0 - smin) * scale); b0 = b0 > 255 ? 255 : b0;
  int b1 = (int)((v1 - smin) * scale); b1 = b1 > 255 ? 255 : b1;
  atomicAdd(&s_hist[b0], 1);
  atomicAdd(&s_hist[b1], 1);
  __syncthreads();
  s_sfx[tid] = s_hist[tid];
  __syncthreads();
  for (int s = 1; s < 256; s <<= 1) {
    const int t = (tid + s < 256) ? s_sfx[tid + s] : 0;
    __syncthreads();
    s_sfx[tid] += t;
    __syncthreads();
  }
  if (s_sfx[tid] >= KSEL && (tid == 255 || s_sfx[tid + 1] < KSEL)) s_B = tid;
  __syncthreads();
  const int B = s_B;
  const unsigned int u0 = __float_as_uint(v0);
  const unsigned int k0 = (u0 & 0x80000000u) ? ~u0 : (u0 | 0x80000000u);
  const unsigned int u1 = __float_as_uint(v1);
  const unsigned int k1 = (u1 & 0x80000000u) ? ~u1 : (u1 | 0x80000000u);
  if (b0 > B) {
    const int p = atomicAdd(&s_cnt, 1); s_midx[p] = tid; s_mval[p] = v0;
  } else if (b0 == B) {
    const int p = atomicAdd(&s_nlist, 1);
    s_list[p] = ((unsigned long long)k0 << 32) | (unsigned int)~tid;
  }
  if (b1 > B) {
    const int p = atomicAdd(&s_cnt, 1); s_midx[p] = 256 + tid; s_mval[p] = v1;
  } else if (b1 == B) {
    const int p = atomicAdd(&s_nlist, 1);
    s_list[p] = ((unsigned long long)k1 << 32) | (unsigned int)~(256u + tid);
  }
  __syncthreads();
  if (wave == 0) {
    const int nl = s_nlist;
    const int above = s_cnt;
    const int rem = KSEL - above;
    for (int r = 0; r < rem; ++r) {
      unsigned long long best = 0; int pos = -1;
      for (int i = lane; i < nl; i += 64)
        if (s_list[i] > best) { best = s_list[i]; pos = i; }
#pragma unroll
      for (int off = 32; off > 0; off >>= 1) {
        const unsigned long long ob = __shfl_xor(best, off);
        const int op = __shfl_xor(pos, off);
        if (ob > best) { best = ob; pos = op; }
      }
      if (lane == 0) {
        s_list[pos] = 0;
        const unsigned int key = (unsigned int)(best >> 32);
        const unsigned int ub = (key & 0x80000000u) ? (key & 0x7fffffffu) : ~key;
        s_midx[above + r] = (int)(~(unsigned int)(best & 0xffffffffu));
        s_mval[above + r] = __uint_as_float(ub);
      }
    }
  }
  __syncthreads();
  if (tid < KSEL) {
    const float e = expf(s_mval[tid] - smax);
    float tot = e;
#pragma unroll
    for (int off = 16; off > 0; off >>= 1) tot += __shfl_xor(tot, off);
    s_w[tid] = e / tot;
  }
  __syncthreads();
  const int d4 = tid << 2;
  float4 acc = make_float4(0.f, 0.f, 0.f, 0.f);
  for (int it = 0; it < KSEL; ++it) {
    const int m = s_midx[it];
    const float w = s_w[it];
    const float4 mv = *(const float4*)(mvals + (size_t)m*HDIM + d4);
    acc.x += w*mv.x; acc.y += w*mv.y; acc.z += w*mv.z; acc.w += w*mv.w;
  }
  const float g = gate[token];
  float4 cur = *(float4*)(out + (size_t)token*HDIM + d4);
  cur.x += g*acc.x; cur.y += g*acc.y; cur.z += g*acc.z; cur.w += g*acc.w;
  *(float4*)(out + (size_t)token*HDIM + d4) = cur;
}

// ---------------------------------------------------------------------------
extern "C" void kernel_launch(void* const* d_in, const int* in_sizes, int n_in,
                              void* d_out, int out_size, void* d_ws, size_t ws_size,
                              hipStream_t stream) {
  const float* hs = (const float*)d_in[0];
  const float* Wq = (const float*)d_in[1];
  const float* bq = (const float*)d_in[2];
  const float* Wk = (const float*)d_in[3];
  const float* bk = (const float*)d_in[4];
  const float* Wv = (const float*)d_in[5];
  const float* bv = (const float*)d_in[6];
  const float* Wo = (const float*)d_in[7];
  const float* bo = (const float*)d_in[8];
  const float* mk = (const float*)d_in[9];
  const float* mv = (const float*)d_in[10];
  const float* gw = (const float*)d_in[11];
  const float* gb = (const float*)d_in[12];
  float* out = (float*)d_out;

  char* ws = (char*)d_ws;
  unsigned short* hsb  = (unsigned short*)(ws);                       // 16 MiB [NTOK,HDIM] bf16
  unsigned short* qb   = (unsigned short*)(ws + ((size_t)16 << 20));  // 16 MiB [NTOK,HDIM] bf16
  unsigned short* ctxb = (unsigned short*)(ws + ((size_t)32 << 20));  // 16 MiB [NTOK,HDIM] bf16
  float*          msc  = (float*)(ws + ((size_t)48 << 20));           // 16 MiB [NTOK,MS] fp32
  unsigned short* Wqt  = (unsigned short*)(ws + ((size_t)64 << 20));  // 2 MiB
  unsigned short* Wot  = (unsigned short*)(ws + ((size_t)66 << 20));  // 2 MiB
  unsigned short* mkb  = (unsigned short*)(ws + ((size_t)68 << 20));  // 1 MiB
  float*          kbuf = (float*)(ws + ((size_t)69 << 20));           // 512 KiB
  float*          vbuf = (float*)(ws + ((size_t)69 << 20) + ((size_t)512 << 10));
  float*          imp  = (float*)(ws + ((size_t)70 << 20));           // 32 KiB
  float*          gate = (float*)(ws + ((size_t)70 << 20) + ((size_t)32 << 10));
  int*            lmi  = (int*)  (ws + ((size_t)70 << 20) + ((size_t)64 << 10)); // 4 KiB
  int*            cnt  = (int*)  (ws + ((size_t)70 << 20) + ((size_t)68 << 10)); // 32 KiB
  // K-split partials alias the msc region (dead until the mem-score GEMM):
  float*          partK = msc;                        // 4 MiB [NB*8][LM][HDIM]
  float*          partV = msc + (size_t)NB*8*LM*HDIM; // 4 MiB

  imp_gate_kernel<<<dim3(NTOK), 256, 0, stream>>>(hs, gw, gb, imp, gate, hsb);
  hipMemsetAsync(cnt, 0, NB*NS*sizeof(int), stream);
  lm_count_kernel<<<dim3(NS/256, 4, NB), 256, 0, stream>>>(imp, cnt);
  lm_sel_kernel<<<dim3(NS/256, NB), 256, 0, stream>>>(cnt, lmi);
  kv_proj_part_kernel<<<dim3(4, 8, 16), 256, 0, stream>>>(hs, lmi, Wk, Wv, partK, partV);
  kv_reduce_kernel<<<dim3(4, LM, NB), 256, 0, stream>>>(partK, partV, bk, bv, kbuf, vbuf);
  wtrans_kernel<<<dim3(32, 32), 256, 0, stream>>>(Wq, Wqt);
  wtrans_kernel<<<dim3(32, 32), 256, 0, stream>>>(Wo, Wot);
  conv_bf16_kernel<<<dim3(MS*HDIM/1024), 256, 0, stream>>>(mk, mkb);

  gemm_bf16_kernel<true, true><<<dim3(HDIM/128, NTOK/128), 256, 0, stream>>>(
      hsb, Wqt, bq, qb, NTOK, HDIM, HDIM, 1.f);
  attn_mfma_kernel<<<dim3(NS/128, NHEAD, NB), 256, 0, stream>>>(qb, kbuf, vbuf, ctxb);
  gemm_bf16_kernel<true, false><<<dim3(HDIM/128, NTOK/128), 256, 0, stream>>>(
      ctxb, Wot, bo, out, NTOK, HDIM, HDIM, 1.f);
  gemm_bf16_kernel<false, false><<<dim3(MS/128, NTOK/128), 256, 0, stream>>>(
      hsb, mkb, nullptr, msc, NTOK, MS, HDIM, 0.03125f);
  mem_kernel<<<dim3(NTOK), 256, 0, stream>>>(msc, mv, gate, out);
}

// Round 7
// 224.056 us; speedup vs baseline: 4.5458x; 1.1290x over previous
//
#include <hip/hip_runtime.h>
#include <math.h>

// Problem constants (from reference setup_inputs)
#define HDIM 1024
#define NHEAD 16
#define HD 64
#define LM 64          // NUM_LANDMARKS
#define MS 512         // memory slots
#define KSEL 32        // top_k
#define NB 2
#define NS 4096
#define NTOK (NB*NS)   // 8192

typedef __attribute__((ext_vector_type(8))) short short8;
typedef __attribute__((ext_vector_type(4))) float f32x4;
typedef __attribute__((ext_vector_type(4))) unsigned short us4;

__device__ __forceinline__ unsigned short f2bf(float f) {
  unsigned int u = __float_as_uint(f);
  unsigned int r = (u + 0x7fffu + ((u >> 16) & 1u)) >> 16;
  return (unsigned short)r;
}
__device__ __forceinline__ float bf2f(unsigned short u) {
  return __uint_as_float(((unsigned int)u) << 16);
}

__device__ __forceinline__ void gload_lds16(const unsigned short* g, unsigned short* l) {
  __builtin_amdgcn_global_load_lds(
      (const __attribute__((address_space(1))) unsigned int*)g,
      (__attribute__((address_space(3))) unsigned int*)l,
      16, 0, 0);
}

// ---------------------------------------------------------------------------
// K1: per-token importance (sum sq) + gate scalar + hs -> bf16 conversion
// ---------------------------------------------------------------------------
__global__ __launch_bounds__(256) void imp_gate_kernel(
    const float* __restrict__ hs, const float* __restrict__ gw,
    const float* __restrict__ gb, float* __restrict__ imp,
    float* __restrict__ gate, unsigned short* __restrict__ hsb) {
  const int row = blockIdx.x;
  const int tid = threadIdx.x;
  const float4 hv = *(const float4*)(hs + (size_t)row*HDIM + tid*4);
  const float4 gv = *(const float4*)(gw + tid*4);
  us4 hb;
  hb.x = f2bf(hv.x); hb.y = f2bf(hv.y); hb.z = f2bf(hv.z); hb.w = f2bf(hv.w);
  *(us4*)(hsb + (size_t)row*HDIM + tid*4) = hb;
  float ss = hv.x*hv.x + hv.y*hv.y + hv.z*hv.z + hv.w*hv.w;
  float dg = hv.x*gv.x + hv.y*gv.y + hv.z*gv.z + hv.w*gv.w;
  __shared__ float sss[256], sdg[256];
  sss[tid] = ss; sdg[tid] = dg;
  __syncthreads();
  for (int s = 128; s > 0; s >>= 1) {
    if (tid < s) { sss[tid] += sss[tid+s]; sdg[tid] += sdg[tid+s]; }
    __syncthreads();
  }
  if (tid == 0) {
    imp[row] = sss[0];
    gate[row] = 1.f/(1.f + expf(-(sdg[0] + gb[0])));
  }
}

// ---------------------------------------------------------------------------
// K2a: rank counting, parallel over (candidate, j-chunk).
// rank(i) = #{j : v[j] > v[i]  or  (v[j]==v[i] and j<i)}  (jax tie-break).
// ---------------------------------------------------------------------------
__global__ __launch_bounds__(256) void lm_count_kernel(
    const float* __restrict__ imp, int* __restrict__ cnt) {
  const int b = blockIdx.z;
  const int jc = blockIdx.y;
  const int i = blockIdx.x*256 + threadIdx.x;
  const float* v = imp + b*NS;
  const float mine = v[i];
  __shared__ float tile[1024];
  const int j0 = jc*1024;
  *(float4*)&tile[threadIdx.x*4] = *(const float4*)&v[j0 + threadIdx.x*4];
  __syncthreads();
  int c = 0;
#pragma unroll 8
  for (int p = 0; p < 1024; p += 4) {
    const float4 t = *(const float4*)&tile[p];
    c += (t.x > mine) || (t.x == mine && (j0+p+0) < i);
    c += (t.y > mine) || (t.y == mine && (j0+p+1) < i);
    c += (t.z > mine) || (t.z == mine && (j0+p+2) < i);
    c += (t.w > mine) || (t.w == mine && (j0+p+3) < i);
  }
  atomicAdd(&cnt[b*NS + i], c);
}

// K2b: scatter selected candidates (set only; order irrelevant downstream).
__global__ __launch_bounds__(256) void lm_sel_kernel(
    const int* __restrict__ cnt, int* __restrict__ lm_idx) {
  const int b = blockIdx.y;
  const int i = blockIdx.x*256 + threadIdx.x;
  const int c = cnt[b*NS + i];
  if (c < LM) lm_idx[b*LM + c] = i;
}

// ---------------------------------------------------------------------------
// K3a: gather 128 landmark rows (bf16) into compact g[NB*LM][HDIM]
// ---------------------------------------------------------------------------
__global__ __launch_bounds__(256) void lm_gather_kernel(
    const unsigned short* __restrict__ hsb, const int* __restrict__ lmi,
    unsigned short* __restrict__ g) {
  const int j = blockIdx.x;           // 0..127 = b*LM + l
  const int b = j >> 6;
  const int idx = lmi[j];
  const us4 v = *(const us4*)(hsb + ((size_t)(b*NS + idx))*HDIM + threadIdx.x*4);
  *(us4*)(g + (size_t)j*HDIM + threadIdx.x*4) = v;
}

// ---------------------------------------------------------------------------
// K3b: K/V projection as bf16 MFMA GEMM, split-K=4.
// C[128][2048] = g[128][1024] @ Wkvt[2048][1024]^T ; partials fp32.
// grid (16 col-blocks, 4 K-splits); m97 structure, row0 = 0.
// ---------------------------------------------------------------------------
__global__ __launch_bounds__(256) void kvproj_gemm_kernel(
    const unsigned short* __restrict__ g, const unsigned short* __restrict__ Wkvt,
    float* __restrict__ part) {
  __shared__ __align__(16) unsigned short As[128*32];
  __shared__ __align__(16) unsigned short Bs[128*32];
  const int tid = threadIdx.x;
  const int lane = tid & 63, wave = tid >> 6;
  const int wr = wave >> 1, wc = wave & 1;
  const int col0 = blockIdx.x << 7;
  const int sp = blockIdx.y;
  const int k00 = sp << 8;            // 256-wide K chunk

  f32x4 acc[4][4];
#pragma unroll
  for (int m = 0; m < 4; ++m)
#pragma unroll
    for (int n = 0; n < 4; ++n) acc[m][n] = (f32x4)(0.f);

  const int srow = tid >> 2;
  const int sk   = (tid & 3) << 3;
  const unsigned short* gA = g    + (size_t)srow*HDIM + sk;
  const unsigned short* gB = Wkvt + (size_t)(col0 + srow)*HDIM + sk;
  const int fr = lane & 15;
  const int fk = (lane >> 4) << 3;
  const int fg = lane >> 4;

  for (int k0 = k00; k0 < k00 + 256; k0 += 32) {
    gload_lds16(gA + k0,             As + tid*8);
    gload_lds16(gA + 64*HDIM + k0,   As + 2048 + tid*8);
    gload_lds16(gB + k0,             Bs + tid*8);
    gload_lds16(gB + 64*HDIM + k0,   Bs + 2048 + tid*8);
    __syncthreads();
    short8 af[4], bf[4];
#pragma unroll
    for (int m = 0; m < 4; ++m)
      af[m] = *(const short8*)&As[(wr*64 + m*16 + fr)*32 + fk];
#pragma unroll
    for (int n = 0; n < 4; ++n)
      bf[n] = *(const short8*)&Bs[(wc*64 + n*16 + fr)*32 + fk];
#pragma unroll
    for (int m = 0; m < 4; ++m)
#pragma unroll
      for (int n = 0; n < 4; ++n)
        acc[m][n] = __builtin_amdgcn_mfma_f32_16x16x32_bf16(af[m], bf[n], acc[m][n], 0, 0, 0);
    __syncthreads();
  }
#pragma unroll
  for (int m = 0; m < 4; ++m)
#pragma unroll
    for (int n = 0; n < 4; ++n) {
      const int colg = col0 + wc*64 + n*16 + fr;
#pragma unroll
      for (int r = 0; r < 4; ++r) {
        const int row = wr*64 + m*16 + fg*4 + r;
        part[((size_t)(sp*128 + row))*2048 + colg] = acc[m][n][r];
      }
    }
}

// K3c: reduce 4 K-split partials + bias -> kbuf/vbuf fp32. grid (8, 128).
__global__ __launch_bounds__(256) void kv_reduce2_kernel(
    const float* __restrict__ part, const float* __restrict__ bk,
    const float* __restrict__ bv, float* __restrict__ kbuf,
    float* __restrict__ vbuf) {
  const int row = blockIdx.y;
  const int col = blockIdx.x*256 + threadIdx.x;   // 0..2047
  float s = 0.f;
#pragma unroll
  for (int sp = 0; sp < 4; ++sp)
    s += part[((size_t)(sp*128 + row))*2048 + col];
  if (col < HDIM) kbuf[(size_t)row*HDIM + col] = s + bk[col];
  else            vbuf[(size_t)row*HDIM + col - HDIM] = s + bv[col - HDIM];
}

// ---------------------------------------------------------------------------
// Prep: transpose+convert weight W[K][N] fp32 -> Wt[N][K] bf16  (1024x1024)
// ---------------------------------------------------------------------------
__global__ __launch_bounds__(256) void wtrans_kernel(
    const float* __restrict__ W, unsigned short* __restrict__ Wt) {
  __shared__ float tile[32][33];
  const int tx = threadIdx.x & 31, ty = threadIdx.x >> 5;
  const int bx = blockIdx.x * 32, by = blockIdx.y * 32;
#pragma unroll
  for (int i = 0; i < 32; i += 8)
    tile[ty + i][tx] = W[(size_t)(by + ty + i)*HDIM + bx + tx];
  __syncthreads();
#pragma unroll
  for (int i = 0; i < 32; i += 8)
    Wt[(size_t)(bx + ty + i)*HDIM + by + tx] = f2bf(tile[tx][ty + i]);
}

// ---------------------------------------------------------------------------
// Prep: elementwise fp32 -> bf16
// ---------------------------------------------------------------------------
__global__ __launch_bounds__(256) void conv_bf16_kernel(
    const float* __restrict__ in, unsigned short* __restrict__ out) {
  const int i = (blockIdx.x*256 + threadIdx.x)*4;
  const float4 v = *(const float4*)&in[i];
  us4 w;
  w.x = f2bf(v.x); w.y = f2bf(v.y); w.z = f2bf(v.z); w.w = f2bf(v.w);
  *(us4*)&out[i] = w;
}

// ---------------------------------------------------------------------------
// bf16 MFMA GEMM (m97 structure): C[M,N] = alpha*(A @ Bt^T) (+ bias)
// OUTBF: write C as bf16 instead of fp32.
// ---------------------------------------------------------------------------
template<bool HASBIAS, bool OUTBF>
__global__ __launch_bounds__(256) void gemm_bf16_kernel(
    const unsigned short* __restrict__ A, const unsigned short* __restrict__ Bt,
    const float* __restrict__ bias, void* __restrict__ Cv,
    int M, int N, int K, float alpha) {
  __shared__ __align__(16) unsigned short As[128*32];
  __shared__ __align__(16) unsigned short Bs[128*32];
  const int tid = threadIdx.x;
  const int lane = tid & 63, wave = tid >> 6;
  const int wr = wave >> 1, wc = wave & 1;
  const int row0 = blockIdx.y << 7, col0 = blockIdx.x << 7;

  f32x4 acc[4][4];
#pragma unroll
  for (int m = 0; m < 4; ++m)
#pragma unroll
    for (int n = 0; n < 4; ++n)
      acc[m][n] = (f32x4)(0.f);

  const int srow = tid >> 2;
  const int sk   = (tid & 3) << 3;
  const unsigned short* gA = A  + (size_t)(row0 + srow)*K + sk;
  const unsigned short* gB = Bt + (size_t)(col0 + srow)*K + sk;
  const int fr = lane & 15;
  const int fk = (lane >> 4) << 3;
  const int fg = lane >> 4;

  for (int k0 = 0; k0 < K; k0 += 32) {
    gload_lds16(gA + k0,          As + tid*8);
    gload_lds16(gA + 64*K + k0,   As + 2048 + tid*8);
    gload_lds16(gB + k0,          Bs + tid*8);
    gload_lds16(gB + 64*K + k0,   Bs + 2048 + tid*8);
    __syncthreads();
    short8 af[4], bf[4];
#pragma unroll
    for (int m = 0; m < 4; ++m)
      af[m] = *(const short8*)&As[(wr*64 + m*16 + fr)*32 + fk];
#pragma unroll
    for (int n = 0; n < 4; ++n)
      bf[n] = *(const short8*)&Bs[(wc*64 + n*16 + fr)*32 + fk];
#pragma unroll
    for (int m = 0; m < 4; ++m)
#pragma unroll
      for (int n = 0; n < 4; ++n)
        acc[m][n] = __builtin_amdgcn_mfma_f32_16x16x32_bf16(af[m], bf[n], acc[m][n], 0, 0, 0);
    __syncthreads();
  }

#pragma unroll
  for (int m = 0; m < 4; ++m) {
#pragma unroll
    for (int n = 0; n < 4; ++n) {
      const int col = col0 + wc*64 + n*16 + fr;
      const float bb = HASBIAS ? bias[col] : 0.f;
#pragma unroll
      for (int r = 0; r < 4; ++r) {
        const int row = row0 + wr*64 + m*16 + fg*4 + r;
        const float val = acc[m][n][r]*alpha + bb;
        if (OUTBF) ((unsigned short*)Cv)[(size_t)row*N + col] = f2bf(val);
        else       ((float*)Cv)[(size_t)row*N + col] = val;
      }
    }
  }
}

// ---------------------------------------------------------------------------
// K5: MFMA landmark attention. Block = 128 tokens x 1 head; 4 waves x 32 rows.
// ---------------------------------------------------------------------------
__global__ __launch_bounds__(256) void attn_mfma_kernel(
    const unsigned short* __restrict__ qb, const float* __restrict__ kbuf,
    const float* __restrict__ vbuf, unsigned short* __restrict__ ctxb) {
  const int tb = blockIdx.x, h = blockIdx.y, b = blockIdx.z;
  const int tid = threadIdx.x;
  const int lane = tid & 63, wave = tid >> 6;
  __shared__ __align__(16) unsigned short Qs[128*64];
  __shared__ __align__(16) unsigned short Ks[64*64];
  __shared__ __align__(16) unsigned short Vt[64*64];
  __shared__ __align__(16) unsigned short Ps[128*64];

  const int tok0 = b*NS + tb*128;
#pragma unroll
  for (int it = 0; it < 4; ++it) {
    const int idx = it*256 + tid;
    gload_lds16(qb + (size_t)(tok0 + (idx >> 3))*HDIM + h*64 + (idx & 7)*8,
                Qs + idx*8);
  }
#pragma unroll
  for (int it = 0; it < 4; ++it) {
    const int i = it*256 + tid;
    const int l = i >> 4, d0 = (i & 15) << 2;
    const size_t base = (size_t)(b*LM + l)*HDIM + h*64 + d0;
    const float4 kv = *(const float4*)(kbuf + base);
    const float4 vv = *(const float4*)(vbuf + base);
    us4 k4; k4.x = f2bf(kv.x); k4.y = f2bf(kv.y); k4.z = f2bf(kv.z); k4.w = f2bf(kv.w);
    *(us4*)&Ks[l*64 + d0] = k4;
    Vt[(d0+0)*64 + l] = f2bf(vv.x);
    Vt[(d0+1)*64 + l] = f2bf(vv.y);
    Vt[(d0+2)*64 + l] = f2bf(vv.z);
    Vt[(d0+3)*64 + l] = f2bf(vv.w);
  }
  __syncthreads();

  const int fr = lane & 15;
  const int fg = lane >> 4;
  const int fk = fg << 3;
  const int wrow = wave*32;

  f32x4 acc[2][4];
#pragma unroll
  for (int m = 0; m < 2; ++m)
#pragma unroll
    for (int n = 0; n < 4; ++n) acc[m][n] = (f32x4)(0.f);
#pragma unroll
  for (int ks = 0; ks < 2; ++ks) {
    short8 af[2], bf[4];
#pragma unroll
    for (int m = 0; m < 2; ++m)
      af[m] = *(const short8*)&Qs[(wrow + m*16 + fr)*64 + ks*32 + fk];
#pragma unroll
    for (int n = 0; n < 4; ++n)
      bf[n] = *(const short8*)&Ks[(n*16 + fr)*64 + ks*32 + fk];
#pragma unroll
    for (int m = 0; m < 2; ++m)
#pragma unroll
      for (int n = 0; n < 4; ++n)
        acc[m][n] = __builtin_amdgcn_mfma_f32_16x16x32_bf16(af[m], bf[n], acc[m][n], 0, 0, 0);
  }

#pragma unroll
  for (int m = 0; m < 2; ++m) {
#pragma unroll
    for (int r = 0; r < 4; ++r) {
      float p0 = acc[m][0][r]*0.125f, p1 = acc[m][1][r]*0.125f;
      float p2 = acc[m][2][r]*0.125f, p3 = acc[m][3][r]*0.125f;
      float mx = fmaxf(fmaxf(p0, p1), fmaxf(p2, p3));
#pragma unroll
      for (int off = 1; off < 16; off <<= 1) mx = fmaxf(mx, __shfl_xor(mx, off));
      p0 = expf(p0 - mx); p1 = expf(p1 - mx); p2 = expf(p2 - mx); p3 = expf(p3 - mx);
      float sm = p0 + p1 + p2 + p3;
#pragma unroll
      for (int off = 1; off < 16; off <<= 1) sm += __shfl_xor(sm, off);
      const float inv = 1.f/sm;
      const int prow = (wrow + m*16 + fg*4 + r)*64;
      Ps[prow + 0*16 + fr] = f2bf(p0*inv);
      Ps[prow + 1*16 + fr] = f2bf(p1*inv);
      Ps[prow + 2*16 + fr] = f2bf(p2*inv);
      Ps[prow + 3*16 + fr] = f2bf(p3*inv);
    }
  }
  __syncthreads();

  f32x4 occ[2][4];
#pragma unroll
  for (int m = 0; m < 2; ++m)
#pragma unroll
    for (int n = 0; n < 4; ++n) occ[m][n] = (f32x4)(0.f);
#pragma unroll
  for (int ks = 0; ks < 2; ++ks) {
    short8 af[2], bf[4];
#pragma unroll
    for (int m = 0; m < 2; ++m)
      af[m] = *(const short8*)&Ps[(wrow + m*16 + fr)*64 + ks*32 + fk];
#pragma unroll
    for (int n = 0; n < 4; ++n)
      bf[n] = *(const short8*)&Vt[(n*16 + fr)*64 + ks*32 + fk];
#pragma unroll
    for (int m = 0; m < 2; ++m)
#pragma unroll
      for (int n = 0; n < 4; ++n)
        occ[m][n] = __builtin_amdgcn_mfma_f32_16x16x32_bf16(af[m], bf[n], occ[m][n], 0, 0, 0);
  }
#pragma unroll
  for (int m = 0; m < 2; ++m)
#pragma unroll
    for (int n = 0; n < 4; ++n)
#pragma unroll
      for (int r = 0; r < 4; ++r)
        ctxb[(size_t)(tok0 + wrow + m*16 + fg*4 + r)*HDIM + h*64 + n*16 + fr] =
            f2bf(occ[m][n][r]);
}

// ---------------------------------------------------------------------------
// K8: per-token top-32 via 256-bin histogram selection + softmax + gather
// (bf16 values); out += gate * mem_out.
// ---------------------------------------------------------------------------
__global__ __launch_bounds__(256) void mem_kernel(
    const float* __restrict__ msc, const unsigned short* __restrict__ mvb,
    const float* __restrict__ gate, float* __restrict__ out) {
  const int token = blockIdx.x;
  const int tid = threadIdx.x;
  const int lane = tid & 63, wave = tid >> 6;

  __shared__ float s_wmax[4], s_wmin[4];
  __shared__ float s_maxv, s_minv, s_scale;
  __shared__ int   s_hist[256];
  __shared__ int   s_sfx[256];
  __shared__ int   s_B, s_cnt, s_nlist;
  __shared__ unsigned long long s_list[MS];
  __shared__ int   s_midx[KSEL];
  __shared__ float s_mval[KSEL];
  __shared__ float s_w[KSEL];

  const float v0 = msc[(size_t)token*MS + tid];
  const float v1 = msc[(size_t)token*MS + 256 + tid];

  float mx = fmaxf(v0, v1), mn = fminf(v0, v1);
#pragma unroll
  for (int off = 32; off > 0; off >>= 1) {
    mx = fmaxf(mx, __shfl_xor(mx, off));
    mn = fminf(mn, __shfl_xor(mn, off));
  }
  if (lane == 0) { s_wmax[wave] = mx; s_wmin[wave] = mn; }
  s_hist[tid] = 0;
  __syncthreads();
  if (tid == 0) {
    float M = s_wmax[0], m = s_wmin[0];
    for (int w = 1; w < 4; ++w) { M = fmaxf(M, s_wmax[w]); m = fminf(m, s_wmin[w]); }
    s_maxv = M; s_minv = m;
    const float range = M - m;
    s_scale = (range > 1e-20f) ? 255.0f / range : 0.0f;
    s_cnt = 0; s_nlist = 0;
  }
  __syncthreads();
  const float scale = s_scale, smin = s_minv, smax = s_maxv;
  int b0 = (int)((v0 - smin) * scale); b0 = b0 > 255 ? 255 : b0;
  int b1 = (int)((v1 - smin) * scale); b1 = b1 > 255 ? 255 : b1;
  atomicAdd(&s_hist[b0], 1);
  atomicAdd(&s_hist[b1], 1);
  __syncthreads();
  s_sfx[tid] = s_hist[tid];
  __syncthreads();
  for (int s = 1; s < 256; s <<= 1) {
    const int t = (tid + s < 256) ? s_sfx[tid + s] : 0;
    __syncthreads();
    s_sfx[tid] += t;
    __syncthreads();
  }
  if (s_sfx[tid] >= KSEL && (tid == 255 || s_sfx[tid + 1] < KSEL)) s_B = tid;
  __syncthreads();
  const int B = s_B;
  const unsigned int u0 = __float_as_uint(v0);
  const unsigned int k0 = (u0 & 0x80000000u) ? ~u0 : (u0 | 0x80000000u);
  const unsigned int u1 = __float_as_uint(v1);
  const unsigned int k1 = (u1 & 0x80000000u) ? ~u1 : (u1 | 0x80000000u);
  if (b0 > B) {
    const int p = atomicAdd(&s_cnt, 1); s_midx[p] = tid; s_mval[p] = v0;
  } else if (b0 == B) {
    const int p = atomicAdd(&s_nlist, 1);
    s_list[p] = ((unsigned long long)k0 << 32) | (unsigned int)~tid;
  }
  if (b1 > B) {
    const int p = atomicAdd(&s_cnt, 1); s_midx[p] = 256 + tid; s_mval[p] = v1;
  } else if (b1 == B) {
    const int p = atomicAdd(&s_nlist, 1);
    s_list[p] = ((unsigned long long)k1 << 32) | (unsigned int)~(256u + tid);
  }
  __syncthreads();
  if (wave == 0) {
    const int nl = s_nlist;
    const int above = s_cnt;
    const int rem = KSEL - above;
    for (int r = 0; r < rem; ++r) {
      unsigned long long best = 0; int pos = -1;
      for (int i = lane; i < nl; i += 64)
        if (s_list[i] > best) { best = s_list[i]; pos = i; }
#pragma unroll
      for (int off = 32; off > 0; off >>= 1) {
        const unsigned long long ob = __shfl_xor(best, off);
        const int op = __shfl_xor(pos, off);
        if (ob > best) { best = ob; pos = op; }
      }
      if (lane == 0) {
        s_list[pos] = 0;
        const unsigned int key = (unsigned int)(best >> 32);
        const unsigned int ub = (key & 0x80000000u) ? (key & 0x7fffffffu) : ~key;
        s_midx[above + r] = (int)(~(unsigned int)(best & 0xffffffffu));
        s_mval[above + r] = __uint_as_float(ub);
      }
    }
  }
  __syncthreads();
  if (tid < KSEL) {
    const float e = expf(s_mval[tid] - smax);
    float tot = e;
#pragma unroll
    for (int off = 16; off > 0; off >>= 1) tot += __shfl_xor(tot, off);
    s_w[tid] = e / tot;
  }
  __syncthreads();
  const int d4 = tid << 2;
  float4 acc = make_float4(0.f, 0.f, 0.f, 0.f);
  for (int it = 0; it < KSEL; ++it) {
    const int m = s_midx[it];
    const float w = s_w[it];
    const us4 mv4 = *(const us4*)(mvb + (size_t)m*HDIM + d4);
    acc.x += w*bf2f(mv4.x); acc.y += w*bf2f(mv4.y);
    acc.z += w*bf2f(mv4.z); acc.w += w*bf2f(mv4.w);
  }
  const float g = gate[token];
  float4 cur = *(float4*)(out + (size_t)token*HDIM + d4);
  cur.x += g*acc.x; cur.y += g*acc.y; cur.z += g*acc.z; cur.w += g*acc.w;
  *(float4*)(out + (size_t)token*HDIM + d4) = cur;
}

// ---------------------------------------------------------------------------
extern "C" void kernel_launch(void* const* d_in, const int* in_sizes, int n_in,
                              void* d_out, int out_size, void* d_ws, size_t ws_size,
                              hipStream_t stream) {
  const float* hs = (const float*)d_in[0];
  const float* Wq = (const float*)d_in[1];
  const float* bq = (const float*)d_in[2];
  const float* Wk = (const float*)d_in[3];
  const float* bk = (const float*)d_in[4];
  const float* Wv = (const float*)d_in[5];
  const float* bv = (const float*)d_in[6];
  const float* Wo = (const float*)d_in[7];
  const float* bo = (const float*)d_in[8];
  const float* mk = (const float*)d_in[9];
  const float* mv = (const float*)d_in[10];
  const float* gw = (const float*)d_in[11];
  const float* gb = (const float*)d_in[12];
  float* out = (float*)d_out;

  // Workspace map (peak ~60 MB). Region A (32..48 MB) time-shares:
  //   kv-partials (4 MB)  ->  qb (16 MB)  ->  msc (16 MB)
  // each producer runs strictly after the previous consumer on `stream`.
  char* ws = (char*)d_ws;
  unsigned short* hsb  = (unsigned short*)(ws);                       // 16 MiB bf16 [NTOK,HDIM]
  unsigned short* ctxb = (unsigned short*)(ws + ((size_t)16 << 20));  // 16 MiB bf16
  char*           regA = ws + ((size_t)32 << 20);                     // 16 MiB shared
  float*          part = (float*)regA;                                // 4 MiB [4][128][2048]
  unsigned short* qb   = (unsigned short*)regA;                       // 16 MiB bf16
  float*          msc  = (float*)regA;                                // 16 MiB fp32 [NTOK,MS]
  unsigned short* Wkvt = (unsigned short*)(ws + ((size_t)48 << 20));  // 4 MiB [2048][1024]
  unsigned short* Wqt  = (unsigned short*)(ws + ((size_t)52 << 20));  // 2 MiB
  unsigned short* Wot  = (unsigned short*)(ws + ((size_t)54 << 20));  // 2 MiB
  unsigned short* mkb  = (unsigned short*)(ws + ((size_t)56 << 20));  // 1 MiB
  unsigned short* mvb  = (unsigned short*)(ws + ((size_t)57 << 20));  // 1 MiB
  float*          kbuf = (float*)(ws + ((size_t)58 << 20));           // 512 KiB
  float*          vbuf = (float*)(ws + ((size_t)58 << 20) + ((size_t)512 << 10));
  unsigned short* g    = (unsigned short*)(ws + ((size_t)59 << 20));  // 256 KiB
  float*          imp  = (float*)(ws + ((size_t)60 << 20));           // 32 KiB
  float*          gate = (float*)(ws + ((size_t)60 << 20) + ((size_t)32 << 10));
  int*            cnt  = (int*)  (ws + ((size_t)60 << 20) + ((size_t)64 << 10)); // 32 KiB
  int*            lmi  = (int*)  (ws + ((size_t)60 << 20) + ((size_t)96 << 10)); // 4 KiB

  imp_gate_kernel<<<dim3(NTOK), 256, 0, stream>>>(hs, gw, gb, imp, gate, hsb);
  hipMemsetAsync(cnt, 0, NB*NS*sizeof(int), stream);
  lm_count_kernel<<<dim3(NS/256, 4, NB), 256, 0, stream>>>(imp, cnt);
  lm_sel_kernel<<<dim3(NS/256, NB), 256, 0, stream>>>(cnt, lmi);
  // weight prep
  wtrans_kernel<<<dim3(32, 32), 256, 0, stream>>>(Wk, Wkvt);
  wtrans_kernel<<<dim3(32, 32), 256, 0, stream>>>(Wv, Wkvt + (size_t)HDIM*HDIM);
  wtrans_kernel<<<dim3(32, 32), 256, 0, stream>>>(Wq, Wqt);
  wtrans_kernel<<<dim3(32, 32), 256, 0, stream>>>(Wo, Wot);
  conv_bf16_kernel<<<dim3(MS*HDIM/1024), 256, 0, stream>>>(mk, mkb);
  conv_bf16_kernel<<<dim3(MS*HDIM/1024), 256, 0, stream>>>(mv, mvb);
  // K/V projection of landmark rows via MFMA GEMM (split-K=4)
  lm_gather_kernel<<<dim3(NB*LM), 256, 0, stream>>>(hsb, lmi, g);
  kvproj_gemm_kernel<<<dim3(16, 4), 256, 0, stream>>>(g, Wkvt, part);
  kv_reduce2_kernel<<<dim3(8, 128), 256, 0, stream>>>(part, bk, bv, kbuf, vbuf);
  // Q projection -> attention -> output projection
  gemm_bf16_kernel<true, true><<<dim3(HDIM/128, NTOK/128), 256, 0, stream>>>(
      hsb, Wqt, bq, qb, NTOK, HDIM, HDIM, 1.f);
  attn_mfma_kernel<<<dim3(NS/128, NHEAD, NB), 256, 0, stream>>>(qb, kbuf, vbuf, ctxb);
  gemm_bf16_kernel<true, false><<<dim3(HDIM/128, NTOK/128), 256, 0, stream>>>(
      ctxb, Wot, bo, out, NTOK, HDIM, HDIM, 1.f);
  // memory bank
  gemm_bf16_kernel<false, false><<<dim3(MS/128, NTOK/128), 256, 0, stream>>>(
      hsb, mkb, nullptr, msc, NTOK, MS, HDIM, 0.03125f);
  mem_kernel<<<dim3(NTOK), 256, 0, stream>>>(msc, mvb, gate, out);
}

// Round 8
// 212.760 us; speedup vs baseline: 4.7872x; 1.0531x over previous
//
#include <hip/hip_runtime.h>
#include <math.h>

// Problem constants (from reference setup_inputs)
#define HDIM 1024
#define NHEAD 16
#define HD 64
#define LM 64          // NUM_LANDMARKS
#define MS 512         // memory slots
#define KSEL 32        // top_k
#define NB 2
#define NS 4096
#define NTOK (NB*NS)   // 8192

typedef __attribute__((ext_vector_type(8))) short short8;
typedef __attribute__((ext_vector_type(4))) float f32x4;
typedef __attribute__((ext_vector_type(4))) unsigned short us4;

__device__ __forceinline__ unsigned short f2bf(float f) {
  unsigned int u = __float_as_uint(f);
  unsigned int r = (u + 0x7fffu + ((u >> 16) & 1u)) >> 16;
  return (unsigned short)r;
}
__device__ __forceinline__ float bf2f(unsigned short u) {
  return __uint_as_float(((unsigned int)u) << 16);
}

__device__ __forceinline__ void gload_lds16(const unsigned short* g, unsigned short* l) {
  __builtin_amdgcn_global_load_lds(
      (const __attribute__((address_space(1))) unsigned int*)g,
      (__attribute__((address_space(3))) unsigned int*)l,
      16, 0, 0);
}

// ---------------------------------------------------------------------------
// K1: per-token importance (sum sq) + gate scalar + hs -> bf16 conversion
// ---------------------------------------------------------------------------
__global__ __launch_bounds__(256) void imp_gate_kernel(
    const float* __restrict__ hs, const float* __restrict__ gw,
    const float* __restrict__ gb, float* __restrict__ imp,
    float* __restrict__ gate, unsigned short* __restrict__ hsb) {
  const int row = blockIdx.x;
  const int tid = threadIdx.x;
  const float4 hv = *(const float4*)(hs + (size_t)row*HDIM + tid*4);
  const float4 gv = *(const float4*)(gw + tid*4);
  us4 hb;
  hb.x = f2bf(hv.x); hb.y = f2bf(hv.y); hb.z = f2bf(hv.z); hb.w = f2bf(hv.w);
  *(us4*)(hsb + (size_t)row*HDIM + tid*4) = hb;
  float ss = hv.x*hv.x + hv.y*hv.y + hv.z*hv.z + hv.w*hv.w;
  float dg = hv.x*gv.x + hv.y*gv.y + hv.z*gv.z + hv.w*gv.w;
  __shared__ float sss[256], sdg[256];
  sss[tid] = ss; sdg[tid] = dg;
  __syncthreads();
  for (int s = 128; s > 0; s >>= 1) {
    if (tid < s) { sss[tid] += sss[tid+s]; sdg[tid] += sdg[tid+s]; }
    __syncthreads();
  }
  if (tid == 0) {
    imp[row] = sss[0];
    gate[row] = 1.f/(1.f + expf(-(sdg[0] + gb[0])));
  }
}

// ---------------------------------------------------------------------------
// K2a: rank counting, parallel over (candidate, j-chunk).
// rank(i) = #{j : v[j] > v[i]  or  (v[j]==v[i] and j<i)}  (jax tie-break).
// ---------------------------------------------------------------------------
__global__ __launch_bounds__(256) void lm_count_kernel(
    const float* __restrict__ imp, int* __restrict__ cnt) {
  const int b = blockIdx.z;
  const int jc = blockIdx.y;
  const int i = blockIdx.x*256 + threadIdx.x;
  const float* v = imp + b*NS;
  const float mine = v[i];
  __shared__ float tile[1024];
  const int j0 = jc*1024;
  *(float4*)&tile[threadIdx.x*4] = *(const float4*)&v[j0 + threadIdx.x*4];
  __syncthreads();
  int c = 0;
#pragma unroll 8
  for (int p = 0; p < 1024; p += 4) {
    const float4 t = *(const float4*)&tile[p];
    c += (t.x > mine) || (t.x == mine && (j0+p+0) < i);
    c += (t.y > mine) || (t.y == mine && (j0+p+1) < i);
    c += (t.z > mine) || (t.z == mine && (j0+p+2) < i);
    c += (t.w > mine) || (t.w == mine && (j0+p+3) < i);
  }
  atomicAdd(&cnt[b*NS + i], c);
}

// K2b: scatter selected candidates (set only; order irrelevant downstream).
__global__ __launch_bounds__(256) void lm_sel_kernel(
    const int* __restrict__ cnt, int* __restrict__ lm_idx) {
  const int b = blockIdx.y;
  const int i = blockIdx.x*256 + threadIdx.x;
  const int c = cnt[b*NS + i];
  if (c < LM) lm_idx[b*LM + c] = i;
}

// ---------------------------------------------------------------------------
// K3a: gather 128 landmark rows (bf16) into compact g[NB*LM][HDIM]
// ---------------------------------------------------------------------------
__global__ __launch_bounds__(256) void lm_gather_kernel(
    const unsigned short* __restrict__ hsb, const int* __restrict__ lmi,
    unsigned short* __restrict__ g) {
  const int j = blockIdx.x;           // 0..127 = b*LM + l
  const int b = j >> 6;
  const int idx = lmi[j];
  const us4 v = *(const us4*)(hsb + ((size_t)(b*NS + idx))*HDIM + threadIdx.x*4);
  *(us4*)(g + (size_t)j*HDIM + threadIdx.x*4) = v;
}

// ---------------------------------------------------------------------------
// K3b: K/V projection as bf16 MFMA GEMM, split-K=4.
// ---------------------------------------------------------------------------
__global__ __launch_bounds__(256) void kvproj_gemm_kernel(
    const unsigned short* __restrict__ g, const unsigned short* __restrict__ Wkvt,
    float* __restrict__ part) {
  __shared__ __align__(16) unsigned short As[128*32];
  __shared__ __align__(16) unsigned short Bs[128*32];
  const int tid = threadIdx.x;
  const int lane = tid & 63, wave = tid >> 6;
  const int wr = wave >> 1, wc = wave & 1;
  const int col0 = blockIdx.x << 7;
  const int sp = blockIdx.y;
  const int k00 = sp << 8;

  f32x4 acc[4][4];
#pragma unroll
  for (int m = 0; m < 4; ++m)
#pragma unroll
    for (int n = 0; n < 4; ++n) acc[m][n] = (f32x4)(0.f);

  const int srow = tid >> 2;
  const int sk   = (tid & 3) << 3;
  const unsigned short* gA = g    + (size_t)srow*HDIM + sk;
  const unsigned short* gB = Wkvt + (size_t)(col0 + srow)*HDIM + sk;
  const int fr = lane & 15;
  const int fk = (lane >> 4) << 3;
  const int fg = lane >> 4;

  for (int k0 = k00; k0 < k00 + 256; k0 += 32) {
    gload_lds16(gA + k0,             As + tid*8);
    gload_lds16(gA + 64*HDIM + k0,   As + 2048 + tid*8);
    gload_lds16(gB + k0,             Bs + tid*8);
    gload_lds16(gB + 64*HDIM + k0,   Bs + 2048 + tid*8);
    __syncthreads();
    short8 af[4], bf[4];
#pragma unroll
    for (int m = 0; m < 4; ++m)
      af[m] = *(const short8*)&As[(wr*64 + m*16 + fr)*32 + fk];
#pragma unroll
    for (int n = 0; n < 4; ++n)
      bf[n] = *(const short8*)&Bs[(wc*64 + n*16 + fr)*32 + fk];
#pragma unroll
    for (int m = 0; m < 4; ++m)
#pragma unroll
      for (int n = 0; n < 4; ++n)
        acc[m][n] = __builtin_amdgcn_mfma_f32_16x16x32_bf16(af[m], bf[n], acc[m][n], 0, 0, 0);
    __syncthreads();
  }
#pragma unroll
  for (int m = 0; m < 4; ++m)
#pragma unroll
    for (int n = 0; n < 4; ++n) {
      const int colg = col0 + wc*64 + n*16 + fr;
#pragma unroll
      for (int r = 0; r < 4; ++r) {
        const int row = wr*64 + m*16 + fg*4 + r;
        part[((size_t)(sp*128 + row))*2048 + colg] = acc[m][n][r];
      }
    }
}

// K3c: reduce 4 K-split partials + bias -> kbuf/vbuf fp32. grid (8, 128).
__global__ __launch_bounds__(256) void kv_reduce2_kernel(
    const float* __restrict__ part, const float* __restrict__ bk,
    const float* __restrict__ bv, float* __restrict__ kbuf,
    float* __restrict__ vbuf) {
  const int row = blockIdx.y;
  const int col = blockIdx.x*256 + threadIdx.x;
  float s = 0.f;
#pragma unroll
  for (int sp = 0; sp < 4; ++sp)
    s += part[((size_t)(sp*128 + row))*2048 + col];
  if (col < HDIM) kbuf[(size_t)row*HDIM + col] = s + bk[col];
  else            vbuf[(size_t)row*HDIM + col - HDIM] = s + bv[col - HDIM];
}

// ---------------------------------------------------------------------------
// Prep (fused): z<4 -> transpose+convert W -> Wt bf16; z==4 -> conv mk/mv.
// grid (32, 32, 5)
// ---------------------------------------------------------------------------
__global__ __launch_bounds__(256) void prep_kernel(
    const float* __restrict__ Wk, const float* __restrict__ Wv,
    const float* __restrict__ Wq, const float* __restrict__ Wo,
    const float* __restrict__ mk, const float* __restrict__ mv,
    unsigned short* __restrict__ Wkvt, unsigned short* __restrict__ Wqt,
    unsigned short* __restrict__ Wot, unsigned short* __restrict__ mkb,
    unsigned short* __restrict__ mvb) {
  const int z = blockIdx.z;
  __shared__ float tile[32][33];
  if (z < 4) {
    const float* W = (z == 0) ? Wk : (z == 1) ? Wv : (z == 2) ? Wq : Wo;
    unsigned short* Wt = (z == 0) ? Wkvt
                       : (z == 1) ? (Wkvt + (size_t)HDIM*HDIM)
                       : (z == 2) ? Wqt : Wot;
    const int tx = threadIdx.x & 31, ty = threadIdx.x >> 5;
    const int bx = blockIdx.x * 32, by = blockIdx.y * 32;
#pragma unroll
    for (int i = 0; i < 32; i += 8)
      tile[ty + i][tx] = W[(size_t)(by + ty + i)*HDIM + bx + tx];
    __syncthreads();
#pragma unroll
    for (int i = 0; i < 32; i += 8)
      Wt[(size_t)(bx + ty + i)*HDIM + by + tx] = f2bf(tile[tx][ty + i]);
  } else {
    const int blk = blockIdx.y*32 + blockIdx.x;     // 0..1023
    const float* src = (blk < 512) ? mk : mv;
    unsigned short* dst = (blk < 512) ? mkb : mvb;
    const int off = ((blk & 511) << 10) + threadIdx.x*4;
    const float4 v = *(const float4*)&src[off];
    us4 w;
    w.x = f2bf(v.x); w.y = f2bf(v.y); w.z = f2bf(v.z); w.w = f2bf(v.w);
    *(us4*)&dst[off] = w;
  }
}

// ---------------------------------------------------------------------------
// bf16 MFMA GEMM (m97 structure): C[M,N] = alpha*(A @ Bt^T) (+ bias)
// ---------------------------------------------------------------------------
template<bool HASBIAS, bool OUTBF>
__global__ __launch_bounds__(256) void gemm_bf16_kernel(
    const unsigned short* __restrict__ A, const unsigned short* __restrict__ Bt,
    const float* __restrict__ bias, void* __restrict__ Cv,
    int M, int N, int K, float alpha) {
  __shared__ __align__(16) unsigned short As[128*32];
  __shared__ __align__(16) unsigned short Bs[128*32];
  const int tid = threadIdx.x;
  const int lane = tid & 63, wave = tid >> 6;
  const int wr = wave >> 1, wc = wave & 1;
  const int row0 = blockIdx.y << 7, col0 = blockIdx.x << 7;

  f32x4 acc[4][4];
#pragma unroll
  for (int m = 0; m < 4; ++m)
#pragma unroll
    for (int n = 0; n < 4; ++n)
      acc[m][n] = (f32x4)(0.f);

  const int srow = tid >> 2;
  const int sk   = (tid & 3) << 3;
  const unsigned short* gA = A  + (size_t)(row0 + srow)*K + sk;
  const unsigned short* gB = Bt + (size_t)(col0 + srow)*K + sk;
  const int fr = lane & 15;
  const int fk = (lane >> 4) << 3;
  const int fg = lane >> 4;

  for (int k0 = 0; k0 < K; k0 += 32) {
    gload_lds16(gA + k0,          As + tid*8);
    gload_lds16(gA + 64*K + k0,   As + 2048 + tid*8);
    gload_lds16(gB + k0,          Bs + tid*8);
    gload_lds16(gB + 64*K + k0,   Bs + 2048 + tid*8);
    __syncthreads();
    short8 af[4], bf[4];
#pragma unroll
    for (int m = 0; m < 4; ++m)
      af[m] = *(const short8*)&As[(wr*64 + m*16 + fr)*32 + fk];
#pragma unroll
    for (int n = 0; n < 4; ++n)
      bf[n] = *(const short8*)&Bs[(wc*64 + n*16 + fr)*32 + fk];
#pragma unroll
    for (int m = 0; m < 4; ++m)
#pragma unroll
      for (int n = 0; n < 4; ++n)
        acc[m][n] = __builtin_amdgcn_mfma_f32_16x16x32_bf16(af[m], bf[n], acc[m][n], 0, 0, 0);
    __syncthreads();
  }

#pragma unroll
  for (int m = 0; m < 4; ++m) {
#pragma unroll
    for (int n = 0; n < 4; ++n) {
      const int col = col0 + wc*64 + n*16 + fr;
      const float bb = HASBIAS ? bias[col] : 0.f;
#pragma unroll
      for (int r = 0; r < 4; ++r) {
        const int row = row0 + wr*64 + m*16 + fg*4 + r;
        const float val = acc[m][n][r]*alpha + bb;
        if (OUTBF) ((unsigned short*)Cv)[(size_t)row*N + col] = f2bf(val);
        else       ((float*)Cv)[(size_t)row*N + col] = val;
      }
    }
  }
}

// ---------------------------------------------------------------------------
// K5: MFMA landmark attention. Block = 128 tokens x 1 head; 4 waves x 32 rows.
// ---------------------------------------------------------------------------
__global__ __launch_bounds__(256) void attn_mfma_kernel(
    const unsigned short* __restrict__ qb, const float* __restrict__ kbuf,
    const float* __restrict__ vbuf, unsigned short* __restrict__ ctxb) {
  const int tb = blockIdx.x, h = blockIdx.y, b = blockIdx.z;
  const int tid = threadIdx.x;
  const int lane = tid & 63, wave = tid >> 6;
  __shared__ __align__(16) unsigned short Qs[128*64];
  __shared__ __align__(16) unsigned short Ks[64*64];
  __shared__ __align__(16) unsigned short Vt[64*64];
  __shared__ __align__(16) unsigned short Ps[128*64];

  const int tok0 = b*NS + tb*128;
#pragma unroll
  for (int it = 0; it < 4; ++it) {
    const int idx = it*256 + tid;
    gload_lds16(qb + (size_t)(tok0 + (idx >> 3))*HDIM + h*64 + (idx & 7)*8,
                Qs + idx*8);
  }
#pragma unroll
  for (int it = 0; it < 4; ++it) {
    const int i = it*256 + tid;
    const int l = i >> 4, d0 = (i & 15) << 2;
    const size_t base = (size_t)(b*LM + l)*HDIM + h*64 + d0;
    const float4 kv = *(const float4*)(kbuf + base);
    const float4 vv = *(const float4*)(vbuf + base);
    us4 k4; k4.x = f2bf(kv.x); k4.y = f2bf(kv.y); k4.z = f2bf(kv.z); k4.w = f2bf(kv.w);
    *(us4*)&Ks[l*64 + d0] = k4;
    Vt[(d0+0)*64 + l] = f2bf(vv.x);
    Vt[(d0+1)*64 + l] = f2bf(vv.y);
    Vt[(d0+2)*64 + l] = f2bf(vv.z);
    Vt[(d0+3)*64 + l] = f2bf(vv.w);
  }
  __syncthreads();

  const int fr = lane & 15;
  const int fg = lane >> 4;
  const int fk = fg << 3;
  const int wrow = wave*32;

  f32x4 acc[2][4];
#pragma unroll
  for (int m = 0; m < 2; ++m)
#pragma unroll
    for (int n = 0; n < 4; ++n) acc[m][n] = (f32x4)(0.f);
#pragma unroll
  for (int ks = 0; ks < 2; ++ks) {
    short8 af[2], bf[4];
#pragma unroll
    for (int m = 0; m < 2; ++m)
      af[m] = *(const short8*)&Qs[(wrow + m*16 + fr)*64 + ks*32 + fk];
#pragma unroll
    for (int n = 0; n < 4; ++n)
      bf[n] = *(const short8*)&Ks[(n*16 + fr)*64 + ks*32 + fk];
#pragma unroll
    for (int m = 0; m < 2; ++m)
#pragma unroll
      for (int n = 0; n < 4; ++n)
        acc[m][n] = __builtin_amdgcn_mfma_f32_16x16x32_bf16(af[m], bf[n], acc[m][n], 0, 0, 0);
  }

#pragma unroll
  for (int m = 0; m < 2; ++m) {
#pragma unroll
    for (int r = 0; r < 4; ++r) {
      float p0 = acc[m][0][r]*0.125f, p1 = acc[m][1][r]*0.125f;
      float p2 = acc[m][2][r]*0.125f, p3 = acc[m][3][r]*0.125f;
      float mx = fmaxf(fmaxf(p0, p1), fmaxf(p2, p3));
#pragma unroll
      for (int off = 1; off < 16; off <<= 1) mx = fmaxf(mx, __shfl_xor(mx, off));
      p0 = expf(p0 - mx); p1 = expf(p1 - mx); p2 = expf(p2 - mx); p3 = expf(p3 - mx);
      float sm = p0 + p1 + p2 + p3;
#pragma unroll
      for (int off = 1; off < 16; off <<= 1) sm += __shfl_xor(sm, off);
      const float inv = 1.f/sm;
      const int prow = (wrow + m*16 + fg*4 + r)*64;
      Ps[prow + 0*16 + fr] = f2bf(p0*inv);
      Ps[prow + 1*16 + fr] = f2bf(p1*inv);
      Ps[prow + 2*16 + fr] = f2bf(p2*inv);
      Ps[prow + 3*16 + fr] = f2bf(p3*inv);
    }
  }
  __syncthreads();

  f32x4 occ[2][4];
#pragma unroll
  for (int m = 0; m < 2; ++m)
#pragma unroll
    for (int n = 0; n < 4; ++n) occ[m][n] = (f32x4)(0.f);
#pragma unroll
  for (int ks = 0; ks < 2; ++ks) {
    short8 af[2], bf[4];
#pragma unroll
    for (int m = 0; m < 2; ++m)
      af[m] = *(const short8*)&Ps[(wrow + m*16 + fr)*64 + ks*32 + fk];
#pragma unroll
    for (int n = 0; n < 4; ++n)
      bf[n] = *(const short8*)&Vt[(n*16 + fr)*64 + ks*32 + fk];
#pragma unroll
    for (int m = 0; m < 2; ++m)
#pragma unroll
      for (int n = 0; n < 4; ++n)
        occ[m][n] = __builtin_amdgcn_mfma_f32_16x16x32_bf16(af[m], bf[n], occ[m][n], 0, 0, 0);
  }
#pragma unroll
  for (int m = 0; m < 2; ++m)
#pragma unroll
    for (int n = 0; n < 4; ++n)
#pragma unroll
      for (int r = 0; r < 4; ++r)
        ctxb[(size_t)(tok0 + wrow + m*16 + fg*4 + r)*HDIM + h*64 + n*16 + fr] =
            f2bf(occ[m][n][r]);
}

// ---------------------------------------------------------------------------
// K8: wave-per-token top-32 (histogram + shfl suffix-scan, ZERO block
// barriers; all LDS wave-private, DS ops in-order per wave) + softmax +
// coalesced gather; out += gate * mem_out.  Block = 4 waves = 4 tokens.
// ---------------------------------------------------------------------------
__global__ __launch_bounds__(256) void mem_kernel(
    const float* __restrict__ msc, const unsigned short* __restrict__ mvb,
    const float* __restrict__ gate, float* __restrict__ out) {
  const int tid = threadIdx.x;
  const int lane = tid & 63, wave = tid >> 6;
  const int token = blockIdx.x*4 + wave;

  __shared__ __align__(16) int s_hist[4][256];
  __shared__ unsigned long long s_list[4][MS];
  __shared__ int   s_midx[4][KSEL];
  __shared__ float s_mval[4][KSEL];
  __shared__ float s_w[4][KSEL];
  __shared__ int   s_B[4], s_cnt[4], s_nlist[4];

  // zero my wave's hist (4 bins/lane) + counters
  *(int4*)&s_hist[wave][lane*4] = make_int4(0, 0, 0, 0);
  if (lane == 0) { s_cnt[wave] = 0; s_nlist[wave] = 0; }

  // load my 8 scores (coalesced within wave)
  float v[8];
#pragma unroll
  for (int j = 0; j < 8; ++j) v[j] = msc[(size_t)token*MS + j*64 + lane];

  // wave max/min
  float mx = v[0], mn = v[0];
#pragma unroll
  for (int j = 1; j < 8; ++j) { mx = fmaxf(mx, v[j]); mn = fminf(mn, v[j]); }
#pragma unroll
  for (int off = 32; off > 0; off >>= 1) {
    mx = fmaxf(mx, __shfl_xor(mx, off));
    mn = fminf(mn, __shfl_xor(mn, off));
  }
  const float range = mx - mn;
  const float scale = (range > 1e-20f) ? 255.f/range : 0.f;

  // histogram (wave-local LDS atomics; zeroing store precedes in program order)
  __builtin_amdgcn_wave_barrier();
  int bins[8];
#pragma unroll
  for (int j = 0; j < 8; ++j) {
    int b = (int)((v[j] - mn)*scale);
    bins[j] = b > 255 ? 255 : b;
    atomicAdd(&s_hist[wave][bins[j]], 1);
  }
  __builtin_amdgcn_wave_barrier();

  // suffix counts: lane owns bins [4l,4l+4); shfl-doubling over lane totals
  const int4 c = *(const int4*)&s_hist[wave][lane*4];
  const int lane_total = c.x + c.y + c.z + c.w;
  int sfx = lane_total;
#pragma unroll
  for (int off = 1; off < 64; off <<= 1) {
    const int src = lane + off;
    int y = __shfl(sfx, src < 64 ? src : lane);
    sfx += (src < 64) ? y : 0;
  }
  const int beyond = sfx - lane_total;   // suffix starting at bin 4(l+1)
  const int s3 = c.w + beyond;
  const int s2 = c.z + s3;
  const int s1 = c.y + s2;
  const int s0 = c.x + s1;
  // unique crossing bin B: sfx[B] >= 32 > sfx[B+1]
  int Bl = -1;
  if (s0 >= KSEL && s1 < KSEL) Bl = lane*4 + 0;
  if (s1 >= KSEL && s2 < KSEL) Bl = lane*4 + 1;
  if (s2 >= KSEL && s3 < KSEL) Bl = lane*4 + 2;
  if (s3 >= KSEL && beyond < KSEL) Bl = lane*4 + 3;
  if (Bl >= 0) s_B[wave] = Bl;           // exactly one lane writes
  __builtin_amdgcn_wave_barrier();
  const int B = s_B[wave];

  // classify: bins>B definite members; bin==B boundary candidates
#pragma unroll
  for (int j = 0; j < 8; ++j) {
    const int idx = j*64 + lane;
    if (bins[j] > B) {
      const int p = atomicAdd(&s_cnt[wave], 1);
      s_midx[wave][p] = idx; s_mval[wave][p] = v[j];
    } else if (bins[j] == B) {
      const unsigned int u = __float_as_uint(v[j]);
      const unsigned int k = (u & 0x80000000u) ? ~u : (u | 0x80000000u);
      const int p = atomicAdd(&s_nlist[wave], 1);
      s_list[wave][p] = ((unsigned long long)k << 32) | (unsigned int)~idx;
    }
  }
  __builtin_amdgcn_wave_barrier();

  // extract remaining (value desc, idx asc) from boundary list — whole wave
  const int above = s_cnt[wave];
  const int nl = s_nlist[wave];
  const int rem = KSEL - above;
  for (int r = 0; r < rem; ++r) {
    unsigned long long best = 0; int pos = -1;
    for (int i = lane; i < nl; i += 64)
      if (s_list[wave][i] > best) { best = s_list[wave][i]; pos = i; }
#pragma unroll
    for (int off = 32; off > 0; off >>= 1) {
      const unsigned long long ob = __shfl_xor(best, off);
      const int op = __shfl_xor(pos, off);
      if (ob > best) { best = ob; pos = op; }
    }
    if (lane == 0) {
      s_list[wave][pos] = 0;
      const unsigned int key = (unsigned int)(best >> 32);
      const unsigned int ub = (key & 0x80000000u) ? (key & 0x7fffffffu) : ~key;
      s_midx[wave][above + r] = (int)(~(unsigned int)(best & 0xffffffffu));
      s_mval[wave][above + r] = __uint_as_float(ub);
    }
    __builtin_amdgcn_wave_barrier();
  }

  // softmax over the 32 selected (mx = row max, exact)
  {
    float e = 0.f;
    if (lane < KSEL) e = expf(s_mval[wave][lane] - mx);
    float tot = e;
#pragma unroll
    for (int off = 16; off > 0; off >>= 1) tot += __shfl_xor(tot, off);
    if (lane < KSEL) s_w[wave][lane] = e / tot;
  }
  __builtin_amdgcn_wave_barrier();

  // gather: lane handles dims {cc*256 + lane*4} — coalesced 512B/instr
  float4 acc[4];
#pragma unroll
  for (int cc = 0; cc < 4; ++cc) acc[cc] = make_float4(0.f, 0.f, 0.f, 0.f);
  for (int it = 0; it < KSEL; ++it) {
    const int m = s_midx[wave][it];
    const float w = s_w[wave][it];
#pragma unroll
    for (int cc = 0; cc < 4; ++cc) {
      const us4 q4 = *(const us4*)(mvb + (size_t)m*HDIM + cc*256 + lane*4);
      acc[cc].x += w*bf2f(q4.x); acc[cc].y += w*bf2f(q4.y);
      acc[cc].z += w*bf2f(q4.z); acc[cc].w += w*bf2f(q4.w);
    }
  }
  const float g = gate[token];
#pragma unroll
  for (int cc = 0; cc < 4; ++cc) {
    float* op = out + (size_t)token*HDIM + cc*256 + lane*4;
    float4 cur = *(float4*)op;
    cur.x += g*acc[cc].x; cur.y += g*acc[cc].y;
    cur.z += g*acc[cc].z; cur.w += g*acc[cc].w;
    *(float4*)op = cur;
  }
}

// ---------------------------------------------------------------------------
extern "C" void kernel_launch(void* const* d_in, const int* in_sizes, int n_in,
                              void* d_out, int out_size, void* d_ws, size_t ws_size,
                              hipStream_t stream) {
  const float* hs = (const float*)d_in[0];
  const float* Wq = (const float*)d_in[1];
  const float* bq = (const float*)d_in[2];
  const float* Wk = (const float*)d_in[3];
  const float* bk = (const float*)d_in[4];
  const float* Wv = (const float*)d_in[5];
  const float* bv = (const float*)d_in[6];
  const float* Wo = (const float*)d_in[7];
  const float* bo = (const float*)d_in[8];
  const float* mk = (const float*)d_in[9];
  const float* mv = (const float*)d_in[10];
  const float* gw = (const float*)d_in[11];
  const float* gb = (const float*)d_in[12];
  float* out = (float*)d_out;

  // Workspace map (peak ~60 MB). Region A (32..48 MB) time-shares:
  //   kv-partials (4 MB) -> qb (16 MB) -> msc (16 MB)
  char* ws = (char*)d_ws;
  unsigned short* hsb  = (unsigned short*)(ws);                       // 16 MiB bf16 [NTOK,HDIM]
  unsigned short* ctxb = (unsigned short*)(ws + ((size_t)16 << 20));  // 16 MiB bf16
  char*           regA = ws + ((size_t)32 << 20);                     // 16 MiB shared
  float*          part = (float*)regA;                                // 4 MiB
  unsigned short* qb   = (unsigned short*)regA;                       // 16 MiB bf16
  float*          msc  = (float*)regA;                                // 16 MiB fp32
  unsigned short* Wkvt = (unsigned short*)(ws + ((size_t)48 << 20));  // 4 MiB
  unsigned short* Wqt  = (unsigned short*)(ws + ((size_t)52 << 20));  // 2 MiB
  unsigned short* Wot  = (unsigned short*)(ws + ((size_t)54 << 20));  // 2 MiB
  unsigned short* mkb  = (unsigned short*)(ws + ((size_t)56 << 20));  // 1 MiB
  unsigned short* mvb  = (unsigned short*)(ws + ((size_t)57 << 20));  // 1 MiB
  float*          kbuf = (float*)(ws + ((size_t)58 << 20));           // 512 KiB
  float*          vbuf = (float*)(ws + ((size_t)58 << 20) + ((size_t)512 << 10));
  unsigned short* g    = (unsigned short*)(ws + ((size_t)59 << 20));  // 256 KiB
  float*          imp  = (float*)(ws + ((size_t)60 << 20));           // 32 KiB
  float*          gate = (float*)(ws + ((size_t)60 << 20) + ((size_t)32 << 10));
  int*            cnt  = (int*)  (ws + ((size_t)60 << 20) + ((size_t)64 << 10)); // 32 KiB
  int*            lmi  = (int*)  (ws + ((size_t)60 << 20) + ((size_t)96 << 10)); // 4 KiB

  imp_gate_kernel<<<dim3(NTOK), 256, 0, stream>>>(hs, gw, gb, imp, gate, hsb);
  hipMemsetAsync(cnt, 0, NB*NS*sizeof(int), stream);
  lm_count_kernel<<<dim3(NS/256, 4, NB), 256, 0, stream>>>(imp, cnt);
  lm_sel_kernel<<<dim3(NS/256, NB), 256, 0, stream>>>(cnt, lmi);
  prep_kernel<<<dim3(32, 32, 5), 256, 0, stream>>>(
      Wk, Wv, Wq, Wo, mk, mv, Wkvt, Wqt, Wot, mkb, mvb);
  // K/V projection of landmark rows via MFMA GEMM (split-K=4)
  lm_gather_kernel<<<dim3(NB*LM), 256, 0, stream>>>(hsb, lmi, g);
  kvproj_gemm_kernel<<<dim3(16, 4), 256, 0, stream>>>(g, Wkvt, part);
  kv_reduce2_kernel<<<dim3(8, 128), 256, 0, stream>>>(part, bk, bv, kbuf, vbuf);
  // Q projection -> attention -> output projection
  gemm_bf16_kernel<true, true><<<dim3(HDIM/128, NTOK/128), 256, 0, stream>>>(
      hsb, Wqt, bq, qb, NTOK, HDIM, HDIM, 1.f);
  attn_mfma_kernel<<<dim3(NS/128, NHEAD, NB), 256, 0, stream>>>(qb, kbuf, vbuf, ctxb);
  gemm_bf16_kernel<true, false><<<dim3(HDIM/128, NTOK/128), 256, 0, stream>>>(
      ctxb, Wot, bo, out, NTOK, HDIM, HDIM, 1.f);
  // memory bank
  gemm_bf16_kernel<false, false><<<dim3(MS/128, NTOK/128), 256, 0, stream>>>(
      hsb, mkb, nullptr, msc, NTOK, MS, HDIM, 0.03125f);
  mem_kernel<<<dim3(NTOK/4), 256, 0, stream>>>(msc, mvb, gate, out);
}

// Round 9
// 188.786 us; speedup vs baseline: 5.3951x; 1.1270x over previous
//
#include <hip/hip_runtime.h>
#include <math.h>

// Problem constants (from reference setup_inputs)
#define HDIM 1024
#define NHEAD 16
#define HD 64
#define LM 64          // NUM_LANDMARKS
#define MS 512         // memory slots
#define KSEL 32        // top_k
#define NB 2
#define NS 4096
#define NTOK (NB*NS)   // 8192

typedef __attribute__((ext_vector_type(8))) short short8;
typedef __attribute__((ext_vector_type(4))) float f32x4;
typedef __attribute__((ext_vector_type(4))) unsigned short us4;

__device__ __forceinline__ unsigned short f2bf(float f) {
  unsigned int u = __float_as_uint(f);
  unsigned int r = (u + 0x7fffu + ((u >> 16) & 1u)) >> 16;
  return (unsigned short)r;
}
__device__ __forceinline__ float bf2f(unsigned short u) {
  return __uint_as_float(((unsigned int)u) << 16);
}

__device__ __forceinline__ void gload_lds16(const unsigned short* g, unsigned short* l) {
  __builtin_amdgcn_global_load_lds(
      (const __attribute__((address_space(1))) unsigned int*)g,
      (__attribute__((address_space(3))) unsigned int*)l,
      16, 0, 0);
}

// ---------------------------------------------------------------------------
// K1: wave-per-row importance (sum sq) + gate + hs -> bf16. Block = 4 rows.
// ---------------------------------------------------------------------------
__global__ __launch_bounds__(256) void imp_gate_kernel(
    const float* __restrict__ hs, const float* __restrict__ gw,
    const float* __restrict__ gb, float* __restrict__ imp,
    float* __restrict__ gate, unsigned short* __restrict__ hsb) {
  const int lane = threadIdx.x & 63, wave = threadIdx.x >> 6;
  const int row = blockIdx.x*4 + wave;
  float ss = 0.f, dg = 0.f;
#pragma unroll
  for (int c = 0; c < 4; ++c) {
    const int d = c*256 + lane*4;
    const float4 hv = *(const float4*)(hs + (size_t)row*HDIM + d);
    const float4 gv = *(const float4*)(gw + d);
    ss += hv.x*hv.x + hv.y*hv.y + hv.z*hv.z + hv.w*hv.w;
    dg += hv.x*gv.x + hv.y*gv.y + hv.z*gv.z + hv.w*gv.w;
    us4 hb;
    hb.x = f2bf(hv.x); hb.y = f2bf(hv.y); hb.z = f2bf(hv.z); hb.w = f2bf(hv.w);
    *(us4*)(hsb + (size_t)row*HDIM + d) = hb;
  }
#pragma unroll
  for (int off = 32; off > 0; off >>= 1) {
    ss += __shfl_xor(ss, off);
    dg += __shfl_xor(dg, off);
  }
  if (lane == 0) {
    imp[row] = ss;
    gate[row] = 1.f/(1.f + expf(-(dg + gb[0])));
  }
}

// ---------------------------------------------------------------------------
// K2a: rank counting, parallel over (candidate, j-chunk).
// rank(i) = #{j : v[j] > v[i]  or  (v[j]==v[i] and j<i)}  (jax tie-break).
// ---------------------------------------------------------------------------
__global__ __launch_bounds__(256) void lm_count_kernel(
    const float* __restrict__ imp, int* __restrict__ cnt) {
  const int b = blockIdx.z;
  const int jc = blockIdx.y;
  const int i = blockIdx.x*256 + threadIdx.x;
  const float* v = imp + b*NS;
  const float mine = v[i];
  __shared__ float tile[1024];
  const int j0 = jc*1024;
  *(float4*)&tile[threadIdx.x*4] = *(const float4*)&v[j0 + threadIdx.x*4];
  __syncthreads();
  int c = 0;
#pragma unroll 8
  for (int p = 0; p < 1024; p += 4) {
    const float4 t = *(const float4*)&tile[p];
    c += (t.x > mine) || (t.x == mine && (j0+p+0) < i);
    c += (t.y > mine) || (t.y == mine && (j0+p+1) < i);
    c += (t.z > mine) || (t.z == mine && (j0+p+2) < i);
    c += (t.w > mine) || (t.w == mine && (j0+p+3) < i);
  }
  atomicAdd(&cnt[b*NS + i], c);
}

// K2b: scatter selected candidates (set only; order irrelevant downstream).
__global__ __launch_bounds__(256) void lm_sel_kernel(
    const int* __restrict__ cnt, int* __restrict__ lm_idx) {
  const int b = blockIdx.y;
  const int i = blockIdx.x*256 + threadIdx.x;
  const int c = cnt[b*NS + i];
  if (c < LM) lm_idx[b*LM + c] = i;
}

// ---------------------------------------------------------------------------
// K3a: gather 128 landmark rows (bf16) into compact g[NB*LM][HDIM]
// ---------------------------------------------------------------------------
__global__ __launch_bounds__(256) void lm_gather_kernel(
    const unsigned short* __restrict__ hsb, const int* __restrict__ lmi,
    unsigned short* __restrict__ g) {
  const int j = blockIdx.x;           // 0..127 = b*LM + l
  const int b = j >> 6;
  const int idx = lmi[j];
  const us4 v = *(const us4*)(hsb + ((size_t)(b*NS + idx))*HDIM + threadIdx.x*4);
  *(us4*)(g + (size_t)j*HDIM + threadIdx.x*4) = v;
}

// ---------------------------------------------------------------------------
// K3b: K/V projection as bf16 MFMA GEMM, split-K=4.
// ---------------------------------------------------------------------------
__global__ __launch_bounds__(256) void kvproj_gemm_kernel(
    const unsigned short* __restrict__ g, const unsigned short* __restrict__ Wkvt,
    float* __restrict__ part) {
  __shared__ __align__(16) unsigned short As[128*32];
  __shared__ __align__(16) unsigned short Bs[128*32];
  const int tid = threadIdx.x;
  const int lane = tid & 63, wave = tid >> 6;
  const int wr = wave >> 1, wc = wave & 1;
  const int col0 = blockIdx.x << 7;
  const int sp = blockIdx.y;
  const int k00 = sp << 8;

  f32x4 acc[4][4];
#pragma unroll
  for (int m = 0; m < 4; ++m)
#pragma unroll
    for (int n = 0; n < 4; ++n) acc[m][n] = (f32x4)(0.f);

  const int srow = tid >> 2;
  const int sk   = (tid & 3) << 3;
  const unsigned short* gA = g    + (size_t)srow*HDIM + sk;
  const unsigned short* gB = Wkvt + (size_t)(col0 + srow)*HDIM + sk;
  const int fr = lane & 15;
  const int fk = (lane >> 4) << 3;
  const int fg = lane >> 4;

  for (int k0 = k00; k0 < k00 + 256; k0 += 32) {
    gload_lds16(gA + k0,             As + tid*8);
    gload_lds16(gA + 64*HDIM + k0,   As + 2048 + tid*8);
    gload_lds16(gB + k0,             Bs + tid*8);
    gload_lds16(gB + 64*HDIM + k0,   Bs + 2048 + tid*8);
    __syncthreads();
    short8 af[4], bf[4];
#pragma unroll
    for (int m = 0; m < 4; ++m)
      af[m] = *(const short8*)&As[(wr*64 + m*16 + fr)*32 + fk];
#pragma unroll
    for (int n = 0; n < 4; ++n)
      bf[n] = *(const short8*)&Bs[(wc*64 + n*16 + fr)*32 + fk];
#pragma unroll
    for (int m = 0; m < 4; ++m)
#pragma unroll
      for (int n = 0; n < 4; ++n)
        acc[m][n] = __builtin_amdgcn_mfma_f32_16x16x32_bf16(af[m], bf[n], acc[m][n], 0, 0, 0);
    __syncthreads();
  }
#pragma unroll
  for (int m = 0; m < 4; ++m)
#pragma unroll
    for (int n = 0; n < 4; ++n) {
      const int colg = col0 + wc*64 + n*16 + fr;
#pragma unroll
      for (int r = 0; r < 4; ++r) {
        const int row = wr*64 + m*16 + fg*4 + r;
        part[((size_t)(sp*128 + row))*2048 + colg] = acc[m][n][r];
      }
    }
}

// K3c: reduce 4 K-split partials + bias -> kbuf/vbuf fp32. grid (8, 128).
__global__ __launch_bounds__(256) void kv_reduce2_kernel(
    const float* __restrict__ part, const float* __restrict__ bk,
    const float* __restrict__ bv, float* __restrict__ kbuf,
    float* __restrict__ vbuf) {
  const int row = blockIdx.y;
  const int col = blockIdx.x*256 + threadIdx.x;
  float s = 0.f;
#pragma unroll
  for (int sp = 0; sp < 4; ++sp)
    s += part[((size_t)(sp*128 + row))*2048 + col];
  if (col < HDIM) kbuf[(size_t)row*HDIM + col] = s + bk[col];
  else            vbuf[(size_t)row*HDIM + col - HDIM] = s + bv[col - HDIM];
}

// ---------------------------------------------------------------------------
// Prep (fused): z<4 -> transpose+convert W; z==4 -> conv mk (into Wcat tail)
// and mv.  grid (32, 32, 5)
// ---------------------------------------------------------------------------
__global__ __launch_bounds__(256) void prep_kernel(
    const float* __restrict__ Wk, const float* __restrict__ Wv,
    const float* __restrict__ Wq, const float* __restrict__ Wo,
    const float* __restrict__ mk, const float* __restrict__ mv,
    unsigned short* __restrict__ Wkvt, unsigned short* __restrict__ Wcat,
    unsigned short* __restrict__ Wot, unsigned short* __restrict__ mvb) {
  const int z = blockIdx.z;
  __shared__ float tile[32][33];
  if (z < 4) {
    const float* W = (z == 0) ? Wk : (z == 1) ? Wv : (z == 2) ? Wq : Wo;
    unsigned short* Wt = (z == 0) ? Wkvt
                       : (z == 1) ? (Wkvt + (size_t)HDIM*HDIM)
                       : (z == 2) ? Wcat : Wot;
    const int tx = threadIdx.x & 31, ty = threadIdx.x >> 5;
    const int bx = blockIdx.x * 32, by = blockIdx.y * 32;
#pragma unroll
    for (int i = 0; i < 32; i += 8)
      tile[ty + i][tx] = W[(size_t)(by + ty + i)*HDIM + bx + tx];
    __syncthreads();
#pragma unroll
    for (int i = 0; i < 32; i += 8)
      Wt[(size_t)(bx + ty + i)*HDIM + by + tx] = f2bf(tile[tx][ty + i]);
  } else {
    const int blk = blockIdx.y*32 + blockIdx.x;     // 0..1023
    const float* src = (blk < 512) ? mk : mv;
    // mem_keys is [MS][HDIM] = [N][K] already -> append to Wcat rows 1024..1535
    unsigned short* dst = (blk < 512) ? (Wcat + (size_t)HDIM*HDIM) : mvb;
    const int off = ((blk & 511) << 10) + threadIdx.x*4;
    const float4 v = *(const float4*)&src[off];
    us4 w;
    w.x = f2bf(v.x); w.y = f2bf(v.y); w.z = f2bf(v.z); w.w = f2bf(v.w);
    *(us4*)&dst[off] = w;
  }
}

// ---------------------------------------------------------------------------
// Fused GEMM: [q | msc] = hsb @ Wcat^T.  Wcat [1536][1024] bf16.
// cols 0..1023  -> qb bf16 (+bq);  cols 1024..1535 -> msc fp32 (*1/32).
// grid (12, 64); 128x128 tile, BK=32.
// ---------------------------------------------------------------------------
__global__ __launch_bounds__(256) void gemm_qmsc_kernel(
    const unsigned short* __restrict__ A, const unsigned short* __restrict__ Bt,
    const float* __restrict__ bq, unsigned short* __restrict__ qb,
    float* __restrict__ msc) {
  __shared__ __align__(16) unsigned short As[128*32];
  __shared__ __align__(16) unsigned short Bs[128*32];
  const int tid = threadIdx.x;
  const int lane = tid & 63, wave = tid >> 6;
  const int wr = wave >> 1, wc = wave & 1;
  const int row0 = blockIdx.y << 7, col0 = blockIdx.x << 7;

  f32x4 acc[4][4];
#pragma unroll
  for (int m = 0; m < 4; ++m)
#pragma unroll
    for (int n = 0; n < 4; ++n) acc[m][n] = (f32x4)(0.f);

  const int srow = tid >> 2;
  const int sk   = (tid & 3) << 3;
  const unsigned short* gA = A  + (size_t)(row0 + srow)*HDIM + sk;
  const unsigned short* gB = Bt + (size_t)(col0 + srow)*HDIM + sk;
  const int fr = lane & 15;
  const int fk = (lane >> 4) << 3;
  const int fg = lane >> 4;

  for (int k0 = 0; k0 < HDIM; k0 += 32) {
    gload_lds16(gA + k0,             As + tid*8);
    gload_lds16(gA + 64*HDIM + k0,   As + 2048 + tid*8);
    gload_lds16(gB + k0,             Bs + tid*8);
    gload_lds16(gB + 64*HDIM + k0,   Bs + 2048 + tid*8);
    __syncthreads();
    short8 af[4], bf[4];
#pragma unroll
    for (int m = 0; m < 4; ++m)
      af[m] = *(const short8*)&As[(wr*64 + m*16 + fr)*32 + fk];
#pragma unroll
    for (int n = 0; n < 4; ++n)
      bf[n] = *(const short8*)&Bs[(wc*64 + n*16 + fr)*32 + fk];
#pragma unroll
    for (int m = 0; m < 4; ++m)
#pragma unroll
      for (int n = 0; n < 4; ++n)
        acc[m][n] = __builtin_amdgcn_mfma_f32_16x16x32_bf16(af[m], bf[n], acc[m][n], 0, 0, 0);
    __syncthreads();
  }

#pragma unroll
  for (int m = 0; m < 4; ++m) {
#pragma unroll
    for (int n = 0; n < 4; ++n) {
      const int col = col0 + wc*64 + n*16 + fr;
      if (col < HDIM) {
        const float bb = bq[col];
#pragma unroll
        for (int r = 0; r < 4; ++r) {
          const int row = row0 + wr*64 + m*16 + fg*4 + r;
          qb[(size_t)row*HDIM + col] = f2bf(acc[m][n][r] + bb);
        }
      } else {
        const int c2 = col - HDIM;
#pragma unroll
        for (int r = 0; r < 4; ++r) {
          const int row = row0 + wr*64 + m*16 + fg*4 + r;
          msc[(size_t)row*MS + c2] = acc[m][n][r]*0.03125f;
        }
      }
    }
  }
}

// ---------------------------------------------------------------------------
// GEMM (m97 structure): out = ctx @ Wot^T + bo  (fp32 out)
// ---------------------------------------------------------------------------
__global__ __launch_bounds__(256) void gemm_out_kernel(
    const unsigned short* __restrict__ A, const unsigned short* __restrict__ Bt,
    const float* __restrict__ bias, float* __restrict__ C) {
  __shared__ __align__(16) unsigned short As[128*32];
  __shared__ __align__(16) unsigned short Bs[128*32];
  const int tid = threadIdx.x;
  const int lane = tid & 63, wave = tid >> 6;
  const int wr = wave >> 1, wc = wave & 1;
  const int row0 = blockIdx.y << 7, col0 = blockIdx.x << 7;

  f32x4 acc[4][4];
#pragma unroll
  for (int m = 0; m < 4; ++m)
#pragma unroll
    for (int n = 0; n < 4; ++n) acc[m][n] = (f32x4)(0.f);

  const int srow = tid >> 2;
  const int sk   = (tid & 3) << 3;
  const unsigned short* gA = A  + (size_t)(row0 + srow)*HDIM + sk;
  const unsigned short* gB = Bt + (size_t)(col0 + srow)*HDIM + sk;
  const int fr = lane & 15;
  const int fk = (lane >> 4) << 3;
  const int fg = lane >> 4;

  for (int k0 = 0; k0 < HDIM; k0 += 32) {
    gload_lds16(gA + k0,             As + tid*8);
    gload_lds16(gA + 64*HDIM + k0,   As + 2048 + tid*8);
    gload_lds16(gB + k0,             Bs + tid*8);
    gload_lds16(gB + 64*HDIM + k0,   Bs + 2048 + tid*8);
    __syncthreads();
    short8 af[4], bf[4];
#pragma unroll
    for (int m = 0; m < 4; ++m)
      af[m] = *(const short8*)&As[(wr*64 + m*16 + fr)*32 + fk];
#pragma unroll
    for (int n = 0; n < 4; ++n)
      bf[n] = *(const short8*)&Bs[(wc*64 + n*16 + fr)*32 + fk];
#pragma unroll
    for (int m = 0; m < 4; ++m)
#pragma unroll
      for (int n = 0; n < 4; ++n)
        acc[m][n] = __builtin_amdgcn_mfma_f32_16x16x32_bf16(af[m], bf[n], acc[m][n], 0, 0, 0);
    __syncthreads();
  }

#pragma unroll
  for (int m = 0; m < 4; ++m) {
#pragma unroll
    for (int n = 0; n < 4; ++n) {
      const int col = col0 + wc*64 + n*16 + fr;
      const float bb = bias[col];
#pragma unroll
      for (int r = 0; r < 4; ++r) {
        const int row = row0 + wr*64 + m*16 + fg*4 + r;
        C[(size_t)row*HDIM + col] = acc[m][n][r] + bb;
      }
    }
  }
}

// ---------------------------------------------------------------------------
// K5: MFMA landmark attention. Block = 128 tokens x 1 head; 4 waves x 32 rows.
// ---------------------------------------------------------------------------
__global__ __launch_bounds__(256) void attn_mfma_kernel(
    const unsigned short* __restrict__ qb, const float* __restrict__ kbuf,
    const float* __restrict__ vbuf, unsigned short* __restrict__ ctxb) {
  const int tb = blockIdx.x, h = blockIdx.y, b = blockIdx.z;
  const int tid = threadIdx.x;
  const int lane = tid & 63, wave = tid >> 6;
  __shared__ __align__(16) unsigned short Qs[128*64];
  __shared__ __align__(16) unsigned short Ks[64*64];
  __shared__ __align__(16) unsigned short Vt[64*64];
  __shared__ __align__(16) unsigned short Ps[128*64];

  const int tok0 = b*NS + tb*128;
#pragma unroll
  for (int it = 0; it < 4; ++it) {
    const int idx = it*256 + tid;
    gload_lds16(qb + (size_t)(tok0 + (idx >> 3))*HDIM + h*64 + (idx & 7)*8,
                Qs + idx*8);
  }
#pragma unroll
  for (int it = 0; it < 4; ++it) {
    const int i = it*256 + tid;
    const int l = i >> 4, d0 = (i & 15) << 2;
    const size_t base = (size_t)(b*LM + l)*HDIM + h*64 + d0;
    const float4 kv = *(const float4*)(kbuf + base);
    const float4 vv = *(const float4*)(vbuf + base);
    us4 k4; k4.x = f2bf(kv.x); k4.y = f2bf(kv.y); k4.z = f2bf(kv.z); k4.w = f2bf(kv.w);
    *(us4*)&Ks[l*64 + d0] = k4;
    Vt[(d0+0)*64 + l] = f2bf(vv.x);
    Vt[(d0+1)*64 + l] = f2bf(vv.y);
    Vt[(d0+2)*64 + l] = f2bf(vv.z);
    Vt[(d0+3)*64 + l] = f2bf(vv.w);
  }
  __syncthreads();

  const int fr = lane & 15;
  const int fg = lane >> 4;
  const int fk = fg << 3;
  const int wrow = wave*32;

  f32x4 acc[2][4];
#pragma unroll
  for (int m = 0; m < 2; ++m)
#pragma unroll
    for (int n = 0; n < 4; ++n) acc[m][n] = (f32x4)(0.f);
#pragma unroll
  for (int ks = 0; ks < 2; ++ks) {
    short8 af[2], bf[4];
#pragma unroll
    for (int m = 0; m < 2; ++m)
      af[m] = *(const short8*)&Qs[(wrow + m*16 + fr)*64 + ks*32 + fk];
#pragma unroll
    for (int n = 0; n < 4; ++n)
      bf[n] = *(const short8*)&Ks[(n*16 + fr)*64 + ks*32 + fk];
#pragma unroll
    for (int m = 0; m < 2; ++m)
#pragma unroll
      for (int n = 0; n < 4; ++n)
        acc[m][n] = __builtin_amdgcn_mfma_f32_16x16x32_bf16(af[m], bf[n], acc[m][n], 0, 0, 0);
  }

#pragma unroll
  for (int m = 0; m < 2; ++m) {
#pragma unroll
    for (int r = 0; r < 4; ++r) {
      float p0 = acc[m][0][r]*0.125f, p1 = acc[m][1][r]*0.125f;
      float p2 = acc[m][2][r]*0.125f, p3 = acc[m][3][r]*0.125f;
      float mx = fmaxf(fmaxf(p0, p1), fmaxf(p2, p3));
#pragma unroll
      for (int off = 1; off < 16; off <<= 1) mx = fmaxf(mx, __shfl_xor(mx, off));
      p0 = expf(p0 - mx); p1 = expf(p1 - mx); p2 = expf(p2 - mx); p3 = expf(p3 - mx);
      float sm = p0 + p1 + p2 + p3;
#pragma unroll
      for (int off = 1; off < 16; off <<= 1) sm += __shfl_xor(sm, off);
      const float inv = 1.f/sm;
      const int prow = (wrow + m*16 + fg*4 + r)*64;
      Ps[prow + 0*16 + fr] = f2bf(p0*inv);
      Ps[prow + 1*16 + fr] = f2bf(p1*inv);
      Ps[prow + 2*16 + fr] = f2bf(p2*inv);
      Ps[prow + 3*16 + fr] = f2bf(p3*inv);
    }
  }
  __syncthreads();

  f32x4 occ[2][4];
#pragma unroll
  for (int m = 0; m < 2; ++m)
#pragma unroll
    for (int n = 0; n < 4; ++n) occ[m][n] = (f32x4)(0.f);
#pragma unroll
  for (int ks = 0; ks < 2; ++ks) {
    short8 af[2], bf[4];
#pragma unroll
    for (int m = 0; m < 2; ++m)
      af[m] = *(const short8*)&Ps[(wrow + m*16 + fr)*64 + ks*32 + fk];
#pragma unroll
    for (int n = 0; n < 4; ++n)
      bf[n] = *(const short8*)&Vt[(n*16 + fr)*64 + ks*32 + fk];
#pragma unroll
    for (int m = 0; m < 2; ++m)
#pragma unroll
      for (int n = 0; n < 4; ++n)
        occ[m][n] = __builtin_amdgcn_mfma_f32_16x16x32_bf16(af[m], bf[n], occ[m][n], 0, 0, 0);
  }
#pragma unroll
  for (int m = 0; m < 2; ++m)
#pragma unroll
    for (int n = 0; n < 4; ++n)
#pragma unroll
      for (int r = 0; r < 4; ++r)
        ctxb[(size_t)(tok0 + wrow + m*16 + fg*4 + r)*HDIM + h*64 + n*16 + fr] =
            f2bf(occ[m][n][r]);
}

// ---------------------------------------------------------------------------
// K8: wave-per-token top-32 (histogram selection, zero block barriers) +
// softmax + register-broadcast unrolled gather; out += gate * mem_out.
// ---------------------------------------------------------------------------
__global__ __launch_bounds__(256) void mem_kernel(
    const float* __restrict__ msc, const unsigned short* __restrict__ mvb,
    const float* __restrict__ gate, float* __restrict__ out) {
  const int tid = threadIdx.x;
  const int lane = tid & 63, wave = tid >> 6;
  const int token = blockIdx.x*4 + wave;

  __shared__ __align__(16) int s_hist[4][256];
  __shared__ unsigned long long s_list[4][MS];
  __shared__ int   s_midx[4][KSEL];
  __shared__ float s_mval[4][KSEL];
  __shared__ int   s_B[4], s_cnt[4], s_nlist[4];

  *(int4*)&s_hist[wave][lane*4] = make_int4(0, 0, 0, 0);
  if (lane == 0) { s_cnt[wave] = 0; s_nlist[wave] = 0; }

  float v[8];
#pragma unroll
  for (int j = 0; j < 8; ++j) v[j] = msc[(size_t)token*MS + j*64 + lane];

  float mx = v[0], mn = v[0];
#pragma unroll
  for (int j = 1; j < 8; ++j) { mx = fmaxf(mx, v[j]); mn = fminf(mn, v[j]); }
#pragma unroll
  for (int off = 32; off > 0; off >>= 1) {
    mx = fmaxf(mx, __shfl_xor(mx, off));
    mn = fminf(mn, __shfl_xor(mn, off));
  }
  const float range = mx - mn;
  const float scale = (range > 1e-20f) ? 255.f/range : 0.f;

  __builtin_amdgcn_wave_barrier();
  int bins[8];
#pragma unroll
  for (int j = 0; j < 8; ++j) {
    int b = (int)((v[j] - mn)*scale);
    bins[j] = b > 255 ? 255 : b;
    atomicAdd(&s_hist[wave][bins[j]], 1);
  }
  __builtin_amdgcn_wave_barrier();

  // suffix counts: lane owns bins [4l,4l+4); shfl-doubling over lane totals
  const int4 c = *(const int4*)&s_hist[wave][lane*4];
  const int lane_total = c.x + c.y + c.z + c.w;
  int sfx = lane_total;
#pragma unroll
  for (int off = 1; off < 64; off <<= 1) {
    const int src = lane + off;
    int y = __shfl(sfx, src < 64 ? src : lane);
    sfx += (src < 64) ? y : 0;
  }
  const int beyond = sfx - lane_total;
  const int s3 = c.w + beyond;
  const int s2 = c.z + s3;
  const int s1 = c.y + s2;
  const int s0 = c.x + s1;
  int Bl = -1;
  if (s0 >= KSEL && s1 < KSEL) Bl = lane*4 + 0;
  if (s1 >= KSEL && s2 < KSEL) Bl = lane*4 + 1;
  if (s2 >= KSEL && s3 < KSEL) Bl = lane*4 + 2;
  if (s3 >= KSEL && beyond < KSEL) Bl = lane*4 + 3;
  if (Bl >= 0) s_B[wave] = Bl;
  __builtin_amdgcn_wave_barrier();
  const int B = s_B[wave];

#pragma unroll
  for (int j = 0; j < 8; ++j) {
    const int idx = j*64 + lane;
    if (bins[j] > B) {
      const int p = atomicAdd(&s_cnt[wave], 1);
      s_midx[wave][p] = idx; s_mval[wave][p] = v[j];
    } else if (bins[j] == B) {
      const unsigned int u = __float_as_uint(v[j]);
      const unsigned int k = (u & 0x80000000u) ? ~u : (u | 0x80000000u);
      const int p = atomicAdd(&s_nlist[wave], 1);
      s_list[wave][p] = ((unsigned long long)k << 32) | (unsigned int)~idx;
    }
  }
  __builtin_amdgcn_wave_barrier();

  const int above = s_cnt[wave];
  const int nl = s_nlist[wave];
  const int rem = KSEL - above;
  for (int r = 0; r < rem; ++r) {
    unsigned long long best = 0; int pos = -1;
    for (int i = lane; i < nl; i += 64)
      if (s_list[wave][i] > best) { best = s_list[wave][i]; pos = i; }
#pragma unroll
    for (int off = 32; off > 0; off >>= 1) {
      const unsigned long long ob = __shfl_xor(best, off);
      const int op = __shfl_xor(pos, off);
      if (ob > best) { best = ob; pos = op; }
    }
    if (lane == 0) {
      s_list[wave][pos] = 0;
      const unsigned int key = (unsigned int)(best >> 32);
      const unsigned int ub = (key & 0x80000000u) ? (key & 0x7fffffffu) : ~key;
      s_midx[wave][above + r] = (int)(~(unsigned int)(best & 0xffffffffu));
      s_mval[wave][above + r] = __uint_as_float(ub);
    }
    __builtin_amdgcn_wave_barrier();
  }

  // softmax weights kept in registers (lanes 0..31)
  float wwv = 0.f;
  {
    float e = 0.f;
    if (lane < KSEL) e = expf(s_mval[wave][lane] - mx);
    float tot = e;
#pragma unroll
    for (int off = 16; off > 0; off >>= 1) tot += __shfl_xor(tot, off);
    if (lane < KSEL) wwv = e / tot;
  }
  const int mi = s_midx[wave][lane & 31];
  __builtin_amdgcn_wave_barrier();

  // gather: idx/weight broadcast via shfl; unroll 4 -> 16 L2 loads in flight
  float4 acc[4];
#pragma unroll
  for (int cc = 0; cc < 4; ++cc) acc[cc] = make_float4(0.f, 0.f, 0.f, 0.f);
#pragma unroll 4
  for (int it = 0; it < KSEL; ++it) {
    const int m = __shfl(mi, it);
    const float w = __shfl(wwv, it);
#pragma unroll
    for (int cc = 0; cc < 4; ++cc) {
      const us4 q4 = *(const us4*)(mvb + (size_t)m*HDIM + cc*256 + lane*4);
      acc[cc].x += w*bf2f(q4.x); acc[cc].y += w*bf2f(q4.y);
      acc[cc].z += w*bf2f(q4.z); acc[cc].w += w*bf2f(q4.w);
    }
  }
  const float g = gate[token];
#pragma unroll
  for (int cc = 0; cc < 4; ++cc) {
    float* op = out + (size_t)token*HDIM + cc*256 + lane*4;
    float4 cur = *(float4*)op;
    cur.x += g*acc[cc].x; cur.y += g*acc[cc].y;
    cur.z += g*acc[cc].z; cur.w += g*acc[cc].w;
    *(float4*)op = cur;
  }
}

// ---------------------------------------------------------------------------
extern "C" void kernel_launch(void* const* d_in, const int* in_sizes, int n_in,
                              void* d_out, int out_size, void* d_ws, size_t ws_size,
                              hipStream_t stream) {
  const float* hs = (const float*)d_in[0];
  const float* Wq = (const float*)d_in[1];
  const float* bq = (const float*)d_in[2];
  const float* Wk = (const float*)d_in[3];
  const float* bk = (const float*)d_in[4];
  const float* Wv = (const float*)d_in[5];
  const float* bv = (const float*)d_in[6];
  const float* Wo = (const float*)d_in[7];
  const float* bo = (const float*)d_in[8];
  const float* mk = (const float*)d_in[9];
  const float* mv = (const float*)d_in[10];
  const float* gw = (const float*)d_in[11];
  const float* gb = (const float*)d_in[12];
  float* out = (float*)d_out;

  // Workspace (peak ~61 MB). hsb region is reused for ctxb: hsb's last
  // reader is the fused q/msc GEMM; attn (which writes ctxb) runs after it.
  char* ws = (char*)d_ws;
  unsigned short* hsb  = (unsigned short*)(ws);                       // 16 MiB bf16 [NTOK,HDIM]
  unsigned short* ctxb = hsb;                                         // alias (see above)
  unsigned short* qb   = (unsigned short*)(ws + ((size_t)16 << 20));  // 16 MiB bf16
  float*          msc  = (float*)(ws + ((size_t)32 << 20));           // 16 MiB fp32 [NTOK,MS]
  unsigned short* Wkvt = (unsigned short*)(ws + ((size_t)48 << 20));  // 4 MiB [2048][1024]
  unsigned short* Wcat = (unsigned short*)(ws + ((size_t)52 << 20));  // 3 MiB [1536][1024]
  unsigned short* Wot  = (unsigned short*)(ws + ((size_t)55 << 20));  // 2 MiB
  unsigned short* mvb  = (unsigned short*)(ws + ((size_t)57 << 20));  // 1 MiB
  float*          kbuf = (float*)(ws + ((size_t)58 << 20));           // 512 KiB
  float*          vbuf = (float*)(ws + ((size_t)58 << 20) + ((size_t)512 << 10));
  unsigned short* g    = (unsigned short*)(ws + ((size_t)59 << 20));  // 256 KiB
  float*          part = (float*)(ws + ((size_t)59 << 20) + ((size_t)256 << 10)); // ...
  float*          imp  = (float*)(ws + ((size_t)64 << 20));           // 32 KiB
  float*          gate = (float*)(ws + ((size_t)64 << 20) + ((size_t)32 << 10));
  int*            cnt  = (int*)  (ws + ((size_t)64 << 20) + ((size_t)64 << 10)); // 32 KiB
  int*            lmi  = (int*)  (ws + ((size_t)64 << 20) + ((size_t)96 << 10)); // 4 KiB

  imp_gate_kernel<<<dim3(NTOK/4), 256, 0, stream>>>(hs, gw, gb, imp, gate, hsb);
  hipMemsetAsync(cnt, 0, NB*NS*sizeof(int), stream);
  lm_count_kernel<<<dim3(NS/256, 4, NB), 256, 0, stream>>>(imp, cnt);
  lm_sel_kernel<<<dim3(NS/256, NB), 256, 0, stream>>>(cnt, lmi);
  prep_kernel<<<dim3(32, 32, 5), 256, 0, stream>>>(
      Wk, Wv, Wq, Wo, mk, mv, Wkvt, Wcat, Wot, mvb);
  // K/V projection of landmark rows via MFMA GEMM (split-K=4)
  lm_gather_kernel<<<dim3(NB*LM), 256, 0, stream>>>(hsb, lmi, g);
  kvproj_gemm_kernel<<<dim3(16, 4), 256, 0, stream>>>(g, Wkvt, part);
  kv_reduce2_kernel<<<dim3(8, 128), 256, 0, stream>>>(part, bk, bv, kbuf, vbuf);
  // fused Q-projection + memory scores (reads hsb for the last time)
  gemm_qmsc_kernel<<<dim3(12, NTOK/128), 256, 0, stream>>>(hsb, Wcat, bq, qb, msc);
  // attention (writes ctxb over the hsb region) -> output projection
  attn_mfma_kernel<<<dim3(NS/128, NHEAD, NB), 256, 0, stream>>>(qb, kbuf, vbuf, ctxb);
  gemm_out_kernel<<<dim3(8, NTOK/128), 256, 0, stream>>>(ctxb, Wot, bo, out);
  // memory bank read
  mem_kernel<<<dim3(NTOK/4), 256, 0, stream>>>(msc, mvb, gate, out);
}

// Round 10
// 182.489 us; speedup vs baseline: 5.5813x; 1.0345x over previous
//
#include <hip/hip_runtime.h>
#include <math.h>

// Problem constants (from reference setup_inputs)
#define HDIM 1024
#define NHEAD 16
#define HD 64
#define LM 64          // NUM_LANDMARKS
#define MS 512         // memory slots
#define KSEL 32        // top_k
#define NB 2
#define NS 4096
#define NTOK (NB*NS)   // 8192

typedef __attribute__((ext_vector_type(8))) short short8;
typedef __attribute__((ext_vector_type(4))) float f32x4;
typedef __attribute__((ext_vector_type(4))) unsigned short us4;

__device__ __forceinline__ unsigned short f2bf(float f) {
  unsigned int u = __float_as_uint(f);
  unsigned int r = (u + 0x7fffu + ((u >> 16) & 1u)) >> 16;
  return (unsigned short)r;
}
__device__ __forceinline__ float bf2f(unsigned short u) {
  return __uint_as_float(((unsigned int)u) << 16);
}

__device__ __forceinline__ void gload_lds16(const unsigned short* g, unsigned short* l) {
  __builtin_amdgcn_global_load_lds(
      (const __attribute__((address_space(1))) unsigned int*)g,
      (__attribute__((address_space(3))) unsigned int*)l,
      16, 0, 0);
}

// ---------------------------------------------------------------------------
// K1: wave-per-row importance (sum sq) + gate + hs -> bf16. Block = 4 rows.
// ---------------------------------------------------------------------------
__global__ __launch_bounds__(256) void imp_gate_kernel(
    const float* __restrict__ hs, const float* __restrict__ gw,
    const float* __restrict__ gb, float* __restrict__ imp,
    float* __restrict__ gate, unsigned short* __restrict__ hsb) {
  const int lane = threadIdx.x & 63, wave = threadIdx.x >> 6;
  const int row = blockIdx.x*4 + wave;
  float ss = 0.f, dg = 0.f;
#pragma unroll
  for (int c = 0; c < 4; ++c) {
    const int d = c*256 + lane*4;
    const float4 hv = *(const float4*)(hs + (size_t)row*HDIM + d);
    const float4 gv = *(const float4*)(gw + d);
    ss += hv.x*hv.x + hv.y*hv.y + hv.z*hv.z + hv.w*hv.w;
    dg += hv.x*gv.x + hv.y*gv.y + hv.z*gv.z + hv.w*gv.w;
    us4 hb;
    hb.x = f2bf(hv.x); hb.y = f2bf(hv.y); hb.z = f2bf(hv.z); hb.w = f2bf(hv.w);
    *(us4*)(hsb + (size_t)row*HDIM + d) = hb;
  }
#pragma unroll
  for (int off = 32; off > 0; off >>= 1) {
    ss += __shfl_xor(ss, off);
    dg += __shfl_xor(dg, off);
  }
  if (lane == 0) {
    imp[row] = ss;
    gate[row] = 1.f/(1.f + expf(-(dg + gb[0])));
  }
}

// ---------------------------------------------------------------------------
// K2a: rank counting, parallel over (candidate, j-chunk).
// rank(i) = #{j : v[j] > v[i]  or  (v[j]==v[i] and j<i)}  (jax tie-break).
// ---------------------------------------------------------------------------
__global__ __launch_bounds__(256) void lm_count_kernel(
    const float* __restrict__ imp, int* __restrict__ cnt) {
  const int b = blockIdx.z;
  const int jc = blockIdx.y;
  const int i = blockIdx.x*256 + threadIdx.x;
  const float* v = imp + b*NS;
  const float mine = v[i];
  __shared__ float tile[1024];
  const int j0 = jc*1024;
  *(float4*)&tile[threadIdx.x*4] = *(const float4*)&v[j0 + threadIdx.x*4];
  __syncthreads();
  int c = 0;
#pragma unroll 8
  for (int p = 0; p < 1024; p += 4) {
    const float4 t = *(const float4*)&tile[p];
    c += (t.x > mine) || (t.x == mine && (j0+p+0) < i);
    c += (t.y > mine) || (t.y == mine && (j0+p+1) < i);
    c += (t.z > mine) || (t.z == mine && (j0+p+2) < i);
    c += (t.w > mine) || (t.w == mine && (j0+p+3) < i);
  }
  atomicAdd(&cnt[b*NS + i], c);
}

// K2b: scatter selected candidates (set only; order irrelevant downstream).
__global__ __launch_bounds__(256) void lm_sel_kernel(
    const int* __restrict__ cnt, int* __restrict__ lm_idx) {
  const int b = blockIdx.y;
  const int i = blockIdx.x*256 + threadIdx.x;
  const int c = cnt[b*NS + i];
  if (c < LM) lm_idx[b*LM + c] = i;
}

// ---------------------------------------------------------------------------
// K3a: gather 128 landmark rows (bf16) into compact g[NB*LM][HDIM]
// ---------------------------------------------------------------------------
__global__ __launch_bounds__(256) void lm_gather_kernel(
    const unsigned short* __restrict__ hsb, const int* __restrict__ lmi,
    unsigned short* __restrict__ g) {
  const int j = blockIdx.x;           // 0..127 = b*LM + l
  const int b = j >> 6;
  const int idx = lmi[j];
  const us4 v = *(const us4*)(hsb + ((size_t)(b*NS + idx))*HDIM + threadIdx.x*4);
  *(us4*)(g + (size_t)j*HDIM + threadIdx.x*4) = v;
}

// ---------------------------------------------------------------------------
// K3b: K/V projection as bf16 MFMA GEMM, split-K=4.
// ---------------------------------------------------------------------------
__global__ __launch_bounds__(256) void kvproj_gemm_kernel(
    const unsigned short* __restrict__ g, const unsigned short* __restrict__ Wkvt,
    float* __restrict__ part) {
  __shared__ __align__(16) unsigned short As[128*32];
  __shared__ __align__(16) unsigned short Bs[128*32];
  const int tid = threadIdx.x;
  const int lane = tid & 63, wave = tid >> 6;
  const int wr = wave >> 1, wc = wave & 1;
  const int col0 = blockIdx.x << 7;
  const int sp = blockIdx.y;
  const int k00 = sp << 8;

  f32x4 acc[4][4];
#pragma unroll
  for (int m = 0; m < 4; ++m)
#pragma unroll
    for (int n = 0; n < 4; ++n) acc[m][n] = (f32x4)(0.f);

  const int srow = tid >> 2;
  const int sk   = (tid & 3) << 3;
  const unsigned short* gA = g    + (size_t)srow*HDIM + sk;
  const unsigned short* gB = Wkvt + (size_t)(col0 + srow)*HDIM + sk;
  const int fr = lane & 15;
  const int fk = (lane >> 4) << 3;
  const int fg = lane >> 4;

  for (int k0 = k00; k0 < k00 + 256; k0 += 32) {
    gload_lds16(gA + k0,             As + tid*8);
    gload_lds16(gA + 64*HDIM + k0,   As + 2048 + tid*8);
    gload_lds16(gB + k0,             Bs + tid*8);
    gload_lds16(gB + 64*HDIM + k0,   Bs + 2048 + tid*8);
    __syncthreads();
    short8 af[4], bf[4];
#pragma unroll
    for (int m = 0; m < 4; ++m)
      af[m] = *(const short8*)&As[(wr*64 + m*16 + fr)*32 + fk];
#pragma unroll
    for (int n = 0; n < 4; ++n)
      bf[n] = *(const short8*)&Bs[(wc*64 + n*16 + fr)*32 + fk];
#pragma unroll
    for (int m = 0; m < 4; ++m)
#pragma unroll
      for (int n = 0; n < 4; ++n)
        acc[m][n] = __builtin_amdgcn_mfma_f32_16x16x32_bf16(af[m], bf[n], acc[m][n], 0, 0, 0);
    __syncthreads();
  }
#pragma unroll
  for (int m = 0; m < 4; ++m)
#pragma unroll
    for (int n = 0; n < 4; ++n) {
      const int colg = col0 + wc*64 + n*16 + fr;
#pragma unroll
      for (int r = 0; r < 4; ++r) {
        const int row = wr*64 + m*16 + fg*4 + r;
        part[((size_t)(sp*128 + row))*2048 + colg] = acc[m][n][r];
      }
    }
}

// K3c: reduce 4 K-split partials + bias -> kbuf/vbuf fp32. grid (8, 128).
__global__ __launch_bounds__(256) void kv_reduce2_kernel(
    const float* __restrict__ part, const float* __restrict__ bk,
    const float* __restrict__ bv, float* __restrict__ kbuf,
    float* __restrict__ vbuf) {
  const int row = blockIdx.y;
  const int col = blockIdx.x*256 + threadIdx.x;
  float s = 0.f;
#pragma unroll
  for (int sp = 0; sp < 4; ++sp)
    s += part[((size_t)(sp*128 + row))*2048 + col];
  if (col < HDIM) kbuf[(size_t)row*HDIM + col] = s + bk[col];
  else            vbuf[(size_t)row*HDIM + col - HDIM] = s + bv[col - HDIM];
}

// ---------------------------------------------------------------------------
// Prep (fused): z<4 -> transpose+convert W; z==4 -> blk<512: conv mk into
// Wcat tail; blk>=512: transpose+convert mem_values -> mvT[1024][512] bf16.
// grid (32, 32, 5)
// ---------------------------------------------------------------------------
__global__ __launch_bounds__(256) void prep_kernel(
    const float* __restrict__ Wk, const float* __restrict__ Wv,
    const float* __restrict__ Wq, const float* __restrict__ Wo,
    const float* __restrict__ mk, const float* __restrict__ mv,
    unsigned short* __restrict__ Wkvt, unsigned short* __restrict__ Wcat,
    unsigned short* __restrict__ Wot, unsigned short* __restrict__ mvT) {
  const int z = blockIdx.z;
  __shared__ float tile[32][33];
  const int tx = threadIdx.x & 31, ty = threadIdx.x >> 5;
  if (z < 4) {
    const float* W = (z == 0) ? Wk : (z == 1) ? Wv : (z == 2) ? Wq : Wo;
    unsigned short* Wt = (z == 0) ? Wkvt
                       : (z == 1) ? (Wkvt + (size_t)HDIM*HDIM)
                       : (z == 2) ? Wcat : Wot;
    const int bx = blockIdx.x * 32, by = blockIdx.y * 32;
#pragma unroll
    for (int i = 0; i < 32; i += 8)
      tile[ty + i][tx] = W[(size_t)(by + ty + i)*HDIM + bx + tx];
    __syncthreads();
#pragma unroll
    for (int i = 0; i < 32; i += 8)
      Wt[(size_t)(bx + ty + i)*HDIM + by + tx] = f2bf(tile[tx][ty + i]);
  } else {
    const int blk = blockIdx.y*32 + blockIdx.x;     // 0..1023
    if (blk < 512) {
      // mem_keys [MS][HDIM] = [N][K] already -> append to Wcat rows 1024..1535
      const int off = (blk << 10) + threadIdx.x*4;
      const float4 v = *(const float4*)&mk[off];
      us4 w;
      w.x = f2bf(v.x); w.y = f2bf(v.y); w.z = f2bf(v.z); w.w = f2bf(v.w);
      *(us4*)&(Wcat + (size_t)HDIM*HDIM)[off] = w;
    } else {
      // transpose mem_values [512][1024] -> mvT [1024][512]
      const int t = blk - 512;                      // 0..511
      const int by = (t >> 5) * 32;                 // row block in mv (0..480)
      const int bx = (t & 31) * 32;                 // col block in mv (0..992)
#pragma unroll
      for (int i = 0; i < 32; i += 8)
        tile[ty + i][tx] = mv[(size_t)(by + ty + i)*HDIM + bx + tx];
      __syncthreads();
#pragma unroll
      for (int i = 0; i < 32; i += 8)
        mvT[(size_t)(bx + ty + i)*MS + by + tx] = f2bf(tile[tx][ty + i]);
    }
  }
}

// ---------------------------------------------------------------------------
// Fused GEMM: [q | msc] = hsb @ Wcat^T.  Wcat [1536][1024] bf16.
// cols 0..1023  -> qb bf16 (+bq);  cols 1024..1535 -> msc fp32 (*1/32).
// grid (12, 64); 128x128 tile, BK=32.
// ---------------------------------------------------------------------------
__global__ __launch_bounds__(256) void gemm_qmsc_kernel(
    const unsigned short* __restrict__ A, const unsigned short* __restrict__ Bt,
    const float* __restrict__ bq, unsigned short* __restrict__ qb,
    float* __restrict__ msc) {
  __shared__ __align__(16) unsigned short As[128*32];
  __shared__ __align__(16) unsigned short Bs[128*32];
  const int tid = threadIdx.x;
  const int lane = tid & 63, wave = tid >> 6;
  const int wr = wave >> 1, wc = wave & 1;
  const int row0 = blockIdx.y << 7, col0 = blockIdx.x << 7;

  f32x4 acc[4][4];
#pragma unroll
  for (int m = 0; m < 4; ++m)
#pragma unroll
    for (int n = 0; n < 4; ++n) acc[m][n] = (f32x4)(0.f);

  const int srow = tid >> 2;
  const int sk   = (tid & 3) << 3;
  const unsigned short* gA = A  + (size_t)(row0 + srow)*HDIM + sk;
  const unsigned short* gB = Bt + (size_t)(col0 + srow)*HDIM + sk;
  const int fr = lane & 15;
  const int fk = (lane >> 4) << 3;
  const int fg = lane >> 4;

  for (int k0 = 0; k0 < HDIM; k0 += 32) {
    gload_lds16(gA + k0,             As + tid*8);
    gload_lds16(gA + 64*HDIM + k0,   As + 2048 + tid*8);
    gload_lds16(gB + k0,             Bs + tid*8);
    gload_lds16(gB + 64*HDIM + k0,   Bs + 2048 + tid*8);
    __syncthreads();
    short8 af[4], bf[4];
#pragma unroll
    for (int m = 0; m < 4; ++m)
      af[m] = *(const short8*)&As[(wr*64 + m*16 + fr)*32 + fk];
#pragma unroll
    for (int n = 0; n < 4; ++n)
      bf[n] = *(const short8*)&Bs[(wc*64 + n*16 + fr)*32 + fk];
#pragma unroll
    for (int m = 0; m < 4; ++m)
#pragma unroll
      for (int n = 0; n < 4; ++n)
        acc[m][n] = __builtin_amdgcn_mfma_f32_16x16x32_bf16(af[m], bf[n], acc[m][n], 0, 0, 0);
    __syncthreads();
  }

#pragma unroll
  for (int m = 0; m < 4; ++m) {
#pragma unroll
    for (int n = 0; n < 4; ++n) {
      const int col = col0 + wc*64 + n*16 + fr;
      if (col < HDIM) {
        const float bb = bq[col];
#pragma unroll
        for (int r = 0; r < 4; ++r) {
          const int row = row0 + wr*64 + m*16 + fg*4 + r;
          qb[(size_t)row*HDIM + col] = f2bf(acc[m][n][r] + bb);
        }
      } else {
        const int c2 = col - HDIM;
#pragma unroll
        for (int r = 0; r < 4; ++r) {
          const int row = row0 + wr*64 + m*16 + fg*4 + r;
          msc[(size_t)row*MS + c2] = acc[m][n][r]*0.03125f;
        }
      }
    }
  }
}

// ---------------------------------------------------------------------------
// GEMM (m97 structure): out = ctx @ Wot^T + bo  (fp32 out)
// ---------------------------------------------------------------------------
__global__ __launch_bounds__(256) void gemm_out_kernel(
    const unsigned short* __restrict__ A, const unsigned short* __restrict__ Bt,
    const float* __restrict__ bias, float* __restrict__ C) {
  __shared__ __align__(16) unsigned short As[128*32];
  __shared__ __align__(16) unsigned short Bs[128*32];
  const int tid = threadIdx.x;
  const int lane = tid & 63, wave = tid >> 6;
  const int wr = wave >> 1, wc = wave & 1;
  const int row0 = blockIdx.y << 7, col0 = blockIdx.x << 7;

  f32x4 acc[4][4];
#pragma unroll
  for (int m = 0; m < 4; ++m)
#pragma unroll
    for (int n = 0; n < 4; ++n) acc[m][n] = (f32x4)(0.f);

  const int srow = tid >> 2;
  const int sk   = (tid & 3) << 3;
  const unsigned short* gA = A  + (size_t)(row0 + srow)*HDIM + sk;
  const unsigned short* gB = Bt + (size_t)(col0 + srow)*HDIM + sk;
  const int fr = lane & 15;
  const int fk = (lane >> 4) << 3;
  const int fg = lane >> 4;

  for (int k0 = 0; k0 < HDIM; k0 += 32) {
    gload_lds16(gA + k0,             As + tid*8);
    gload_lds16(gA + 64*HDIM + k0,   As + 2048 + tid*8);
    gload_lds16(gB + k0,             Bs + tid*8);
    gload_lds16(gB + 64*HDIM + k0,   Bs + 2048 + tid*8);
    __syncthreads();
    short8 af[4], bf[4];
#pragma unroll
    for (int m = 0; m < 4; ++m)
      af[m] = *(const short8*)&As[(wr*64 + m*16 + fr)*32 + fk];
#pragma unroll
    for (int n = 0; n < 4; ++n)
      bf[n] = *(const short8*)&Bs[(wc*64 + n*16 + fr)*32 + fk];
#pragma unroll
    for (int m = 0; m < 4; ++m)
#pragma unroll
      for (int n = 0; n < 4; ++n)
        acc[m][n] = __builtin_amdgcn_mfma_f32_16x16x32_bf16(af[m], bf[n], acc[m][n], 0, 0, 0);
    __syncthreads();
  }

#pragma unroll
  for (int m = 0; m < 4; ++m) {
#pragma unroll
    for (int n = 0; n < 4; ++n) {
      const int col = col0 + wc*64 + n*16 + fr;
      const float bb = bias[col];
#pragma unroll
      for (int r = 0; r < 4; ++r) {
        const int row = row0 + wr*64 + m*16 + fg*4 + r;
        C[(size_t)row*HDIM + col] = acc[m][n][r] + bb;
      }
    }
  }
}

// ---------------------------------------------------------------------------
// K5: MFMA landmark attention. Block = 128 tokens x 1 head; 4 waves x 32 rows.
// ---------------------------------------------------------------------------
__global__ __launch_bounds__(256) void attn_mfma_kernel(
    const unsigned short* __restrict__ qb, const float* __restrict__ kbuf,
    const float* __restrict__ vbuf, unsigned short* __restrict__ ctxb) {
  const int tb = blockIdx.x, h = blockIdx.y, b = blockIdx.z;
  const int tid = threadIdx.x;
  const int lane = tid & 63, wave = tid >> 6;
  __shared__ __align__(16) unsigned short Qs[128*64];
  __shared__ __align__(16) unsigned short Ks[64*64];
  __shared__ __align__(16) unsigned short Vt[64*64];
  __shared__ __align__(16) unsigned short Ps[128*64];

  const int tok0 = b*NS + tb*128;
#pragma unroll
  for (int it = 0; it < 4; ++it) {
    const int idx = it*256 + tid;
    gload_lds16(qb + (size_t)(tok0 + (idx >> 3))*HDIM + h*64 + (idx & 7)*8,
                Qs + idx*8);
  }
#pragma unroll
  for (int it = 0; it < 4; ++it) {
    const int i = it*256 + tid;
    const int l = i >> 4, d0 = (i & 15) << 2;
    const size_t base = (size_t)(b*LM + l)*HDIM + h*64 + d0;
    const float4 kv = *(const float4*)(kbuf + base);
    const float4 vv = *(const float4*)(vbuf + base);
    us4 k4; k4.x = f2bf(kv.x); k4.y = f2bf(kv.y); k4.z = f2bf(kv.z); k4.w = f2bf(kv.w);
    *(us4*)&Ks[l*64 + d0] = k4;
    Vt[(d0+0)*64 + l] = f2bf(vv.x);
    Vt[(d0+1)*64 + l] = f2bf(vv.y);
    Vt[(d0+2)*64 + l] = f2bf(vv.z);
    Vt[(d0+3)*64 + l] = f2bf(vv.w);
  }
  __syncthreads();

  const int fr = lane & 15;
  const int fg = lane >> 4;
  const int fk = fg << 3;
  const int wrow = wave*32;

  f32x4 acc[2][4];
#pragma unroll
  for (int m = 0; m < 2; ++m)
#pragma unroll
    for (int n = 0; n < 4; ++n) acc[m][n] = (f32x4)(0.f);
#pragma unroll
  for (int ks = 0; ks < 2; ++ks) {
    short8 af[2], bf[4];
#pragma unroll
    for (int m = 0; m < 2; ++m)
      af[m] = *(const short8*)&Qs[(wrow + m*16 + fr)*64 + ks*32 + fk];
#pragma unroll
    for (int n = 0; n < 4; ++n)
      bf[n] = *(const short8*)&Ks[(n*16 + fr)*64 + ks*32 + fk];
#pragma unroll
    for (int m = 0; m < 2; ++m)
#pragma unroll
      for (int n = 0; n < 4; ++n)
        acc[m][n] = __builtin_amdgcn_mfma_f32_16x16x32_bf16(af[m], bf[n], acc[m][n], 0, 0, 0);
  }

#pragma unroll
  for (int m = 0; m < 2; ++m) {
#pragma unroll
    for (int r = 0; r < 4; ++r) {
      float p0 = acc[m][0][r]*0.125f, p1 = acc[m][1][r]*0.125f;
      float p2 = acc[m][2][r]*0.125f, p3 = acc[m][3][r]*0.125f;
      float mx = fmaxf(fmaxf(p0, p1), fmaxf(p2, p3));
#pragma unroll
      for (int off = 1; off < 16; off <<= 1) mx = fmaxf(mx, __shfl_xor(mx, off));
      p0 = expf(p0 - mx); p1 = expf(p1 - mx); p2 = expf(p2 - mx); p3 = expf(p3 - mx);
      float sm = p0 + p1 + p2 + p3;
#pragma unroll
      for (int off = 1; off < 16; off <<= 1) sm += __shfl_xor(sm, off);
      const float inv = 1.f/sm;
      const int prow = (wrow + m*16 + fg*4 + r)*64;
      Ps[prow + 0*16 + fr] = f2bf(p0*inv);
      Ps[prow + 1*16 + fr] = f2bf(p1*inv);
      Ps[prow + 2*16 + fr] = f2bf(p2*inv);
      Ps[prow + 3*16 + fr] = f2bf(p3*inv);
    }
  }
  __syncthreads();

  f32x4 occ[2][4];
#pragma unroll
  for (int m = 0; m < 2; ++m)
#pragma unroll
    for (int n = 0; n < 4; ++n) occ[m][n] = (f32x4)(0.f);
#pragma unroll
  for (int ks = 0; ks < 2; ++ks) {
    short8 af[2], bf[4];
#pragma unroll
    for (int m = 0; m < 2; ++m)
      af[m] = *(const short8*)&Ps[(wrow + m*16 + fr)*64 + ks*32 + fk];
#pragma unroll
    for (int n = 0; n < 4; ++n)
      bf[n] = *(const short8*)&Vt[(n*16 + fr)*64 + ks*32 + fk];
#pragma unroll
    for (int m = 0; m < 2; ++m)
#pragma unroll
      for (int n = 0; n < 4; ++n)
        occ[m][n] = __builtin_amdgcn_mfma_f32_16x16x32_bf16(af[m], bf[n], occ[m][n], 0, 0, 0);
  }
#pragma unroll
  for (int m = 0; m < 2; ++m)
#pragma unroll
    for (int n = 0; n < 4; ++n)
#pragma unroll
      for (int r = 0; r < 4; ++r)
        ctxb[(size_t)(tok0 + wrow + m*16 + fg*4 + r)*HDIM + h*64 + n*16 + fr] =
            f2bf(occ[m][n][r]);
}

// ---------------------------------------------------------------------------
// K8a: wave-per-token top-32 THRESHOLD selection -> dense weight row.
// Finds T = 32nd-largest packed key (value desc, idx asc — exact jax order),
// then each lane writes softmax weight (or 0) for its 8 slots.
// Wm[token][m] = softmax weight if selected else 0 (bf16). Zero block barriers.
// ---------------------------------------------------------------------------
__global__ __launch_bounds__(256) void sel_kernel(
    const float* __restrict__ msc, unsigned short* __restrict__ Wm) {
  const int tid = threadIdx.x;
  const int lane = tid & 63, wave = tid >> 6;
  const int token = blockIdx.x*4 + wave;

  __shared__ __align__(16) int s_hist[4][256];
  __shared__ unsigned long long s_list[4][256];
  __shared__ int s_B[4], s_above[4], s_nlist[4];

  *(int4*)&s_hist[wave][lane*4] = make_int4(0, 0, 0, 0);
  if (lane == 0) s_nlist[wave] = 0;

  float v[8];
#pragma unroll
  for (int j = 0; j < 8; ++j) v[j] = msc[(size_t)token*MS + j*64 + lane];

  // wave max/min
  float mx = v[0], mn = v[0];
#pragma unroll
  for (int j = 1; j < 8; ++j) { mx = fmaxf(mx, v[j]); mn = fminf(mn, v[j]); }
#pragma unroll
  for (int off = 32; off > 0; off >>= 1) {
    mx = fmaxf(mx, __shfl_xor(mx, off));
    mn = fminf(mn, __shfl_xor(mn, off));
  }
  const float range = mx - mn;
  const float scale = (range > 1e-20f) ? 255.f/range : 0.f;

  __builtin_amdgcn_wave_barrier();
  int bins[8];
#pragma unroll
  for (int j = 0; j < 8; ++j) {
    int b = (int)((v[j] - mn)*scale);
    bins[j] = b > 255 ? 255 : b;
    atomicAdd(&s_hist[wave][bins[j]], 1);
  }
  __builtin_amdgcn_wave_barrier();

  // suffix counts: lane owns bins [4l,4l+4); shfl-doubling over lane totals
  const int4 c = *(const int4*)&s_hist[wave][lane*4];
  const int lane_total = c.x + c.y + c.z + c.w;
  int sfx = lane_total;
#pragma unroll
  for (int off = 1; off < 64; off <<= 1) {
    const int src = lane + off;
    int y = __shfl(sfx, src < 64 ? src : lane);
    sfx += (src < 64) ? y : 0;
  }
  const int beyond = sfx - lane_total;
  const int s3 = c.w + beyond;
  const int s2 = c.z + s3;
  const int s1 = c.y + s2;
  const int s0 = c.x + s1;
  // unique crossing bin B: sfx[B] >= 32 > sfx[B+1]; above = sfx[B+1] < 32
  int Bl = -1, abv = 0;
  if (s0 >= KSEL && s1 < KSEL) { Bl = lane*4 + 0; abv = s1; }
  if (s1 >= KSEL && s2 < KSEL) { Bl = lane*4 + 1; abv = s2; }
  if (s2 >= KSEL && s3 < KSEL) { Bl = lane*4 + 2; abv = s3; }
  if (s3 >= KSEL && beyond < KSEL) { Bl = lane*4 + 3; abv = beyond; }
  if (Bl >= 0) { s_B[wave] = Bl; s_above[wave] = abv; }
  __builtin_amdgcn_wave_barrier();
  const int B = s_B[wave];
  const int rem = KSEL - s_above[wave];   // >= 1 by construction

  // boundary-bin candidates -> list (packed u64 keys; cap 256, non-degenerate
  // data puts only a handful of the 512 values in the crossing bin)
#pragma unroll
  for (int j = 0; j < 8; ++j) {
    if (bins[j] == B) {
      const unsigned int u = __float_as_uint(v[j]);
      const unsigned int vk = (u & 0x80000000u) ? ~u : (u | 0x80000000u);
      const int p = atomicAdd(&s_nlist[wave], 1);
      if (p < 256)
        s_list[wave][p] = ((unsigned long long)vk << 32) | (unsigned int)~(j*64 + lane);
    }
  }
  __builtin_amdgcn_wave_barrier();

  // T = rem-th largest boundary key (iterative wave-argmax; rem typically 1-5)
  const int nl = s_nlist[wave] < 256 ? s_nlist[wave] : 256;
  unsigned long long T = ~0ull;
  for (int r = 0; r < rem; ++r) {
    unsigned long long best = 0; int pos = -1;
    for (int i = lane; i < nl; i += 64)
      if (s_list[wave][i] > best) { best = s_list[wave][i]; pos = i; }
#pragma unroll
    for (int off = 32; off > 0; off >>= 1) {
      const unsigned long long ob = __shfl_xor(best, off);
      const int op = __shfl_xor(pos, off);
      if (ob > best) { best = ob; pos = op; }
    }
    if (lane == 0) s_list[wave][pos] = 0;
    T = best;
    __builtin_amdgcn_wave_barrier();
  }

  // local selection test + softmax (mx = exact row max, always selected)
  float e[8];
  float esum = 0.f;
#pragma unroll
  for (int j = 0; j < 8; ++j) {
    bool sel = bins[j] > B;
    if (!sel && bins[j] == B) {
      const unsigned int u = __float_as_uint(v[j]);
      const unsigned int vk = (u & 0x80000000u) ? ~u : (u | 0x80000000u);
      const unsigned long long key =
          ((unsigned long long)vk << 32) | (unsigned int)~(j*64 + lane);
      sel = key >= T;
    }
    e[j] = sel ? expf(v[j] - mx) : 0.f;
    esum += e[j];
  }
#pragma unroll
  for (int off = 32; off > 0; off >>= 1) esum += __shfl_xor(esum, off);
  const float inv = 1.f/esum;
#pragma unroll
  for (int j = 0; j < 8; ++j)
    Wm[(size_t)token*MS + j*64 + lane] = f2bf(e[j]*inv);
}

// ---------------------------------------------------------------------------
// K8b: mem_out via dense MFMA GEMM over the sparse weight rows:
// out[row][col] += gate[row] * (Wm[row][:] @ mvT[col][:]).
// M=NTOK, N=HDIM, K=MS. grid (8, 64).
// ---------------------------------------------------------------------------
__global__ __launch_bounds__(256) void gemm_mem_kernel(
    const unsigned short* __restrict__ Wm, const unsigned short* __restrict__ mvT,
    const float* __restrict__ gate, float* __restrict__ out) {
  __shared__ __align__(16) unsigned short As[128*32];
  __shared__ __align__(16) unsigned short Bs[128*32];
  const int tid = threadIdx.x;
  const int lane = tid & 63, wave = tid >> 6;
  const int wr = wave >> 1, wc = wave & 1;
  const int row0 = blockIdx.y << 7, col0 = blockIdx.x << 7;

  f32x4 acc[4][4];
#pragma unroll
  for (int m = 0; m < 4; ++m)
#pragma unroll
    for (int n = 0; n < 4; ++n) acc[m][n] = (f32x4)(0.f);

  const int srow = tid >> 2;
  const int sk   = (tid & 3) << 3;
  const unsigned short* gA = Wm  + (size_t)(row0 + srow)*MS + sk;
  const unsigned short* gB = mvT + (size_t)(col0 + srow)*MS + sk;
  const int fr = lane & 15;
  const int fk = (lane >> 4) << 3;
  const int fg = lane >> 4;

  for (int k0 = 0; k0 < MS; k0 += 32) {
    gload_lds16(gA + k0,           As + tid*8);
    gload_lds16(gA + 64*MS + k0,   As + 2048 + tid*8);
    gload_lds16(gB + k0,           Bs + tid*8);
    gload_lds16(gB + 64*MS + k0,   Bs + 2048 + tid*8);
    __syncthreads();
    short8 af[4], bf[4];
#pragma unroll
    for (int m = 0; m < 4; ++m)
      af[m] = *(const short8*)&As[(wr*64 + m*16 + fr)*32 + fk];
#pragma unroll
    for (int n = 0; n < 4; ++n)
      bf[n] = *(const short8*)&Bs[(wc*64 + n*16 + fr)*32 + fk];
#pragma unroll
    for (int m = 0; m < 4; ++m)
#pragma unroll
      for (int n = 0; n < 4; ++n)
        acc[m][n] = __builtin_amdgcn_mfma_f32_16x16x32_bf16(af[m], bf[n], acc[m][n], 0, 0, 0);
    __syncthreads();
  }

#pragma unroll
  for (int m = 0; m < 4; ++m) {
#pragma unroll
    for (int r = 0; r < 4; ++r) {
      const int row = row0 + wr*64 + m*16 + fg*4 + r;
      const float g = gate[row];
#pragma unroll
      for (int n = 0; n < 4; ++n) {
        const int col = col0 + wc*64 + n*16 + fr;
        out[(size_t)row*HDIM + col] += g*acc[m][n][r];
      }
    }
  }
}

// ---------------------------------------------------------------------------
extern "C" void kernel_launch(void* const* d_in, const int* in_sizes, int n_in,
                              void* d_out, int out_size, void* d_ws, size_t ws_size,
                              hipStream_t stream) {
  const float* hs = (const float*)d_in[0];
  const float* Wq = (const float*)d_in[1];
  const float* bq = (const float*)d_in[2];
  const float* Wk = (const float*)d_in[3];
  const float* bk = (const float*)d_in[4];
  const float* Wv = (const float*)d_in[5];
  const float* bv = (const float*)d_in[6];
  const float* Wo = (const float*)d_in[7];
  const float* bo = (const float*)d_in[8];
  const float* mk = (const float*)d_in[9];
  const float* mv = (const float*)d_in[10];
  const float* gw = (const float*)d_in[11];
  const float* gb = (const float*)d_in[12];
  float* out = (float*)d_out;

  // Workspace (peak ~64 MB). Aliases (all producer-after-last-consumer on
  // the single stream):  ctxb = hsb (hsb last read by gemm_qmsc);
  //                      Wm   = qb  (qb last read by attn).
  char* ws = (char*)d_ws;
  unsigned short* hsb  = (unsigned short*)(ws);                       // 16 MiB bf16 [NTOK,HDIM]
  unsigned short* ctxb = hsb;                                         // alias
  unsigned short* qb   = (unsigned short*)(ws + ((size_t)16 << 20));  // 16 MiB bf16
  unsigned short* Wm   = qb;                                          // alias, 8 MiB [NTOK,MS]
  float*          msc  = (float*)(ws + ((size_t)32 << 20));           // 16 MiB fp32 [NTOK,MS]
  unsigned short* Wkvt = (unsigned short*)(ws + ((size_t)48 << 20));  // 4 MiB [2048][1024]
  unsigned short* Wcat = (unsigned short*)(ws + ((size_t)52 << 20));  // 3 MiB [1536][1024]
  unsigned short* Wot  = (unsigned short*)(ws + ((size_t)55 << 20));  // 2 MiB
  unsigned short* mvT  = (unsigned short*)(ws + ((size_t)57 << 20));  // 1 MiB [HDIM][MS]
  float*          kbuf = (float*)(ws + ((size_t)58 << 20));           // 512 KiB
  float*          vbuf = (float*)(ws + ((size_t)58 << 20) + ((size_t)512 << 10));
  unsigned short* g    = (unsigned short*)(ws + ((size_t)59 << 20));  // 256 KiB
  float*          part = (float*)(ws + ((size_t)59 << 20) + ((size_t)256 << 10)); // 4 MiB
  float*          imp  = (float*)(ws + ((size_t)64 << 20));           // 32 KiB
  float*          gate = (float*)(ws + ((size_t)64 << 20) + ((size_t)32 << 10));
  int*            cnt  = (int*)  (ws + ((size_t)64 << 20) + ((size_t)64 << 10)); // 32 KiB
  int*            lmi  = (int*)  (ws + ((size_t)64 << 20) + ((size_t)96 << 10)); // 4 KiB

  imp_gate_kernel<<<dim3(NTOK/4), 256, 0, stream>>>(hs, gw, gb, imp, gate, hsb);
  hipMemsetAsync(cnt, 0, NB*NS*sizeof(int), stream);
  lm_count_kernel<<<dim3(NS/256, 4, NB), 256, 0, stream>>>(imp, cnt);
  lm_sel_kernel<<<dim3(NS/256, NB), 256, 0, stream>>>(cnt, lmi);
  prep_kernel<<<dim3(32, 32, 5), 256, 0, stream>>>(
      Wk, Wv, Wq, Wo, mk, mv, Wkvt, Wcat, Wot, mvT);
  // K/V projection of landmark rows via MFMA GEMM (split-K=4)
  lm_gather_kernel<<<dim3(NB*LM), 256, 0, stream>>>(hsb, lmi, g);
  kvproj_gemm_kernel<<<dim3(16, 4), 256, 0, stream>>>(g, Wkvt, part);
  kv_reduce2_kernel<<<dim3(8, 128), 256, 0, stream>>>(part, bk, bv, kbuf, vbuf);
  // fused Q-projection + memory scores (reads hsb for the last time)
  gemm_qmsc_kernel<<<dim3(12, NTOK/128), 256, 0, stream>>>(hsb, Wcat, bq, qb, msc);
  // attention (writes ctxb over hsb; reads qb for the last time)
  attn_mfma_kernel<<<dim3(NS/128, NHEAD, NB), 256, 0, stream>>>(qb, kbuf, vbuf, ctxb);
  gemm_out_kernel<<<dim3(8, NTOK/128), 256, 0, stream>>>(ctxb, Wot, bo, out);
  // memory bank: threshold selection -> dense weight rows -> MFMA GEMM
  sel_kernel<<<dim3(NTOK/4), 256, 0, stream>>>(msc, Wm);
  gemm_mem_kernel<<<dim3(8, NTOK/128), 256, 0, stream>>>(Wm, mvT, gate, out);
}

// Round 11
// 167.891 us; speedup vs baseline: 6.0666x; 1.0869x over previous
//
#include <hip/hip_runtime.h>
#include <math.h>

// Problem constants (from reference setup_inputs)
#define HDIM 1024
#define NHEAD 16
#define HD 64
#define LM 64          // NUM_LANDMARKS
#define MS 512         // memory slots
#define KSEL 32        // top_k
#define NB 2
#define NS 4096
#define NTOK (NB*NS)   // 8192

typedef __attribute__((ext_vector_type(8))) short short8;
typedef __attribute__((ext_vector_type(4))) float f32x4;
typedef __attribute__((ext_vector_type(4))) unsigned short us4;

__device__ __forceinline__ unsigned short f2bf(float f) {
  unsigned int u = __float_as_uint(f);
  unsigned int r = (u + 0x7fffu + ((u >> 16) & 1u)) >> 16;
  return (unsigned short)r;
}
__device__ __forceinline__ float bf2f(unsigned short u) {
  return __uint_as_float(((unsigned int)u) << 16);
}

__device__ __forceinline__ void gload_lds16(const unsigned short* g, unsigned short* l) {
  __builtin_amdgcn_global_load_lds(
      (const __attribute__((address_space(1))) unsigned int*)g,
      (__attribute__((address_space(3))) unsigned int*)l,
      16, 0, 0);
}

// ---------------------------------------------------------------------------
// K1: wave-per-row importance (sum sq) + gate + hs -> bf16. Block = 4 rows.
// ---------------------------------------------------------------------------
__global__ __launch_bounds__(256) void imp_gate_kernel(
    const float* __restrict__ hs, const float* __restrict__ gw,
    const float* __restrict__ gb, float* __restrict__ imp,
    float* __restrict__ gate, unsigned short* __restrict__ hsb) {
  const int lane = threadIdx.x & 63, wave = threadIdx.x >> 6;
  const int row = blockIdx.x*4 + wave;
  float ss = 0.f, dg = 0.f;
#pragma unroll
  for (int c = 0; c < 4; ++c) {
    const int d = c*256 + lane*4;
    const float4 hv = *(const float4*)(hs + (size_t)row*HDIM + d);
    const float4 gv = *(const float4*)(gw + d);
    ss += hv.x*hv.x + hv.y*hv.y + hv.z*hv.z + hv.w*hv.w;
    dg += hv.x*gv.x + hv.y*gv.y + hv.z*gv.z + hv.w*gv.w;
    us4 hb;
    hb.x = f2bf(hv.x); hb.y = f2bf(hv.y); hb.z = f2bf(hv.z); hb.w = f2bf(hv.w);
    *(us4*)(hsb + (size_t)row*HDIM + d) = hb;
  }
#pragma unroll
  for (int off = 32; off > 0; off >>= 1) {
    ss += __shfl_xor(ss, off);
    dg += __shfl_xor(dg, off);
  }
  if (lane == 0) {
    imp[row] = ss;
    gate[row] = 1.f/(1.f + expf(-(dg + gb[0])));
  }
}

// ---------------------------------------------------------------------------
// K2a: rank counting, parallel over (candidate, j-chunk).
// rank(i) = #{j : v[j] > v[i]  or  (v[j]==v[i] and j<i)}  (jax tie-break).
// ---------------------------------------------------------------------------
__global__ __launch_bounds__(256) void lm_count_kernel(
    const float* __restrict__ imp, int* __restrict__ cnt) {
  const int b = blockIdx.z;
  const int jc = blockIdx.y;
  const int i = blockIdx.x*256 + threadIdx.x;
  const float* v = imp + b*NS;
  const float mine = v[i];
  __shared__ float tile[1024];
  const int j0 = jc*1024;
  *(float4*)&tile[threadIdx.x*4] = *(const float4*)&v[j0 + threadIdx.x*4];
  __syncthreads();
  int c = 0;
#pragma unroll 8
  for (int p = 0; p < 1024; p += 4) {
    const float4 t = *(const float4*)&tile[p];
    c += (t.x > mine) || (t.x == mine && (j0+p+0) < i);
    c += (t.y > mine) || (t.y == mine && (j0+p+1) < i);
    c += (t.z > mine) || (t.z == mine && (j0+p+2) < i);
    c += (t.w > mine) || (t.w == mine && (j0+p+3) < i);
  }
  atomicAdd(&cnt[b*NS + i], c);
}

// K2b: scatter selected candidates (set only; order irrelevant downstream).
__global__ __launch_bounds__(256) void lm_sel_kernel(
    const int* __restrict__ cnt, int* __restrict__ lm_idx) {
  const int b = blockIdx.y;
  const int i = blockIdx.x*256 + threadIdx.x;
  const int c = cnt[b*NS + i];
  if (c < LM) lm_idx[b*LM + c] = i;
}

// ---------------------------------------------------------------------------
// K3a: gather 128 landmark rows (bf16) into compact g[NB*LM][HDIM]
// ---------------------------------------------------------------------------
__global__ __launch_bounds__(256) void lm_gather_kernel(
    const unsigned short* __restrict__ hsb, const int* __restrict__ lmi,
    unsigned short* __restrict__ g) {
  const int j = blockIdx.x;           // 0..127 = b*LM + l
  const int b = j >> 6;
  const int idx = lmi[j];
  const us4 v = *(const us4*)(hsb + ((size_t)(b*NS + idx))*HDIM + threadIdx.x*4);
  *(us4*)(g + (size_t)j*HDIM + threadIdx.x*4) = v;
}

// ---------------------------------------------------------------------------
// K3b: K/V projection as bf16 MFMA GEMM, split-K=4.
// ---------------------------------------------------------------------------
__global__ __launch_bounds__(256) void kvproj_gemm_kernel(
    const unsigned short* __restrict__ g, const unsigned short* __restrict__ Wkvt,
    float* __restrict__ part) {
  __shared__ __align__(16) unsigned short As[128*32];
  __shared__ __align__(16) unsigned short Bs[128*32];
  const int tid = threadIdx.x;
  const int lane = tid & 63, wave = tid >> 6;
  const int wr = wave >> 1, wc = wave & 1;
  const int col0 = blockIdx.x << 7;
  const int sp = blockIdx.y;
  const int k00 = sp << 8;

  f32x4 acc[4][4];
#pragma unroll
  for (int m = 0; m < 4; ++m)
#pragma unroll
    for (int n = 0; n < 4; ++n) acc[m][n] = (f32x4)(0.f);

  const int srow = tid >> 2;
  const int sk   = (tid & 3) << 3;
  const unsigned short* gA = g    + (size_t)srow*HDIM + sk;
  const unsigned short* gB = Wkvt + (size_t)(col0 + srow)*HDIM + sk;
  const int fr = lane & 15;
  const int fk = (lane >> 4) << 3;
  const int fg = lane >> 4;

  for (int k0 = k00; k0 < k00 + 256; k0 += 32) {
    gload_lds16(gA + k0,             As + tid*8);
    gload_lds16(gA + 64*HDIM + k0,   As + 2048 + tid*8);
    gload_lds16(gB + k0,             Bs + tid*8);
    gload_lds16(gB + 64*HDIM + k0,   Bs + 2048 + tid*8);
    __syncthreads();
    short8 af[4], bf[4];
#pragma unroll
    for (int m = 0; m < 4; ++m)
      af[m] = *(const short8*)&As[(wr*64 + m*16 + fr)*32 + fk];
#pragma unroll
    for (int n = 0; n < 4; ++n)
      bf[n] = *(const short8*)&Bs[(wc*64 + n*16 + fr)*32 + fk];
#pragma unroll
    for (int m = 0; m < 4; ++m)
#pragma unroll
      for (int n = 0; n < 4; ++n)
        acc[m][n] = __builtin_amdgcn_mfma_f32_16x16x32_bf16(af[m], bf[n], acc[m][n], 0, 0, 0);
    __syncthreads();
  }
#pragma unroll
  for (int m = 0; m < 4; ++m)
#pragma unroll
    for (int n = 0; n < 4; ++n) {
      const int colg = col0 + wc*64 + n*16 + fr;
#pragma unroll
      for (int r = 0; r < 4; ++r) {
        const int row = wr*64 + m*16 + fg*4 + r;
        part[((size_t)(sp*128 + row))*2048 + colg] = acc[m][n][r];
      }
    }
}

// K3c: reduce 4 K-split partials + bias -> kbuf/vbuf fp32. grid (8, 128).
__global__ __launch_bounds__(256) void kv_reduce2_kernel(
    const float* __restrict__ part, const float* __restrict__ bk,
    const float* __restrict__ bv, float* __restrict__ kbuf,
    float* __restrict__ vbuf) {
  const int row = blockIdx.y;
  const int col = blockIdx.x*256 + threadIdx.x;
  float s = 0.f;
#pragma unroll
  for (int sp = 0; sp < 4; ++sp)
    s += part[((size_t)(sp*128 + row))*2048 + col];
  if (col < HDIM) kbuf[(size_t)row*HDIM + col] = s + bk[col];
  else            vbuf[(size_t)row*HDIM + col - HDIM] = s + bv[col - HDIM];
}

// ---------------------------------------------------------------------------
// Prep (fused): z<4 -> transpose+convert W; z==4 -> blk<512: conv mk into
// Wcat tail; blk>=512: transpose+convert mem_values -> mvT[1024][512] bf16.
// grid (32, 32, 5)
// ---------------------------------------------------------------------------
__global__ __launch_bounds__(256) void prep_kernel(
    const float* __restrict__ Wk, const float* __restrict__ Wv,
    const float* __restrict__ Wq, const float* __restrict__ Wo,
    const float* __restrict__ mk, const float* __restrict__ mv,
    unsigned short* __restrict__ Wkvt, unsigned short* __restrict__ Wcat,
    unsigned short* __restrict__ Wot, unsigned short* __restrict__ mvT) {
  const int z = blockIdx.z;
  __shared__ float tile[32][33];
  const int tx = threadIdx.x & 31, ty = threadIdx.x >> 5;
  if (z < 4) {
    const float* W = (z == 0) ? Wk : (z == 1) ? Wv : (z == 2) ? Wq : Wo;
    unsigned short* Wt = (z == 0) ? Wkvt
                       : (z == 1) ? (Wkvt + (size_t)HDIM*HDIM)
                       : (z == 2) ? Wcat : Wot;
    const int bx = blockIdx.x * 32, by = blockIdx.y * 32;
#pragma unroll
    for (int i = 0; i < 32; i += 8)
      tile[ty + i][tx] = W[(size_t)(by + ty + i)*HDIM + bx + tx];
    __syncthreads();
#pragma unroll
    for (int i = 0; i < 32; i += 8)
      Wt[(size_t)(bx + ty + i)*HDIM + by + tx] = f2bf(tile[tx][ty + i]);
  } else {
    const int blk = blockIdx.y*32 + blockIdx.x;     // 0..1023
    if (blk < 512) {
      // mem_keys [MS][HDIM] = [N][K] already -> append to Wcat rows 1024..1535
      const int off = (blk << 10) + threadIdx.x*4;
      const float4 v = *(const float4*)&mk[off];
      us4 w;
      w.x = f2bf(v.x); w.y = f2bf(v.y); w.z = f2bf(v.z); w.w = f2bf(v.w);
      *(us4*)&(Wcat + (size_t)HDIM*HDIM)[off] = w;
    } else {
      // transpose mem_values [512][1024] -> mvT [1024][512]
      const int t = blk - 512;                      // 0..511
      const int by = (t >> 5) * 32;                 // row block in mv (0..480)
      const int bx = (t & 31) * 32;                 // col block in mv (0..992)
#pragma unroll
      for (int i = 0; i < 32; i += 8)
        tile[ty + i][tx] = mv[(size_t)(by + ty + i)*HDIM + bx + tx];
      __syncthreads();
#pragma unroll
      for (int i = 0; i < 32; i += 8)
        mvT[(size_t)(bx + ty + i)*MS + by + tx] = f2bf(tile[tx][ty + i]);
    }
  }
}

// ---------------------------------------------------------------------------
// Fused GEMM: [q | msc] = hsb @ Wcat^T.  Wcat [1536][1024] bf16.
// cols 0..1023  -> qb bf16 (+bq);  cols 1024..1535 -> msc fp32 (*1/32).
// Launched flat (768 blocks) with XCD-aware swizzle: each XCD gets 96
// consecutive logical tiles (8 A row-panels x all 12 B col-panels) so the
// per-XCD L2 holds the working set instead of round-robin scatter.
// ---------------------------------------------------------------------------
__global__ __launch_bounds__(256) void gemm_qmsc_kernel(
    const unsigned short* __restrict__ A, const unsigned short* __restrict__ Bt,
    const float* __restrict__ bq, unsigned short* __restrict__ qb,
    float* __restrict__ msc) {
  __shared__ __align__(16) unsigned short As[128*32];
  __shared__ __align__(16) unsigned short Bs[128*32];
  const int tid = threadIdx.x;
  const int lane = tid & 63, wave = tid >> 6;
  const int wr = wave >> 1, wc = wave & 1;
  const int wg = blockIdx.x;                    // 0..767, nwg%8==0
  const int swz = (wg & 7)*96 + (wg >> 3);      // bijective XCD swizzle
  const int bx = swz % 12, by = swz / 12;
  const int row0 = by << 7, col0 = bx << 7;

  f32x4 acc[4][4];
#pragma unroll
  for (int m = 0; m < 4; ++m)
#pragma unroll
    for (int n = 0; n < 4; ++n) acc[m][n] = (f32x4)(0.f);

  const int srow = tid >> 2;
  const int sk   = (tid & 3) << 3;
  const unsigned short* gA = A  + (size_t)(row0 + srow)*HDIM + sk;
  const unsigned short* gB = Bt + (size_t)(col0 + srow)*HDIM + sk;
  const int fr = lane & 15;
  const int fk = (lane >> 4) << 3;
  const int fg = lane >> 4;

  for (int k0 = 0; k0 < HDIM; k0 += 32) {
    gload_lds16(gA + k0,             As + tid*8);
    gload_lds16(gA + 64*HDIM + k0,   As + 2048 + tid*8);
    gload_lds16(gB + k0,             Bs + tid*8);
    gload_lds16(gB + 64*HDIM + k0,   Bs + 2048 + tid*8);
    __syncthreads();
    short8 af[4], bf[4];
#pragma unroll
    for (int m = 0; m < 4; ++m)
      af[m] = *(const short8*)&As[(wr*64 + m*16 + fr)*32 + fk];
#pragma unroll
    for (int n = 0; n < 4; ++n)
      bf[n] = *(const short8*)&Bs[(wc*64 + n*16 + fr)*32 + fk];
#pragma unroll
    for (int m = 0; m < 4; ++m)
#pragma unroll
      for (int n = 0; n < 4; ++n)
        acc[m][n] = __builtin_amdgcn_mfma_f32_16x16x32_bf16(af[m], bf[n], acc[m][n], 0, 0, 0);
    __syncthreads();
  }

#pragma unroll
  for (int m = 0; m < 4; ++m) {
#pragma unroll
    for (int n = 0; n < 4; ++n) {
      const int col = col0 + wc*64 + n*16 + fr;
      if (col < HDIM) {
        const float bb = bq[col];
#pragma unroll
        for (int r = 0; r < 4; ++r) {
          const int row = row0 + wr*64 + m*16 + fg*4 + r;
          qb[(size_t)row*HDIM + col] = f2bf(acc[m][n][r] + bb);
        }
      } else {
        const int c2 = col - HDIM;
#pragma unroll
        for (int r = 0; r < 4; ++r) {
          const int row = row0 + wr*64 + m*16 + fg*4 + r;
          msc[(size_t)row*MS + c2] = acc[m][n][r]*0.03125f;
        }
      }
    }
  }
}

// ---------------------------------------------------------------------------
// K5: MFMA landmark attention. Block = 128 tokens x 1 head; 4 waves x 32 rows.
// ---------------------------------------------------------------------------
__global__ __launch_bounds__(256) void attn_mfma_kernel(
    const unsigned short* __restrict__ qb, const float* __restrict__ kbuf,
    const float* __restrict__ vbuf, unsigned short* __restrict__ ctxb) {
  const int tb = blockIdx.x, h = blockIdx.y, b = blockIdx.z;
  const int tid = threadIdx.x;
  const int lane = tid & 63, wave = tid >> 6;
  __shared__ __align__(16) unsigned short Qs[128*64];
  __shared__ __align__(16) unsigned short Ks[64*64];
  __shared__ __align__(16) unsigned short Vt[64*64];
  __shared__ __align__(16) unsigned short Ps[128*64];

  const int tok0 = b*NS + tb*128;
#pragma unroll
  for (int it = 0; it < 4; ++it) {
    const int idx = it*256 + tid;
    gload_lds16(qb + (size_t)(tok0 + (idx >> 3))*HDIM + h*64 + (idx & 7)*8,
                Qs + idx*8);
  }
#pragma unroll
  for (int it = 0; it < 4; ++it) {
    const int i = it*256 + tid;
    const int l = i >> 4, d0 = (i & 15) << 2;
    const size_t base = (size_t)(b*LM + l)*HDIM + h*64 + d0;
    const float4 kv = *(const float4*)(kbuf + base);
    const float4 vv = *(const float4*)(vbuf + base);
    us4 k4; k4.x = f2bf(kv.x); k4.y = f2bf(kv.y); k4.z = f2bf(kv.z); k4.w = f2bf(kv.w);
    *(us4*)&Ks[l*64 + d0] = k4;
    Vt[(d0+0)*64 + l] = f2bf(vv.x);
    Vt[(d0+1)*64 + l] = f2bf(vv.y);
    Vt[(d0+2)*64 + l] = f2bf(vv.z);
    Vt[(d0+3)*64 + l] = f2bf(vv.w);
  }
  __syncthreads();

  const int fr = lane & 15;
  const int fg = lane >> 4;
  const int fk = fg << 3;
  const int wrow = wave*32;

  f32x4 acc[2][4];
#pragma unroll
  for (int m = 0; m < 2; ++m)
#pragma unroll
    for (int n = 0; n < 4; ++n) acc[m][n] = (f32x4)(0.f);
#pragma unroll
  for (int ks = 0; ks < 2; ++ks) {
    short8 af[2], bf[4];
#pragma unroll
    for (int m = 0; m < 2; ++m)
      af[m] = *(const short8*)&Qs[(wrow + m*16 + fr)*64 + ks*32 + fk];
#pragma unroll
    for (int n = 0; n < 4; ++n)
      bf[n] = *(const short8*)&Ks[(n*16 + fr)*64 + ks*32 + fk];
#pragma unroll
    for (int m = 0; m < 2; ++m)
#pragma unroll
      for (int n = 0; n < 4; ++n)
        acc[m][n] = __builtin_amdgcn_mfma_f32_16x16x32_bf16(af[m], bf[n], acc[m][n], 0, 0, 0);
  }

#pragma unroll
  for (int m = 0; m < 2; ++m) {
#pragma unroll
    for (int r = 0; r < 4; ++r) {
      float p0 = acc[m][0][r]*0.125f, p1 = acc[m][1][r]*0.125f;
      float p2 = acc[m][2][r]*0.125f, p3 = acc[m][3][r]*0.125f;
      float mx = fmaxf(fmaxf(p0, p1), fmaxf(p2, p3));
#pragma unroll
      for (int off = 1; off < 16; off <<= 1) mx = fmaxf(mx, __shfl_xor(mx, off));
      p0 = expf(p0 - mx); p1 = expf(p1 - mx); p2 = expf(p2 - mx); p3 = expf(p3 - mx);
      float sm = p0 + p1 + p2 + p3;
#pragma unroll
      for (int off = 1; off < 16; off <<= 1) sm += __shfl_xor(sm, off);
      const float inv = 1.f/sm;
      const int prow = (wrow + m*16 + fg*4 + r)*64;
      Ps[prow + 0*16 + fr] = f2bf(p0*inv);
      Ps[prow + 1*16 + fr] = f2bf(p1*inv);
      Ps[prow + 2*16 + fr] = f2bf(p2*inv);
      Ps[prow + 3*16 + fr] = f2bf(p3*inv);
    }
  }
  __syncthreads();

  f32x4 occ[2][4];
#pragma unroll
  for (int m = 0; m < 2; ++m)
#pragma unroll
    for (int n = 0; n < 4; ++n) occ[m][n] = (f32x4)(0.f);
#pragma unroll
  for (int ks = 0; ks < 2; ++ks) {
    short8 af[2], bf[4];
#pragma unroll
    for (int m = 0; m < 2; ++m)
      af[m] = *(const short8*)&Ps[(wrow + m*16 + fr)*64 + ks*32 + fk];
#pragma unroll
    for (int n = 0; n < 4; ++n)
      bf[n] = *(const short8*)&Vt[(n*16 + fr)*64 + ks*32 + fk];
#pragma unroll
    for (int m = 0; m < 2; ++m)
#pragma unroll
      for (int n = 0; n < 4; ++n)
        occ[m][n] = __builtin_amdgcn_mfma_f32_16x16x32_bf16(af[m], bf[n], occ[m][n], 0, 0, 0);
  }
#pragma unroll
  for (int m = 0; m < 2; ++m)
#pragma unroll
    for (int n = 0; n < 4; ++n)
#pragma unroll
      for (int r = 0; r < 4; ++r)
        ctxb[(size_t)(tok0 + wrow + m*16 + fg*4 + r)*HDIM + h*64 + n*16 + fr] =
            f2bf(occ[m][n][r]);
}

// ---------------------------------------------------------------------------
// K8a: wave-per-token top-32 THRESHOLD selection -> dense weight row,
// PRE-SCALED by gate[token]: Wm[token][m] = gate*softmax_w or 0 (bf16).
// ---------------------------------------------------------------------------
__global__ __launch_bounds__(256) void sel_kernel(
    const float* __restrict__ msc, const float* __restrict__ gate,
    unsigned short* __restrict__ Wm) {
  const int tid = threadIdx.x;
  const int lane = tid & 63, wave = tid >> 6;
  const int token = blockIdx.x*4 + wave;

  __shared__ __align__(16) int s_hist[4][256];
  __shared__ unsigned long long s_list[4][256];
  __shared__ int s_B[4], s_above[4], s_nlist[4];

  *(int4*)&s_hist[wave][lane*4] = make_int4(0, 0, 0, 0);
  if (lane == 0) s_nlist[wave] = 0;

  float v[8];
#pragma unroll
  for (int j = 0; j < 8; ++j) v[j] = msc[(size_t)token*MS + j*64 + lane];

  float mx = v[0], mn = v[0];
#pragma unroll
  for (int j = 1; j < 8; ++j) { mx = fmaxf(mx, v[j]); mn = fminf(mn, v[j]); }
#pragma unroll
  for (int off = 32; off > 0; off >>= 1) {
    mx = fmaxf(mx, __shfl_xor(mx, off));
    mn = fminf(mn, __shfl_xor(mn, off));
  }
  const float range = mx - mn;
  const float scale = (range > 1e-20f) ? 255.f/range : 0.f;

  __builtin_amdgcn_wave_barrier();
  int bins[8];
#pragma unroll
  for (int j = 0; j < 8; ++j) {
    int b = (int)((v[j] - mn)*scale);
    bins[j] = b > 255 ? 255 : b;
    atomicAdd(&s_hist[wave][bins[j]], 1);
  }
  __builtin_amdgcn_wave_barrier();

  const int4 c = *(const int4*)&s_hist[wave][lane*4];
  const int lane_total = c.x + c.y + c.z + c.w;
  int sfx = lane_total;
#pragma unroll
  for (int off = 1; off < 64; off <<= 1) {
    const int src = lane + off;
    int y = __shfl(sfx, src < 64 ? src : lane);
    sfx += (src < 64) ? y : 0;
  }
  const int beyond = sfx - lane_total;
  const int s3 = c.w + beyond;
  const int s2 = c.z + s3;
  const int s1 = c.y + s2;
  const int s0 = c.x + s1;
  int Bl = -1, abv = 0;
  if (s0 >= KSEL && s1 < KSEL) { Bl = lane*4 + 0; abv = s1; }
  if (s1 >= KSEL && s2 < KSEL) { Bl = lane*4 + 1; abv = s2; }
  if (s2 >= KSEL && s3 < KSEL) { Bl = lane*4 + 2; abv = s3; }
  if (s3 >= KSEL && beyond < KSEL) { Bl = lane*4 + 3; abv = beyond; }
  if (Bl >= 0) { s_B[wave] = Bl; s_above[wave] = abv; }
  __builtin_amdgcn_wave_barrier();
  const int B = s_B[wave];
  const int rem = KSEL - s_above[wave];   // >= 1 by construction

#pragma unroll
  for (int j = 0; j < 8; ++j) {
    if (bins[j] == B) {
      const unsigned int u = __float_as_uint(v[j]);
      const unsigned int vk = (u & 0x80000000u) ? ~u : (u | 0x80000000u);
      const int p = atomicAdd(&s_nlist[wave], 1);
      if (p < 256)
        s_list[wave][p] = ((unsigned long long)vk << 32) | (unsigned int)~(j*64 + lane);
    }
  }
  __builtin_amdgcn_wave_barrier();

  const int nl = s_nlist[wave] < 256 ? s_nlist[wave] : 256;
  unsigned long long T = ~0ull;
  for (int r = 0; r < rem; ++r) {
    unsigned long long best = 0; int pos = -1;
    for (int i = lane; i < nl; i += 64)
      if (s_list[wave][i] > best) { best = s_list[wave][i]; pos = i; }
#pragma unroll
    for (int off = 32; off > 0; off >>= 1) {
      const unsigned long long ob = __shfl_xor(best, off);
      const int op = __shfl_xor(pos, off);
      if (ob > best) { best = ob; pos = op; }
    }
    if (lane == 0) s_list[wave][pos] = 0;
    T = best;
    __builtin_amdgcn_wave_barrier();
  }

  float e[8];
  float esum = 0.f;
#pragma unroll
  for (int j = 0; j < 8; ++j) {
    bool sel = bins[j] > B;
    if (!sel && bins[j] == B) {
      const unsigned int u = __float_as_uint(v[j]);
      const unsigned int vk = (u & 0x80000000u) ? ~u : (u | 0x80000000u);
      const unsigned long long key =
          ((unsigned long long)vk << 32) | (unsigned int)~(j*64 + lane);
      sel = key >= T;
    }
    e[j] = sel ? expf(v[j] - mx) : 0.f;
    esum += e[j];
  }
#pragma unroll
  for (int off = 32; off > 0; off >>= 1) esum += __shfl_xor(esum, off);
  const float ginv = gate[token]/esum;
#pragma unroll
  for (int j = 0; j < 8; ++j)
    Wm[(size_t)token*MS + j*64 + lane] = f2bf(e[j]*ginv);
}

// ---------------------------------------------------------------------------
// K9: FUSED output GEMM: out = ctx @ Wot^T + bo + Wm' @ mvT^T
// (Wm' is gate-scaled). Two K-loops accumulate into the SAME registers;
// out written exactly once (no RMW). XCD-swizzled flat grid (512 blocks).
// ---------------------------------------------------------------------------
__global__ __launch_bounds__(256) void gemm_fused_out_kernel(
    const unsigned short* __restrict__ A,   // ctxb [NTOK][HDIM]
    const unsigned short* __restrict__ Bt,  // Wot  [HDIM][HDIM]
    const unsigned short* __restrict__ Wm,  // [NTOK][MS] gate-scaled bf16
    const unsigned short* __restrict__ mvT, // [HDIM][MS]
    const float* __restrict__ bias, float* __restrict__ out) {
  __shared__ __align__(16) unsigned short As[128*32];
  __shared__ __align__(16) unsigned short Bs[128*32];
  const int tid = threadIdx.x;
  const int lane = tid & 63, wave = tid >> 6;
  const int wr = wave >> 1, wc = wave & 1;
  const int wg = blockIdx.x;                  // 0..511
  const int swz = (wg & 7)*64 + (wg >> 3);    // bijective XCD swizzle
  const int bx = swz & 7, by = swz >> 3;
  const int row0 = by << 7, col0 = bx << 7;

  f32x4 acc[4][4];
#pragma unroll
  for (int m = 0; m < 4; ++m)
#pragma unroll
    for (int n = 0; n < 4; ++n) acc[m][n] = (f32x4)(0.f);

  const int srow = tid >> 2;
  const int sk   = (tid & 3) << 3;
  const int fr = lane & 15;
  const int fk = (lane >> 4) << 3;
  const int fg = lane >> 4;

  // ---- loop 1: ctx @ Wot^T (K = HDIM) ----
  {
    const unsigned short* gA = A  + (size_t)(row0 + srow)*HDIM + sk;
    const unsigned short* gB = Bt + (size_t)(col0 + srow)*HDIM + sk;
    for (int k0 = 0; k0 < HDIM; k0 += 32) {
      gload_lds16(gA + k0,             As + tid*8);
      gload_lds16(gA + 64*HDIM + k0,   As + 2048 + tid*8);
      gload_lds16(gB + k0,             Bs + tid*8);
      gload_lds16(gB + 64*HDIM + k0,   Bs + 2048 + tid*8);
      __syncthreads();
      short8 af[4], bf[4];
#pragma unroll
      for (int m = 0; m < 4; ++m)
        af[m] = *(const short8*)&As[(wr*64 + m*16 + fr)*32 + fk];
#pragma unroll
      for (int n = 0; n < 4; ++n)
        bf[n] = *(const short8*)&Bs[(wc*64 + n*16 + fr)*32 + fk];
#pragma unroll
      for (int m = 0; m < 4; ++m)
#pragma unroll
        for (int n = 0; n < 4; ++n)
          acc[m][n] = __builtin_amdgcn_mfma_f32_16x16x32_bf16(af[m], bf[n], acc[m][n], 0, 0, 0);
      __syncthreads();
    }
  }
  // ---- loop 2: Wm' @ mvT^T (K = MS), same accumulators ----
  {
    const unsigned short* gA = Wm  + (size_t)(row0 + srow)*MS + sk;
    const unsigned short* gB = mvT + (size_t)(col0 + srow)*MS + sk;
    for (int k0 = 0; k0 < MS; k0 += 32) {
      gload_lds16(gA + k0,           As + tid*8);
      gload_lds16(gA + 64*MS + k0,   As + 2048 + tid*8);
      gload_lds16(gB + k0,           Bs + tid*8);
      gload_lds16(gB + 64*MS + k0,   Bs + 2048 + tid*8);
      __syncthreads();
      short8 af[4], bf[4];
#pragma unroll
      for (int m = 0; m < 4; ++m)
        af[m] = *(const short8*)&As[(wr*64 + m*16 + fr)*32 + fk];
#pragma unroll
      for (int n = 0; n < 4; ++n)
        bf[n] = *(const short8*)&Bs[(wc*64 + n*16 + fr)*32 + fk];
#pragma unroll
      for (int m = 0; m < 4; ++m)
#pragma unroll
        for (int n = 0; n < 4; ++n)
          acc[m][n] = __builtin_amdgcn_mfma_f32_16x16x32_bf16(af[m], bf[n], acc[m][n], 0, 0, 0);
      __syncthreads();
    }
  }

#pragma unroll
  for (int m = 0; m < 4; ++m) {
#pragma unroll
    for (int n = 0; n < 4; ++n) {
      const int col = col0 + wc*64 + n*16 + fr;
      const float bb = bias[col];
#pragma unroll
      for (int r = 0; r < 4; ++r) {
        const int row = row0 + wr*64 + m*16 + fg*4 + r;
        out[(size_t)row*HDIM + col] = acc[m][n][r] + bb;
      }
    }
  }
}

// ---------------------------------------------------------------------------
extern "C" void kernel_launch(void* const* d_in, const int* in_sizes, int n_in,
                              void* d_out, int out_size, void* d_ws, size_t ws_size,
                              hipStream_t stream) {
  const float* hs = (const float*)d_in[0];
  const float* Wq = (const float*)d_in[1];
  const float* bq = (const float*)d_in[2];
  const float* Wk = (const float*)d_in[3];
  const float* bk = (const float*)d_in[4];
  const float* Wv = (const float*)d_in[5];
  const float* bv = (const float*)d_in[6];
  const float* Wo = (const float*)d_in[7];
  const float* bo = (const float*)d_in[8];
  const float* mk = (const float*)d_in[9];
  const float* mv = (const float*)d_in[10];
  const float* gw = (const float*)d_in[11];
  const float* gb = (const float*)d_in[12];
  float* out = (float*)d_out;

  // Workspace (peak ~64 MB). Aliases (producer strictly after last consumer
  // on the single stream):  ctxb = hsb (hsb last read by gemm_qmsc);
  //                         Wm   = qb  (qb last read by attn).
  char* ws = (char*)d_ws;
  unsigned short* hsb  = (unsigned short*)(ws);                       // 16 MiB bf16 [NTOK,HDIM]
  unsigned short* ctxb = hsb;                                         // alias
  unsigned short* qb   = (unsigned short*)(ws + ((size_t)16 << 20));  // 16 MiB bf16
  unsigned short* Wm   = qb;                                          // alias, 8 MiB [NTOK,MS]
  float*          msc  = (float*)(ws + ((size_t)32 << 20));           // 16 MiB fp32 [NTOK,MS]
  unsigned short* Wkvt = (unsigned short*)(ws + ((size_t)48 << 20));  // 4 MiB [2048][1024]
  unsigned short* Wcat = (unsigned short*)(ws + ((size_t)52 << 20));  // 3 MiB [1536][1024]
  unsigned short* Wot  = (unsigned short*)(ws + ((size_t)55 << 20));  // 2 MiB
  unsigned short* mvT  = (unsigned short*)(ws + ((size_t)57 << 20));  // 1 MiB [HDIM][MS]
  float*          kbuf = (float*)(ws + ((size_t)58 << 20));           // 512 KiB
  float*          vbuf = (float*)(ws + ((size_t)58 << 20) + ((size_t)512 << 10));
  unsigned short* g    = (unsigned short*)(ws + ((size_t)59 << 20));  // 256 KiB
  float*          part = (float*)(ws + ((size_t)59 << 20) + ((size_t)256 << 10)); // 4 MiB
  float*          imp  = (float*)(ws + ((size_t)64 << 20));           // 32 KiB
  float*          gate = (float*)(ws + ((size_t)64 << 20) + ((size_t)32 << 10));
  int*            cnt  = (int*)  (ws + ((size_t)64 << 20) + ((size_t)64 << 10)); // 32 KiB
  int*            lmi  = (int*)  (ws + ((size_t)64 << 20) + ((size_t)96 << 10)); // 4 KiB

  imp_gate_kernel<<<dim3(NTOK/4), 256, 0, stream>>>(hs, gw, gb, imp, gate, hsb);
  hipMemsetAsync(cnt, 0, NB*NS*sizeof(int), stream);
  lm_count_kernel<<<dim3(NS/256, 4, NB), 256, 0, stream>>>(imp, cnt);
  lm_sel_kernel<<<dim3(NS/256, NB), 256, 0, stream>>>(cnt, lmi);
  prep_kernel<<<dim3(32, 32, 5), 256, 0, stream>>>(
      Wk, Wv, Wq, Wo, mk, mv, Wkvt, Wcat, Wot, mvT);
  // K/V projection of landmark rows via MFMA GEMM (split-K=4)
  lm_gather_kernel<<<dim3(NB*LM), 256, 0, stream>>>(hsb, lmi, g);
  kvproj_gemm_kernel<<<dim3(16, 4), 256, 0, stream>>>(g, Wkvt, part);
  kv_reduce2_kernel<<<dim3(8, 128), 256, 0, stream>>>(part, bk, bv, kbuf, vbuf);
  // fused Q-projection + memory scores (reads hsb for the last time)
  gemm_qmsc_kernel<<<dim3(768), 256, 0, stream>>>(hsb, Wcat, bq, qb, msc);
  // attention (writes ctxb over hsb; reads qb for the last time)
  attn_mfma_kernel<<<dim3(NS/128, NHEAD, NB), 256, 0, stream>>>(qb, kbuf, vbuf, ctxb);
  // memory-bank selection -> gate-scaled dense weight rows (Wm over qb)
  sel_kernel<<<dim3(NTOK/4), 256, 0, stream>>>(msc, gate, Wm);
  // single fused output GEMM: out = ctx@Wot^T + bo + Wm'@mvT^T
  gemm_fused_out_kernel<<<dim3(512), 256, 0, stream>>>(ctxb, Wot, Wm, mvT, bo, out);
}

// Round 12
// 163.622 us; speedup vs baseline: 6.2249x; 1.0261x over previous
//
#include <hip/hip_runtime.h>
#include <math.h>

// Problem constants (from reference setup_inputs)
#define HDIM 1024
#define NHEAD 16
#define HD 64
#define LM 64          // NUM_LANDMARKS
#define MS 512         // memory slots
#define KSEL 32        // top_k
#define NB 2
#define NS 4096
#define NTOK (NB*NS)   // 8192

typedef __attribute__((ext_vector_type(8))) short short8;
typedef __attribute__((ext_vector_type(4))) float f32x4;
typedef __attribute__((ext_vector_type(4))) unsigned short us4;

__device__ __forceinline__ unsigned short f2bf(float f) {
  unsigned int u = __float_as_uint(f);
  unsigned int r = (u + 0x7fffu + ((u >> 16) & 1u)) >> 16;
  return (unsigned short)r;
}
__device__ __forceinline__ float bf2f(unsigned short u) {
  return __uint_as_float(((unsigned int)u) << 16);
}

__device__ __forceinline__ void gload_lds16(const unsigned short* g, unsigned short* l) {
  __builtin_amdgcn_global_load_lds(
      (const __attribute__((address_space(1))) unsigned int*)g,
      (__attribute__((address_space(3))) unsigned int*)l,
      16, 0, 0);
}

// ---------------------------------------------------------------------------
// BK=64 GEMM tile helpers (128x64 A/B tiles, XOR-swizzled 16B chunks).
// LDS layout: [row][64] bf16, 128B rows; LDS[row][chunk] holds global
// chunk (chunk ^ (row&7)) -> reads at chunk ((lc)^(row&7)) are 2-way
// conflict-free.  Staging: linear LDS dest + swizzled global source.
// ---------------------------------------------------------------------------
#define STAGE64(gbase, k0, LDA, lds)                                          \
  {                                                                           \
    const unsigned short* _s = (gbase) + (k0) + gchk*8;                       \
    gload_lds16(_s,                 (lds) + tid*8);                           \
    gload_lds16(_s + (size_t)32*(LDA), (lds) + 2048 + tid*8);                 \
    gload_lds16(_s + (size_t)64*(LDA), (lds) + 4096 + tid*8);                 \
    gload_lds16(_s + (size_t)96*(LDA), (lds) + 6144 + tid*8);                 \
  }

// ---------------------------------------------------------------------------
// K1: wave-per-row importance (sum sq) + gate + hs -> bf16. Block = 4 rows.
// ---------------------------------------------------------------------------
__global__ __launch_bounds__(256) void imp_gate_kernel(
    const float* __restrict__ hs, const float* __restrict__ gw,
    const float* __restrict__ gb, float* __restrict__ imp,
    float* __restrict__ gate, unsigned short* __restrict__ hsb) {
  const int lane = threadIdx.x & 63, wave = threadIdx.x >> 6;
  const int row = blockIdx.x*4 + wave;
  float ss = 0.f, dg = 0.f;
#pragma unroll
  for (int c = 0; c < 4; ++c) {
    const int d = c*256 + lane*4;
    const float4 hv = *(const float4*)(hs + (size_t)row*HDIM + d);
    const float4 gv = *(const float4*)(gw + d);
    ss += hv.x*hv.x + hv.y*hv.y + hv.z*hv.z + hv.w*hv.w;
    dg += hv.x*gv.x + hv.y*gv.y + hv.z*gv.z + hv.w*gv.w;
    us4 hb;
    hb.x = f2bf(hv.x); hb.y = f2bf(hv.y); hb.z = f2bf(hv.z); hb.w = f2bf(hv.w);
    *(us4*)(hsb + (size_t)row*HDIM + d) = hb;
  }
#pragma unroll
  for (int off = 32; off > 0; off >>= 1) {
    ss += __shfl_xor(ss, off);
    dg += __shfl_xor(dg, off);
  }
  if (lane == 0) {
    imp[row] = ss;
    gate[row] = 1.f/(1.f + expf(-(dg + gb[0])));
  }
}

// ---------------------------------------------------------------------------
// K2a: rank counting (jax tie-break).
// ---------------------------------------------------------------------------
__global__ __launch_bounds__(256) void lm_count_kernel(
    const float* __restrict__ imp, int* __restrict__ cnt) {
  const int b = blockIdx.z;
  const int jc = blockIdx.y;
  const int i = blockIdx.x*256 + threadIdx.x;
  const float* v = imp + b*NS;
  const float mine = v[i];
  __shared__ float tile[1024];
  const int j0 = jc*1024;
  *(float4*)&tile[threadIdx.x*4] = *(const float4*)&v[j0 + threadIdx.x*4];
  __syncthreads();
  int c = 0;
#pragma unroll 8
  for (int p = 0; p < 1024; p += 4) {
    const float4 t = *(const float4*)&tile[p];
    c += (t.x > mine) || (t.x == mine && (j0+p+0) < i);
    c += (t.y > mine) || (t.y == mine && (j0+p+1) < i);
    c += (t.z > mine) || (t.z == mine && (j0+p+2) < i);
    c += (t.w > mine) || (t.w == mine && (j0+p+3) < i);
  }
  atomicAdd(&cnt[b*NS + i], c);
}

// K2b: scatter selected candidates (set only).
__global__ __launch_bounds__(256) void lm_sel_kernel(
    const int* __restrict__ cnt, int* __restrict__ lm_idx) {
  const int b = blockIdx.y;
  const int i = blockIdx.x*256 + threadIdx.x;
  const int c = cnt[b*NS + i];
  if (c < LM) lm_idx[b*LM + c] = i;
}

// ---------------------------------------------------------------------------
// K3a: gather 128 landmark rows (bf16) into compact g[NB*LM][HDIM]
// ---------------------------------------------------------------------------
__global__ __launch_bounds__(256) void lm_gather_kernel(
    const unsigned short* __restrict__ hsb, const int* __restrict__ lmi,
    unsigned short* __restrict__ g) {
  const int j = blockIdx.x;
  const int b = j >> 6;
  const int idx = lmi[j];
  const us4 v = *(const us4*)(hsb + ((size_t)(b*NS + idx))*HDIM + threadIdx.x*4);
  *(us4*)(g + (size_t)j*HDIM + threadIdx.x*4) = v;
}

// ---------------------------------------------------------------------------
// K3b: K/V projection as bf16 MFMA GEMM, split-K=4 (BK=32, tiny kernel).
// ---------------------------------------------------------------------------
__global__ __launch_bounds__(256) void kvproj_gemm_kernel(
    const unsigned short* __restrict__ g, const unsigned short* __restrict__ Wkvt,
    float* __restrict__ part) {
  __shared__ __align__(16) unsigned short As[128*32];
  __shared__ __align__(16) unsigned short Bs[128*32];
  const int tid = threadIdx.x;
  const int lane = tid & 63, wave = tid >> 6;
  const int wr = wave >> 1, wc = wave & 1;
  const int col0 = blockIdx.x << 7;
  const int sp = blockIdx.y;
  const int k00 = sp << 8;

  f32x4 acc[4][4];
#pragma unroll
  for (int m = 0; m < 4; ++m)
#pragma unroll
    for (int n = 0; n < 4; ++n) acc[m][n] = (f32x4)(0.f);

  const int srow = tid >> 2;
  const int sk   = (tid & 3) << 3;
  const unsigned short* gA = g    + (size_t)srow*HDIM + sk;
  const unsigned short* gB = Wkvt + (size_t)(col0 + srow)*HDIM + sk;
  const int fr = lane & 15;
  const int fk = (lane >> 4) << 3;
  const int fg = lane >> 4;

  for (int k0 = k00; k0 < k00 + 256; k0 += 32) {
    gload_lds16(gA + k0,             As + tid*8);
    gload_lds16(gA + 64*HDIM + k0,   As + 2048 + tid*8);
    gload_lds16(gB + k0,             Bs + tid*8);
    gload_lds16(gB + 64*HDIM + k0,   Bs + 2048 + tid*8);
    __syncthreads();
    short8 af[4], bf[4];
#pragma unroll
    for (int m = 0; m < 4; ++m)
      af[m] = *(const short8*)&As[(wr*64 + m*16 + fr)*32 + fk];
#pragma unroll
    for (int n = 0; n < 4; ++n)
      bf[n] = *(const short8*)&Bs[(wc*64 + n*16 + fr)*32 + fk];
#pragma unroll
    for (int m = 0; m < 4; ++m)
#pragma unroll
      for (int n = 0; n < 4; ++n)
        acc[m][n] = __builtin_amdgcn_mfma_f32_16x16x32_bf16(af[m], bf[n], acc[m][n], 0, 0, 0);
    __syncthreads();
  }
#pragma unroll
  for (int m = 0; m < 4; ++m)
#pragma unroll
    for (int n = 0; n < 4; ++n) {
      const int colg = col0 + wc*64 + n*16 + fr;
#pragma unroll
      for (int r = 0; r < 4; ++r) {
        const int row = wr*64 + m*16 + fg*4 + r;
        part[((size_t)(sp*128 + row))*2048 + colg] = acc[m][n][r];
      }
    }
}

// K3c: reduce 4 K-split partials + bias -> kbuf/vbuf fp32. grid (8, 128).
__global__ __launch_bounds__(256) void kv_reduce2_kernel(
    const float* __restrict__ part, const float* __restrict__ bk,
    const float* __restrict__ bv, float* __restrict__ kbuf,
    float* __restrict__ vbuf) {
  const int row = blockIdx.y;
  const int col = blockIdx.x*256 + threadIdx.x;
  float s = 0.f;
#pragma unroll
  for (int sp = 0; sp < 4; ++sp)
    s += part[((size_t)(sp*128 + row))*2048 + col];
  if (col < HDIM) kbuf[(size_t)row*HDIM + col] = s + bk[col];
  else            vbuf[(size_t)row*HDIM + col - HDIM] = s + bv[col - HDIM];
}

// ---------------------------------------------------------------------------
// Prep (fused): z<4 -> transpose+convert W; z==4 -> blk<512: conv mk into
// Wcat tail; blk>=512: transpose+convert mem_values -> mvT[1024][512] bf16.
// ---------------------------------------------------------------------------
__global__ __launch_bounds__(256) void prep_kernel(
    const float* __restrict__ Wk, const float* __restrict__ Wv,
    const float* __restrict__ Wq, const float* __restrict__ Wo,
    const float* __restrict__ mk, const float* __restrict__ mv,
    unsigned short* __restrict__ Wkvt, unsigned short* __restrict__ Wcat,
    unsigned short* __restrict__ Wot, unsigned short* __restrict__ mvT) {
  const int z = blockIdx.z;
  __shared__ float tile[32][33];
  const int tx = threadIdx.x & 31, ty = threadIdx.x >> 5;
  if (z < 4) {
    const float* W = (z == 0) ? Wk : (z == 1) ? Wv : (z == 2) ? Wq : Wo;
    unsigned short* Wt = (z == 0) ? Wkvt
                       : (z == 1) ? (Wkvt + (size_t)HDIM*HDIM)
                       : (z == 2) ? Wcat : Wot;
    const int bx = blockIdx.x * 32, by = blockIdx.y * 32;
#pragma unroll
    for (int i = 0; i < 32; i += 8)
      tile[ty + i][tx] = W[(size_t)(by + ty + i)*HDIM + bx + tx];
    __syncthreads();
#pragma unroll
    for (int i = 0; i < 32; i += 8)
      Wt[(size_t)(bx + ty + i)*HDIM + by + tx] = f2bf(tile[tx][ty + i]);
  } else {
    const int blk = blockIdx.y*32 + blockIdx.x;
    if (blk < 512) {
      const int off = (blk << 10) + threadIdx.x*4;
      const float4 v = *(const float4*)&mk[off];
      us4 w;
      w.x = f2bf(v.x); w.y = f2bf(v.y); w.z = f2bf(v.z); w.w = f2bf(v.w);
      *(us4*)&(Wcat + (size_t)HDIM*HDIM)[off] = w;
    } else {
      const int t = blk - 512;
      const int by = (t >> 5) * 32;
      const int bx = (t & 31) * 32;
#pragma unroll
      for (int i = 0; i < 32; i += 8)
        tile[ty + i][tx] = mv[(size_t)(by + ty + i)*HDIM + bx + tx];
      __syncthreads();
#pragma unroll
      for (int i = 0; i < 32; i += 8)
        mvT[(size_t)(bx + ty + i)*MS + by + tx] = f2bf(tile[tx][ty + i]);
    }
  }
}

// ---------------------------------------------------------------------------
// Fused GEMM (BK=64, swizzled): [q | msc] = hsb @ Wcat^T.
// XCD-swizzled flat grid (768 blocks).
// ---------------------------------------------------------------------------
__global__ __launch_bounds__(256) void gemm_qmsc_kernel(
    const unsigned short* __restrict__ A, const unsigned short* __restrict__ Bt,
    const float* __restrict__ bq, unsigned short* __restrict__ qb,
    float* __restrict__ msc) {
  __shared__ __align__(16) unsigned short As[128*64];
  __shared__ __align__(16) unsigned short Bs[128*64];
  const int tid = threadIdx.x;
  const int lane = tid & 63, wave = tid >> 6;
  const int wr = wave >> 1, wc = wave & 1;
  const int wg = blockIdx.x;                    // 0..767
  const int swz = (wg & 7)*96 + (wg >> 3);      // bijective XCD swizzle
  const int bx = swz % 12, by = swz / 12;
  const int row0 = by << 7, col0 = bx << 7;

  f32x4 acc[4][4];
#pragma unroll
  for (int m = 0; m < 4; ++m)
#pragma unroll
    for (int n = 0; n < 4; ++n) acc[m][n] = (f32x4)(0.f);

  const int srow = tid >> 3;                    // 0..31
  const int gchk = (tid & 7) ^ (srow & 7);      // swizzled source 16B chunk
  const unsigned short* gA = A  + (size_t)(row0 + srow)*HDIM;
  const unsigned short* gB = Bt + (size_t)(col0 + srow)*HDIM;
  const int fr = lane & 15;
  const int fg = lane >> 4;
  const int ca = ((0*4 + fg) ^ (fr & 7)) * 8;   // swizzled read chunk, kk=0
  const int cb = ((1*4 + fg) ^ (fr & 7)) * 8;   // swizzled read chunk, kk=32

  for (int k0 = 0; k0 < HDIM; k0 += 64) {
    STAGE64(gA, k0, HDIM, As);
    STAGE64(gB, k0, HDIM, Bs);
    __syncthreads();
#pragma unroll
    for (int kh = 0; kh < 2; ++kh) {
      const int cc = kh ? cb : ca;
      short8 af[4], bf[4];
#pragma unroll
      for (int m = 0; m < 4; ++m)
        af[m] = *(const short8*)&As[(wr*64 + m*16 + fr)*64 + cc];
#pragma unroll
      for (int n = 0; n < 4; ++n)
        bf[n] = *(const short8*)&Bs[(wc*64 + n*16 + fr)*64 + cc];
#pragma unroll
      for (int m = 0; m < 4; ++m)
#pragma unroll
        for (int n = 0; n < 4; ++n)
          acc[m][n] = __builtin_amdgcn_mfma_f32_16x16x32_bf16(af[m], bf[n], acc[m][n], 0, 0, 0);
    }
    __syncthreads();
  }

#pragma unroll
  for (int m = 0; m < 4; ++m) {
#pragma unroll
    for (int n = 0; n < 4; ++n) {
      const int col = col0 + wc*64 + n*16 + fr;
      if (col < HDIM) {
        const float bb = bq[col];
#pragma unroll
        for (int r = 0; r < 4; ++r) {
          const int row = row0 + wr*64 + m*16 + fg*4 + r;
          qb[(size_t)row*HDIM + col] = f2bf(acc[m][n][r] + bb);
        }
      } else {
        const int c2 = col - HDIM;
#pragma unroll
        for (int r = 0; r < 4; ++r) {
          const int row = row0 + wr*64 + m*16 + fg*4 + r;
          msc[(size_t)row*MS + c2] = acc[m][n][r]*0.03125f;
        }
      }
    }
  }
}

// ---------------------------------------------------------------------------
// K5: MFMA landmark attention. Block = 128 tokens x 1 head; 4 waves x 32 rows.
// P is written over the Q LDS region (each wave touches only its own 32-row
// slice -> no cross-wave hazard; per-wave DS pipe is in-order). LDS = 32 KiB.
// ---------------------------------------------------------------------------
__global__ __launch_bounds__(256) void attn_mfma_kernel(
    const unsigned short* __restrict__ qb, const float* __restrict__ kbuf,
    const float* __restrict__ vbuf, unsigned short* __restrict__ ctxb) {
  const int tb = blockIdx.x, h = blockIdx.y, b = blockIdx.z;
  const int tid = threadIdx.x;
  const int lane = tid & 63, wave = tid >> 6;
  __shared__ __align__(16) unsigned short Qs[128*64];  // 16 KiB (Q, then P)
  __shared__ __align__(16) unsigned short Ks[64*64];   //  8 KiB
  __shared__ __align__(16) unsigned short Vt[64*64];   //  8 KiB [d][l]

  const int tok0 = b*NS + tb*128;
#pragma unroll
  for (int it = 0; it < 4; ++it) {
    const int idx = it*256 + tid;
    gload_lds16(qb + (size_t)(tok0 + (idx >> 3))*HDIM + h*64 + (idx & 7)*8,
                Qs + idx*8);
  }
#pragma unroll
  for (int it = 0; it < 4; ++it) {
    const int i = it*256 + tid;
    const int l = i >> 4, d0 = (i & 15) << 2;
    const size_t base = (size_t)(b*LM + l)*HDIM + h*64 + d0;
    const float4 kv = *(const float4*)(kbuf + base);
    const float4 vv = *(const float4*)(vbuf + base);
    us4 k4; k4.x = f2bf(kv.x); k4.y = f2bf(kv.y); k4.z = f2bf(kv.z); k4.w = f2bf(kv.w);
    *(us4*)&Ks[l*64 + d0] = k4;
    Vt[(d0+0)*64 + l] = f2bf(vv.x);
    Vt[(d0+1)*64 + l] = f2bf(vv.y);
    Vt[(d0+2)*64 + l] = f2bf(vv.z);
    Vt[(d0+3)*64 + l] = f2bf(vv.w);
  }
  __syncthreads();

  const int fr = lane & 15;
  const int fg = lane >> 4;
  const int fk = fg << 3;
  const int wrow = wave*32;

  f32x4 acc[2][4];
#pragma unroll
  for (int m = 0; m < 2; ++m)
#pragma unroll
    for (int n = 0; n < 4; ++n) acc[m][n] = (f32x4)(0.f);
#pragma unroll
  for (int ks = 0; ks < 2; ++ks) {
    short8 af[2], bf[4];
#pragma unroll
    for (int m = 0; m < 2; ++m)
      af[m] = *(const short8*)&Qs[(wrow + m*16 + fr)*64 + ks*32 + fk];
#pragma unroll
    for (int n = 0; n < 4; ++n)
      bf[n] = *(const short8*)&Ks[(n*16 + fr)*64 + ks*32 + fk];
#pragma unroll
    for (int m = 0; m < 2; ++m)
#pragma unroll
      for (int n = 0; n < 4; ++n)
        acc[m][n] = __builtin_amdgcn_mfma_f32_16x16x32_bf16(af[m], bf[n], acc[m][n], 0, 0, 0);
  }

  // in-register softmax; write P over the Q region (own 32-row slice only)
#pragma unroll
  for (int m = 0; m < 2; ++m) {
#pragma unroll
    for (int r = 0; r < 4; ++r) {
      float p0 = acc[m][0][r]*0.125f, p1 = acc[m][1][r]*0.125f;
      float p2 = acc[m][2][r]*0.125f, p3 = acc[m][3][r]*0.125f;
      float mx = fmaxf(fmaxf(p0, p1), fmaxf(p2, p3));
#pragma unroll
      for (int off = 1; off < 16; off <<= 1) mx = fmaxf(mx, __shfl_xor(mx, off));
      p0 = expf(p0 - mx); p1 = expf(p1 - mx); p2 = expf(p2 - mx); p3 = expf(p3 - mx);
      float sm = p0 + p1 + p2 + p3;
#pragma unroll
      for (int off = 1; off < 16; off <<= 1) sm += __shfl_xor(sm, off);
      const float inv = 1.f/sm;
      const int prow = (wrow + m*16 + fg*4 + r)*64;
      Qs[prow + 0*16 + fr] = f2bf(p0*inv);
      Qs[prow + 1*16 + fr] = f2bf(p1*inv);
      Qs[prow + 2*16 + fr] = f2bf(p2*inv);
      Qs[prow + 3*16 + fr] = f2bf(p3*inv);
    }
  }
  // no barrier needed: PV reads only this wave's P rows + Vt (sync'd above)

  f32x4 occ[2][4];
#pragma unroll
  for (int m = 0; m < 2; ++m)
#pragma unroll
    for (int n = 0; n < 4; ++n) occ[m][n] = (f32x4)(0.f);
#pragma unroll
  for (int ks = 0; ks < 2; ++ks) {
    short8 af[2], bf[4];
#pragma unroll
    for (int m = 0; m < 2; ++m)
      af[m] = *(const short8*)&Qs[(wrow + m*16 + fr)*64 + ks*32 + fk];
#pragma unroll
    for (int n = 0; n < 4; ++n)
      bf[n] = *(const short8*)&Vt[(n*16 + fr)*64 + ks*32 + fk];
#pragma unroll
    for (int m = 0; m < 2; ++m)
#pragma unroll
      for (int n = 0; n < 4; ++n)
        occ[m][n] = __builtin_amdgcn_mfma_f32_16x16x32_bf16(af[m], bf[n], occ[m][n], 0, 0, 0);
  }
#pragma unroll
  for (int m = 0; m < 2; ++m)
#pragma unroll
    for (int n = 0; n < 4; ++n)
#pragma unroll
      for (int r = 0; r < 4; ++r)
        ctxb[(size_t)(tok0 + wrow + m*16 + fg*4 + r)*HDIM + h*64 + n*16 + fr] =
            f2bf(occ[m][n][r]);
}

// ---------------------------------------------------------------------------
// K8a: wave-per-token top-32 THRESHOLD selection -> gate-scaled dense
// weight row Wm[token][m] (bf16). Zero block barriers.
// ---------------------------------------------------------------------------
__global__ __launch_bounds__(256) void sel_kernel(
    const float* __restrict__ msc, const float* __restrict__ gate,
    unsigned short* __restrict__ Wm) {
  const int tid = threadIdx.x;
  const int lane = tid & 63, wave = tid >> 6;
  const int token = blockIdx.x*4 + wave;

  __shared__ __align__(16) int s_hist[4][256];
  __shared__ unsigned long long s_list[4][256];
  __shared__ int s_B[4], s_above[4], s_nlist[4];

  *(int4*)&s_hist[wave][lane*4] = make_int4(0, 0, 0, 0);
  if (lane == 0) s_nlist[wave] = 0;

  float v[8];
#pragma unroll
  for (int j = 0; j < 8; ++j) v[j] = msc[(size_t)token*MS + j*64 + lane];

  float mx = v[0], mn = v[0];
#pragma unroll
  for (int j = 1; j < 8; ++j) { mx = fmaxf(mx, v[j]); mn = fminf(mn, v[j]); }
#pragma unroll
  for (int off = 32; off > 0; off >>= 1) {
    mx = fmaxf(mx, __shfl_xor(mx, off));
    mn = fminf(mn, __shfl_xor(mn, off));
  }
  const float range = mx - mn;
  const float scale = (range > 1e-20f) ? 255.f/range : 0.f;

  __builtin_amdgcn_wave_barrier();
  int bins[8];
#pragma unroll
  for (int j = 0; j < 8; ++j) {
    int b = (int)((v[j] - mn)*scale);
    bins[j] = b > 255 ? 255 : b;
    atomicAdd(&s_hist[wave][bins[j]], 1);
  }
  __builtin_amdgcn_wave_barrier();

  const int4 c = *(const int4*)&s_hist[wave][lane*4];
  const int lane_total = c.x + c.y + c.z + c.w;
  int sfx = lane_total;
#pragma unroll
  for (int off = 1; off < 64; off <<= 1) {
    const int src = lane + off;
    int y = __shfl(sfx, src < 64 ? src : lane);
    sfx += (src < 64) ? y : 0;
  }
  const int beyond = sfx - lane_total;
  const int s3 = c.w + beyond;
  const int s2 = c.z + s3;
  const int s1 = c.y + s2;
  const int s0 = c.x + s1;
  int Bl = -1, abv = 0;
  if (s0 >= KSEL && s1 < KSEL) { Bl = lane*4 + 0; abv = s1; }
  if (s1 >= KSEL && s2 < KSEL) { Bl = lane*4 + 1; abv = s2; }
  if (s2 >= KSEL && s3 < KSEL) { Bl = lane*4 + 2; abv = s3; }
  if (s3 >= KSEL && beyond < KSEL) { Bl = lane*4 + 3; abv = beyond; }
  if (Bl >= 0) { s_B[wave] = Bl; s_above[wave] = abv; }
  __builtin_amdgcn_wave_barrier();
  const int B = s_B[wave];
  const int rem = KSEL - s_above[wave];

#pragma unroll
  for (int j = 0; j < 8; ++j) {
    if (bins[j] == B) {
      const unsigned int u = __float_as_uint(v[j]);
      const unsigned int vk = (u & 0x80000000u) ? ~u : (u | 0x80000000u);
      const int p = atomicAdd(&s_nlist[wave], 1);
      if (p < 256)
        s_list[wave][p] = ((unsigned long long)vk << 32) | (unsigned int)~(j*64 + lane);
    }
  }
  __builtin_amdgcn_wave_barrier();

  const int nl = s_nlist[wave] < 256 ? s_nlist[wave] : 256;
  unsigned long long T = ~0ull;
  for (int r = 0; r < rem; ++r) {
    unsigned long long best = 0; int pos = -1;
    for (int i = lane; i < nl; i += 64)
      if (s_list[wave][i] > best) { best = s_list[wave][i]; pos = i; }
#pragma unroll
    for (int off = 32; off > 0; off >>= 1) {
      const unsigned long long ob = __shfl_xor(best, off);
      const int op = __shfl_xor(pos, off);
      if (ob > best) { best = ob; pos = op; }
    }
    if (lane == 0) s_list[wave][pos] = 0;
    T = best;
    __builtin_amdgcn_wave_barrier();
  }

  float e[8];
  float esum = 0.f;
#pragma unroll
  for (int j = 0; j < 8; ++j) {
    bool sel = bins[j] > B;
    if (!sel && bins[j] == B) {
      const unsigned int u = __float_as_uint(v[j]);
      const unsigned int vk = (u & 0x80000000u) ? ~u : (u | 0x80000000u);
      const unsigned long long key =
          ((unsigned long long)vk << 32) | (unsigned int)~(j*64 + lane);
      sel = key >= T;
    }
    e[j] = sel ? expf(v[j] - mx) : 0.f;
    esum += e[j];
  }
#pragma unroll
  for (int off = 32; off > 0; off >>= 1) esum += __shfl_xor(esum, off);
  const float ginv = gate[token]/esum;
#pragma unroll
  for (int j = 0; j < 8; ++j)
    Wm[(size_t)token*MS + j*64 + lane] = f2bf(e[j]*ginv);
}

// ---------------------------------------------------------------------------
// K9: FUSED output GEMM (BK=64, swizzled): out = ctx@Wot^T + bo + Wm'@mvT^T.
// Two K-loops into the same accumulators; out written once. 512 blocks, XCD
// swizzled.
// ---------------------------------------------------------------------------
__global__ __launch_bounds__(256) void gemm_fused_out_kernel(
    const unsigned short* __restrict__ A,   // ctxb [NTOK][HDIM]
    const unsigned short* __restrict__ Bt,  // Wot  [HDIM][HDIM]
    const unsigned short* __restrict__ Wm,  // [NTOK][MS] gate-scaled bf16
    const unsigned short* __restrict__ mvT, // [HDIM][MS]
    const float* __restrict__ bias, float* __restrict__ out) {
  __shared__ __align__(16) unsigned short As[128*64];
  __shared__ __align__(16) unsigned short Bs[128*64];
  const int tid = threadIdx.x;
  const int lane = tid & 63, wave = tid >> 6;
  const int wr = wave >> 1, wc = wave & 1;
  const int wg = blockIdx.x;                  // 0..511
  const int swz = (wg & 7)*64 + (wg >> 3);    // bijective XCD swizzle
  const int bx = swz & 7, by = swz >> 3;
  const int row0 = by << 7, col0 = bx << 7;

  f32x4 acc[4][4];
#pragma unroll
  for (int m = 0; m < 4; ++m)
#pragma unroll
    for (int n = 0; n < 4; ++n) acc[m][n] = (f32x4)(0.f);

  const int srow = tid >> 3;
  const int gchk = (tid & 7) ^ (srow & 7);
  const int fr = lane & 15;
  const int fg = lane >> 4;
  const int ca = ((0*4 + fg) ^ (fr & 7)) * 8;
  const int cb = ((1*4 + fg) ^ (fr & 7)) * 8;

  // ---- loop 1: ctx @ Wot^T (K = HDIM) ----
  {
    const unsigned short* gA = A  + (size_t)(row0 + srow)*HDIM;
    const unsigned short* gB = Bt + (size_t)(col0 + srow)*HDIM;
    for (int k0 = 0; k0 < HDIM; k0 += 64) {
      STAGE64(gA, k0, HDIM, As);
      STAGE64(gB, k0, HDIM, Bs);
      __syncthreads();
#pragma unroll
      for (int kh = 0; kh < 2; ++kh) {
        const int cc = kh ? cb : ca;
        short8 af[4], bf[4];
#pragma unroll
        for (int m = 0; m < 4; ++m)
          af[m] = *(const short8*)&As[(wr*64 + m*16 + fr)*64 + cc];
#pragma unroll
        for (int n = 0; n < 4; ++n)
          bf[n] = *(const short8*)&Bs[(wc*64 + n*16 + fr)*64 + cc];
#pragma unroll
        for (int m = 0; m < 4; ++m)
#pragma unroll
          for (int n = 0; n < 4; ++n)
            acc[m][n] = __builtin_amdgcn_mfma_f32_16x16x32_bf16(af[m], bf[n], acc[m][n], 0, 0, 0);
      }
      __syncthreads();
    }
  }
  // ---- loop 2: Wm' @ mvT^T (K = MS), same accumulators ----
  {
    const unsigned short* gA = Wm  + (size_t)(row0 + srow)*MS;
    const unsigned short* gB = mvT + (size_t)(col0 + srow)*MS;
    for (int k0 = 0; k0 < MS; k0 += 64) {
      STAGE64(gA, k0, MS, As);
      STAGE64(gB, k0, MS, Bs);
      __syncthreads();
#pragma unroll
      for (int kh = 0; kh < 2; ++kh) {
        const int cc = kh ? cb : ca;
        short8 af[4], bf[4];
#pragma unroll
        for (int m = 0; m < 4; ++m)
          af[m] = *(const short8*)&As[(wr*64 + m*16 + fr)*64 + cc];
#pragma unroll
        for (int n = 0; n < 4; ++n)
          bf[n] = *(const short8*)&Bs[(wc*64 + n*16 + fr)*64 + cc];
#pragma unroll
        for (int m = 0; m < 4; ++m)
#pragma unroll
          for (int n = 0; n < 4; ++n)
            acc[m][n] = __builtin_amdgcn_mfma_f32_16x16x32_bf16(af[m], bf[n], acc[m][n], 0, 0, 0);
      }
      __syncthreads();
    }
  }

#pragma unroll
  for (int m = 0; m < 4; ++m) {
#pragma unroll
    for (int n = 0; n < 4; ++n) {
      const int col = col0 + wc*64 + n*16 + fr;
      const float bb = bias[col];
#pragma unroll
      for (int r = 0; r < 4; ++r) {
        const int row = row0 + wr*64 + m*16 + fg*4 + r;
        out[(size_t)row*HDIM + col] = acc[m][n][r] + bb;
      }
    }
  }
}

// ---------------------------------------------------------------------------
extern "C" void kernel_launch(void* const* d_in, const int* in_sizes, int n_in,
                              void* d_out, int out_size, void* d_ws, size_t ws_size,
                              hipStream_t stream) {
  const float* hs = (const float*)d_in[0];
  const float* Wq = (const float*)d_in[1];
  const float* bq = (const float*)d_in[2];
  const float* Wk = (const float*)d_in[3];
  const float* bk = (const float*)d_in[4];
  const float* Wv = (const float*)d_in[5];
  const float* bv = (const float*)d_in[6];
  const float* Wo = (const float*)d_in[7];
  const float* bo = (const float*)d_in[8];
  const float* mk = (const float*)d_in[9];
  const float* mv = (const float*)d_in[10];
  const float* gw = (const float*)d_in[11];
  const float* gb = (const float*)d_in[12];
  float* out = (float*)d_out;

  // Workspace (peak ~64 MB). Aliases (producer strictly after last consumer
  // on the single stream):  ctxb = hsb (hsb last read by gemm_qmsc);
  //                         Wm   = qb  (qb last read by attn).
  char* ws = (char*)d_ws;
  unsigned short* hsb  = (unsigned short*)(ws);                       // 16 MiB bf16 [NTOK,HDIM]
  unsigned short* ctxb = hsb;                                         // alias
  unsigned short* qb   = (unsigned short*)(ws + ((size_t)16 << 20));  // 16 MiB bf16
  unsigned short* Wm   = qb;                                          // alias, 8 MiB [NTOK,MS]
  float*          msc  = (float*)(ws + ((size_t)32 << 20));           // 16 MiB fp32 [NTOK,MS]
  unsigned short* Wkvt = (unsigned short*)(ws + ((size_t)48 << 20));  // 4 MiB [2048][1024]
  unsigned short* Wcat = (unsigned short*)(ws + ((size_t)52 << 20));  // 3 MiB [1536][1024]
  unsigned short* Wot  = (unsigned short*)(ws + ((size_t)55 << 20));  // 2 MiB
  unsigned short* mvT  = (unsigned short*)(ws + ((size_t)57 << 20));  // 1 MiB [HDIM][MS]
  float*          kbuf = (float*)(ws + ((size_t)58 << 20));           // 512 KiB
  float*          vbuf = (float*)(ws + ((size_t)58 << 20) + ((size_t)512 << 10));
  unsigned short* g    = (unsigned short*)(ws + ((size_t)59 << 20));  // 256 KiB
  float*          part = (float*)(ws + ((size_t)59 << 20) + ((size_t)256 << 10)); // 4 MiB
  float*          imp  = (float*)(ws + ((size_t)64 << 20));           // 32 KiB
  float*          gate = (float*)(ws + ((size_t)64 << 20) + ((size_t)32 << 10));
  int*            cnt  = (int*)  (ws + ((size_t)64 << 20) + ((size_t)64 << 10)); // 32 KiB
  int*            lmi  = (int*)  (ws + ((size_t)64 << 20) + ((size_t)96 << 10)); // 4 KiB

  imp_gate_kernel<<<dim3(NTOK/4), 256, 0, stream>>>(hs, gw, gb, imp, gate, hsb);
  hipMemsetAsync(cnt, 0, NB*NS*sizeof(int), stream);
  lm_count_kernel<<<dim3(NS/256, 4, NB), 256, 0, stream>>>(imp, cnt);
  lm_sel_kernel<<<dim3(NS/256, NB), 256, 0, stream>>>(cnt, lmi);
  prep_kernel<<<dim3(32, 32, 5), 256, 0, stream>>>(
      Wk, Wv, Wq, Wo, mk, mv, Wkvt, Wcat, Wot, mvT);
  // K/V projection of landmark rows via MFMA GEMM (split-K=4)
  lm_gather_kernel<<<dim3(NB*LM), 256, 0, stream>>>(hsb, lmi, g);
  kvproj_gemm_kernel<<<dim3(16, 4), 256, 0, stream>>>(g, Wkvt, part);
  kv_reduce2_kernel<<<dim3(8, 128), 256, 0, stream>>>(part, bk, bv, kbuf, vbuf);
  // fused Q-projection + memory scores (reads hsb for the last time)
  gemm_qmsc_kernel<<<dim3(768), 256, 0, stream>>>(hsb, Wcat, bq, qb, msc);
  // attention (writes ctxb over hsb; reads qb for the last time)
  attn_mfma_kernel<<<dim3(NS/128, NHEAD, NB), 256, 0, stream>>>(qb, kbuf, vbuf, ctxb);
  // memory-bank selection -> gate-scaled dense weight rows (Wm over qb)
  sel_kernel<<<dim3(NTOK/4), 256, 0, stream>>>(msc, gate, Wm);
  // single fused output GEMM: out = ctx@Wot^T + bo + Wm'@mvT^T
  gemm_fused_out_kernel<<<dim3(512), 256, 0, stream>>>(ctxb, Wot, Wm, mvT, bo, out);
}

// Round 13
// 147.071 us; speedup vs baseline: 6.9254x; 1.1125x over previous
//
#include <hip/hip_runtime.h>
#include <math.h>

// Problem constants (from reference setup_inputs)
#define HDIM 1024
#define NHEAD 16
#define HD 64
#define LM 64          // NUM_LANDMARKS
#define MS 512         // memory slots
#define KSEL 32        // top_k
#define NB 2
#define NS 4096
#define NTOK (NB*NS)   // 8192

typedef __attribute__((ext_vector_type(8))) short short8;
typedef __attribute__((ext_vector_type(4))) float f32x4;
typedef __attribute__((ext_vector_type(4))) unsigned short us4;

__device__ __forceinline__ unsigned short f2bf(float f) {
  unsigned int u = __float_as_uint(f);
  unsigned int r = (u + 0x7fffu + ((u >> 16) & 1u)) >> 16;
  return (unsigned short)r;
}
__device__ __forceinline__ float bf2f(unsigned short u) {
  return __uint_as_float(((unsigned int)u) << 16);
}

__device__ __forceinline__ void gload_lds16(const unsigned short* g, unsigned short* l) {
  __builtin_amdgcn_global_load_lds(
      (const __attribute__((address_space(1))) unsigned int*)g,
      (__attribute__((address_space(3))) unsigned int*)l,
      16, 0, 0);
}

// BK=64 tile stager (used by gemm_fused_out): XOR-swizzled source chunks.
#define STAGE64(gbase, k0, LDA, lds)                                          \
  {                                                                           \
    const unsigned short* _s = (gbase) + (k0) + gchk*8;                       \
    gload_lds16(_s,                 (lds) + tid*8);                           \
    gload_lds16(_s + (size_t)32*(LDA), (lds) + 2048 + tid*8);                 \
    gload_lds16(_s + (size_t)64*(LDA), (lds) + 4096 + tid*8);                 \
    gload_lds16(_s + (size_t)96*(LDA), (lds) + 6144 + tid*8);                 \
  }

// ---------------------------------------------------------------------------
// K1: wave-per-row importance (sum sq) + gate + hs -> bf16. Block = 4 rows.
// ---------------------------------------------------------------------------
__global__ __launch_bounds__(256) void imp_gate_kernel(
    const float* __restrict__ hs, const float* __restrict__ gw,
    const float* __restrict__ gb, float* __restrict__ imp,
    float* __restrict__ gate, unsigned short* __restrict__ hsb) {
  const int lane = threadIdx.x & 63, wave = threadIdx.x >> 6;
  const int row = blockIdx.x*4 + wave;
  float ss = 0.f, dg = 0.f;
#pragma unroll
  for (int c = 0; c < 4; ++c) {
    const int d = c*256 + lane*4;
    const float4 hv = *(const float4*)(hs + (size_t)row*HDIM + d);
    const float4 gv = *(const float4*)(gw + d);
    ss += hv.x*hv.x + hv.y*hv.y + hv.z*hv.z + hv.w*hv.w;
    dg += hv.x*gv.x + hv.y*gv.y + hv.z*gv.z + hv.w*gv.w;
    us4 hb;
    hb.x = f2bf(hv.x); hb.y = f2bf(hv.y); hb.z = f2bf(hv.z); hb.w = f2bf(hv.w);
    *(us4*)(hsb + (size_t)row*HDIM + d) = hb;
  }
#pragma unroll
  for (int off = 32; off > 0; off >>= 1) {
    ss += __shfl_xor(ss, off);
    dg += __shfl_xor(dg, off);
  }
  if (lane == 0) {
    imp[row] = ss;
    gate[row] = 1.f/(1.f + expf(-(dg + gb[0])));
  }
}

// ---------------------------------------------------------------------------
// K2a: rank counting (jax tie-break).
// ---------------------------------------------------------------------------
__global__ __launch_bounds__(256) void lm_count_kernel(
    const float* __restrict__ imp, int* __restrict__ cnt) {
  const int b = blockIdx.z;
  const int jc = blockIdx.y;
  const int i = blockIdx.x*256 + threadIdx.x;
  const float* v = imp + b*NS;
  const float mine = v[i];
  __shared__ float tile[1024];
  const int j0 = jc*1024;
  *(float4*)&tile[threadIdx.x*4] = *(const float4*)&v[j0 + threadIdx.x*4];
  __syncthreads();
  int c = 0;
#pragma unroll 8
  for (int p = 0; p < 1024; p += 4) {
    const float4 t = *(const float4*)&tile[p];
    c += (t.x > mine) || (t.x == mine && (j0+p+0) < i);
    c += (t.y > mine) || (t.y == mine && (j0+p+1) < i);
    c += (t.z > mine) || (t.z == mine && (j0+p+2) < i);
    c += (t.w > mine) || (t.w == mine && (j0+p+3) < i);
  }
  atomicAdd(&cnt[b*NS + i], c);
}

// K2b: scatter selected candidates (set only).
__global__ __launch_bounds__(256) void lm_sel_kernel(
    const int* __restrict__ cnt, int* __restrict__ lm_idx) {
  const int b = blockIdx.y;
  const int i = blockIdx.x*256 + threadIdx.x;
  const int c = cnt[b*NS + i];
  if (c < LM) lm_idx[b*LM + c] = i;
}

// ---------------------------------------------------------------------------
// K3a: gather 128 landmark rows (bf16) into compact g[NB*LM][HDIM]
// ---------------------------------------------------------------------------
__global__ __launch_bounds__(256) void lm_gather_kernel(
    const unsigned short* __restrict__ hsb, const int* __restrict__ lmi,
    unsigned short* __restrict__ g) {
  const int j = blockIdx.x;
  const int b = j >> 6;
  const int idx = lmi[j];
  const us4 v = *(const us4*)(hsb + ((size_t)(b*NS + idx))*HDIM + threadIdx.x*4);
  *(us4*)(g + (size_t)j*HDIM + threadIdx.x*4) = v;
}

// ---------------------------------------------------------------------------
// K3b: K/V projection as bf16 MFMA GEMM, split-K=4.
// ---------------------------------------------------------------------------
__global__ __launch_bounds__(256) void kvproj_gemm_kernel(
    const unsigned short* __restrict__ g, const unsigned short* __restrict__ Wkvt,
    float* __restrict__ part) {
  __shared__ __align__(16) unsigned short As[128*32];
  __shared__ __align__(16) unsigned short Bs[128*32];
  const int tid = threadIdx.x;
  const int lane = tid & 63, wave = tid >> 6;
  const int wr = wave >> 1, wc = wave & 1;
  const int col0 = blockIdx.x << 7;
  const int sp = blockIdx.y;
  const int k00 = sp << 8;

  f32x4 acc[4][4];
#pragma unroll
  for (int m = 0; m < 4; ++m)
#pragma unroll
    for (int n = 0; n < 4; ++n) acc[m][n] = (f32x4)(0.f);

  const int srow = tid >> 2;
  const int sk   = (tid & 3) << 3;
  const unsigned short* gA = g    + (size_t)srow*HDIM + sk;
  const unsigned short* gB = Wkvt + (size_t)(col0 + srow)*HDIM + sk;
  const int fr = lane & 15;
  const int fk = (lane >> 4) << 3;
  const int fg = lane >> 4;

  for (int k0 = k00; k0 < k00 + 256; k0 += 32) {
    gload_lds16(gA + k0,             As + tid*8);
    gload_lds16(gA + 64*HDIM + k0,   As + 2048 + tid*8);
    gload_lds16(gB + k0,             Bs + tid*8);
    gload_lds16(gB + 64*HDIM + k0,   Bs + 2048 + tid*8);
    __syncthreads();
    short8 af[4], bf[4];
#pragma unroll
    for (int m = 0; m < 4; ++m)
      af[m] = *(const short8*)&As[(wr*64 + m*16 + fr)*32 + fk];
#pragma unroll
    for (int n = 0; n < 4; ++n)
      bf[n] = *(const short8*)&Bs[(wc*64 + n*16 + fr)*32 + fk];
#pragma unroll
    for (int m = 0; m < 4; ++m)
#pragma unroll
      for (int n = 0; n < 4; ++n)
        acc[m][n] = __builtin_amdgcn_mfma_f32_16x16x32_bf16(af[m], bf[n], acc[m][n], 0, 0, 0);
    __syncthreads();
  }
#pragma unroll
  for (int m = 0; m < 4; ++m)
#pragma unroll
    for (int n = 0; n < 4; ++n) {
      const int colg = col0 + wc*64 + n*16 + fr;
#pragma unroll
      for (int r = 0; r < 4; ++r) {
        const int row = wr*64 + m*16 + fg*4 + r;
        part[((size_t)(sp*128 + row))*2048 + colg] = acc[m][n][r];
      }
    }
}

// K3c: reduce 4 K-split partials + bias -> bf16 K (row-major) and V^T.
// kbb [NB*64][1024] bf16;  vbbT [NB][1024 dims][64 lm] bf16.
__global__ __launch_bounds__(256) void kv_reduce2_kernel(
    const float* __restrict__ part, const float* __restrict__ bk,
    const float* __restrict__ bv, unsigned short* __restrict__ kbb,
    unsigned short* __restrict__ vbbT) {
  const int row = blockIdx.y;                     // 0..127 = b*64 + l
  const int col = blockIdx.x*256 + threadIdx.x;   // 0..2047
  float s = 0.f;
#pragma unroll
  for (int sp = 0; sp < 4; ++sp)
    s += part[((size_t)(sp*128 + row))*2048 + col];
  if (col < HDIM) {
    kbb[(size_t)row*HDIM + col] = f2bf(s + bk[col]);
  } else {
    const int d = col - HDIM;
    const int b = row >> 6, l = row & 63;
    vbbT[(size_t)b*65536 + (size_t)d*64 + l] = f2bf(s + bv[d]);
  }
}

// ---------------------------------------------------------------------------
// Prep (fused): z<4 -> transpose+convert W; z==4 -> blk<512: conv mk into
// Wcat tail; blk>=512: transpose+convert mem_values -> mvT[1024][512] bf16.
// ---------------------------------------------------------------------------
__global__ __launch_bounds__(256) void prep_kernel(
    const float* __restrict__ Wk, const float* __restrict__ Wv,
    const float* __restrict__ Wq, const float* __restrict__ Wo,
    const float* __restrict__ mk, const float* __restrict__ mv,
    unsigned short* __restrict__ Wkvt, unsigned short* __restrict__ Wcat,
    unsigned short* __restrict__ Wot, unsigned short* __restrict__ mvT) {
  const int z = blockIdx.z;
  __shared__ float tile[32][33];
  const int tx = threadIdx.x & 31, ty = threadIdx.x >> 5;
  if (z < 4) {
    const float* W = (z == 0) ? Wk : (z == 1) ? Wv : (z == 2) ? Wq : Wo;
    unsigned short* Wt = (z == 0) ? Wkvt
                       : (z == 1) ? (Wkvt + (size_t)HDIM*HDIM)
                       : (z == 2) ? Wcat : Wot;
    const int bx = blockIdx.x * 32, by = blockIdx.y * 32;
#pragma unroll
    for (int i = 0; i < 32; i += 8)
      tile[ty + i][tx] = W[(size_t)(by + ty + i)*HDIM + bx + tx];
    __syncthreads();
#pragma unroll
    for (int i = 0; i < 32; i += 8)
      Wt[(size_t)(bx + ty + i)*HDIM + by + tx] = f2bf(tile[tx][ty + i]);
  } else {
    const int blk = blockIdx.y*32 + blockIdx.x;
    if (blk < 512) {
      const int off = (blk << 10) + threadIdx.x*4;
      const float4 v = *(const float4*)&mk[off];
      us4 w;
      w.x = f2bf(v.x); w.y = f2bf(v.y); w.z = f2bf(v.z); w.w = f2bf(v.w);
      *(us4*)&(Wcat + (size_t)HDIM*HDIM)[off] = w;
    } else {
      const int t = blk - 512;
      const int by = (t >> 5) * 32;
      const int bx = (t & 31) * 32;
#pragma unroll
      for (int i = 0; i < 32; i += 8)
        tile[ty + i][tx] = mv[(size_t)(by + ty + i)*HDIM + bx + tx];
      __syncthreads();
#pragma unroll
      for (int i = 0; i < 32; i += 8)
        mvT[(size_t)(bx + ty + i)*MS + by + tx] = f2bf(tile[tx][ty + i]);
    }
  }
}

// ---------------------------------------------------------------------------
// K4: FUSED GEMM + ATTENTION.  [q | msc] = hsb @ Wcat^T (BK=32, 128x128).
// bx<8: the 128x128 q-tile (2 heads) stays in registers; each wave runs
//       landmark attention for its 64 tokens x 1 head in two 32-row passes,
//       using a 4KB per-wave LDS buffer (reusing dead As/Bs) for the q/P
//       fragment transposes; ctx written straight to global.
// bx>=8: msc epilogue (fp32 * 1/32).
// K/V (bf16, from kbb/vbbT) staged via global_load_lds at kernel start;
// the k-loop barriers drain them for free. LDS = 48 KiB -> 3 blocks/CU.
// ---------------------------------------------------------------------------
__global__ __launch_bounds__(256, 3) void gemm_qattn_kernel(
    const unsigned short* __restrict__ A,    // hsb
    const unsigned short* __restrict__ Bt,   // Wcat [1536][1024]
    const float* __restrict__ bq,
    const unsigned short* __restrict__ kbb,  // [NB*64][1024]
    const unsigned short* __restrict__ vbbT, // [NB][1024][64]
    unsigned short* __restrict__ ctxb, float* __restrict__ msc) {
  __shared__ __align__(16) unsigned short As[128*32];   // 8 KiB (later wavebuf 0,1)
  __shared__ __align__(16) unsigned short Bs[128*32];   // 8 KiB (later wavebuf 2,3)
  __shared__ __align__(16) unsigned short Ks[2*64*64];  // 16 KiB [h][lm][d]
  __shared__ __align__(16) unsigned short Vt[2*64*64];  // 16 KiB [h][d][lm]
  const int tid = threadIdx.x;
  const int lane = tid & 63, wave = tid >> 6;
  const int wr = wave >> 1, wc = wave & 1;
  const int wg = blockIdx.x;                    // 0..767
  const int swz = (wg & 7)*96 + (wg >> 3);      // bijective XCD swizzle
  const int bx = swz % 12, by = swz / 12;
  const int row0 = by << 7, col0 = bx << 7;
  const int fr = lane & 15;
  const int fk = (lane >> 4) << 3;
  const int fg = lane >> 4;

  // issue K/V staging early (q-blocks only); k-loop barriers drain it
  if (bx < 8) {
    const int b = by >> 5;
#pragma unroll
    for (int it = 0; it < 4; ++it) {
      const int c = it*256 + tid;               // 0..1023
      const int hh = c >> 9, l = (c >> 3) & 63, ch = c & 7;
      gload_lds16(kbb + (size_t)(b*64 + l)*HDIM + (bx*2 + hh)*64 + ch*8,
                  Ks + c*8);
    }
#pragma unroll
    for (int it = 0; it < 4; ++it) {
      const int c = it*256 + tid;
      const int hh = c >> 9, dr = (c >> 3) & 63, ch = c & 7;
      gload_lds16(vbbT + (size_t)(by >> 5)*65536 + (size_t)((bx*2 + hh)*64 + dr)*64 + ch*8,
                  Vt + c*8);
    }
  }

  f32x4 acc[4][4];
#pragma unroll
  for (int m = 0; m < 4; ++m)
#pragma unroll
    for (int n = 0; n < 4; ++n) acc[m][n] = (f32x4)(0.f);

  const int srow = tid >> 2;
  const int sk   = (tid & 3) << 3;
  const unsigned short* gA = A  + (size_t)(row0 + srow)*HDIM + sk;
  const unsigned short* gB = Bt + (size_t)(col0 + srow)*HDIM + sk;

  for (int k0 = 0; k0 < HDIM; k0 += 32) {
    gload_lds16(gA + k0,             As + tid*8);
    gload_lds16(gA + 64*HDIM + k0,   As + 2048 + tid*8);
    gload_lds16(gB + k0,             Bs + tid*8);
    gload_lds16(gB + 64*HDIM + k0,   Bs + 2048 + tid*8);
    __syncthreads();
    short8 af[4], bf[4];
#pragma unroll
    for (int m = 0; m < 4; ++m)
      af[m] = *(const short8*)&As[(wr*64 + m*16 + fr)*32 + fk];
#pragma unroll
    for (int n = 0; n < 4; ++n)
      bf[n] = *(const short8*)&Bs[(wc*64 + n*16 + fr)*32 + fk];
#pragma unroll
    for (int m = 0; m < 4; ++m)
#pragma unroll
      for (int n = 0; n < 4; ++n)
        acc[m][n] = __builtin_amdgcn_mfma_f32_16x16x32_bf16(af[m], bf[n], acc[m][n], 0, 0, 0);
    __syncthreads();
  }

  if (bx >= 8) {
    // msc epilogue
#pragma unroll
    for (int m = 0; m < 4; ++m)
#pragma unroll
      for (int n = 0; n < 4; ++n) {
        const int c2 = col0 + wc*64 + n*16 + fr - HDIM;
#pragma unroll
        for (int r = 0; r < 4; ++r) {
          const int row = row0 + wr*64 + m*16 + fg*4 + r;
          msc[(size_t)row*MS + c2] = acc[m][n][r]*0.03125f;
        }
      }
    return;
  }

  // ---- per-wave landmark attention (64 tokens x 1 head, 2 passes of 32) ----
  float bqv[4];
#pragma unroll
  for (int n = 0; n < 4; ++n) bqv[n] = bq[col0 + wc*64 + n*16 + fr];

  unsigned short* wb = (wave < 2) ? (As + wave*2048) : (Bs + (wave - 2)*2048);
  const int hb = wc*4096;   // head base into Ks/Vt

#pragma unroll
  for (int pass = 0; pass < 2; ++pass) {
    // q (+bias) -> bf16 -> wavebuf [32][64]
#pragma unroll
    for (int m2 = 0; m2 < 2; ++m2)
#pragma unroll
      for (int n = 0; n < 4; ++n)
#pragma unroll
        for (int r = 0; r < 4; ++r)
          wb[(m2*16 + fg*4 + r)*64 + n*16 + fr] =
              f2bf(acc[pass*2 + m2][n][r] + bqv[n]);
    __builtin_amdgcn_wave_barrier();

    // QK^T: scores [32 tok][64 lm]
    f32x4 sc_[2][4];
#pragma unroll
    for (int m2 = 0; m2 < 2; ++m2)
#pragma unroll
      for (int n = 0; n < 4; ++n) sc_[m2][n] = (f32x4)(0.f);
#pragma unroll
    for (int ks = 0; ks < 2; ++ks) {
      short8 af[2], bf[4];
#pragma unroll
      for (int m2 = 0; m2 < 2; ++m2)
        af[m2] = *(const short8*)&wb[(m2*16 + fr)*64 + ks*32 + fk];
#pragma unroll
      for (int n = 0; n < 4; ++n)
        bf[n] = *(const short8*)&Ks[hb + (n*16 + fr)*64 + ks*32 + fk];
#pragma unroll
      for (int m2 = 0; m2 < 2; ++m2)
#pragma unroll
        for (int n = 0; n < 4; ++n)
          sc_[m2][n] = __builtin_amdgcn_mfma_f32_16x16x32_bf16(af[m2], bf[n], sc_[m2][n], 0, 0, 0);
    }

    // in-register row softmax; P -> wavebuf
#pragma unroll
    for (int m2 = 0; m2 < 2; ++m2) {
#pragma unroll
      for (int r = 0; r < 4; ++r) {
        float p0 = sc_[m2][0][r]*0.125f, p1 = sc_[m2][1][r]*0.125f;
        float p2 = sc_[m2][2][r]*0.125f, p3 = sc_[m2][3][r]*0.125f;
        float mx = fmaxf(fmaxf(p0, p1), fmaxf(p2, p3));
#pragma unroll
        for (int off = 1; off < 16; off <<= 1) mx = fmaxf(mx, __shfl_xor(mx, off));
        p0 = expf(p0 - mx); p1 = expf(p1 - mx); p2 = expf(p2 - mx); p3 = expf(p3 - mx);
        float sm = p0 + p1 + p2 + p3;
#pragma unroll
        for (int off = 1; off < 16; off <<= 1) sm += __shfl_xor(sm, off);
        const float inv = 1.f/sm;
        const int prow = (m2*16 + fg*4 + r)*64;
        wb[prow + 0*16 + fr] = f2bf(p0*inv);
        wb[prow + 1*16 + fr] = f2bf(p1*inv);
        wb[prow + 2*16 + fr] = f2bf(p2*inv);
        wb[prow + 3*16 + fr] = f2bf(p3*inv);
      }
    }
    __builtin_amdgcn_wave_barrier();

    // PV: ctx [32 tok][64 dims]
    f32x4 oc_[2][4];
#pragma unroll
    for (int m2 = 0; m2 < 2; ++m2)
#pragma unroll
      for (int n = 0; n < 4; ++n) oc_[m2][n] = (f32x4)(0.f);
#pragma unroll
    for (int ks = 0; ks < 2; ++ks) {
      short8 af[2], bf[4];
#pragma unroll
      for (int m2 = 0; m2 < 2; ++m2)
        af[m2] = *(const short8*)&wb[(m2*16 + fr)*64 + ks*32 + fk];
#pragma unroll
      for (int n = 0; n < 4; ++n)
        bf[n] = *(const short8*)&Vt[hb + (n*16 + fr)*64 + ks*32 + fk];
#pragma unroll
      for (int m2 = 0; m2 < 2; ++m2)
#pragma unroll
        for (int n = 0; n < 4; ++n)
          oc_[m2][n] = __builtin_amdgcn_mfma_f32_16x16x32_bf16(af[m2], bf[n], oc_[m2][n], 0, 0, 0);
    }
#pragma unroll
    for (int m2 = 0; m2 < 2; ++m2)
#pragma unroll
      for (int n = 0; n < 4; ++n)
#pragma unroll
        for (int r = 0; r < 4; ++r) {
          const int tok = row0 + wr*64 + pass*32 + m2*16 + fg*4 + r;
          ctxb[(size_t)tok*HDIM + col0 + wc*64 + n*16 + fr] = f2bf(oc_[m2][n][r]);
        }
    __builtin_amdgcn_wave_barrier();
  }
}

// ---------------------------------------------------------------------------
// K8a: wave-per-token top-32 THRESHOLD selection -> gate-scaled dense
// weight row Wm[token][m] (bf16). Zero block barriers.
// ---------------------------------------------------------------------------
__global__ __launch_bounds__(256) void sel_kernel(
    const float* __restrict__ msc, const float* __restrict__ gate,
    unsigned short* __restrict__ Wm) {
  const int tid = threadIdx.x;
  const int lane = tid & 63, wave = tid >> 6;
  const int token = blockIdx.x*4 + wave;

  __shared__ __align__(16) int s_hist[4][256];
  __shared__ unsigned long long s_list[4][256];
  __shared__ int s_B[4], s_above[4], s_nlist[4];

  *(int4*)&s_hist[wave][lane*4] = make_int4(0, 0, 0, 0);
  if (lane == 0) s_nlist[wave] = 0;

  float v[8];
#pragma unroll
  for (int j = 0; j < 8; ++j) v[j] = msc[(size_t)token*MS + j*64 + lane];

  float mx = v[0], mn = v[0];
#pragma unroll
  for (int j = 1; j < 8; ++j) { mx = fmaxf(mx, v[j]); mn = fminf(mn, v[j]); }
#pragma unroll
  for (int off = 32; off > 0; off >>= 1) {
    mx = fmaxf(mx, __shfl_xor(mx, off));
    mn = fminf(mn, __shfl_xor(mn, off));
  }
  const float range = mx - mn;
  const float scale = (range > 1e-20f) ? 255.f/range : 0.f;

  __builtin_amdgcn_wave_barrier();
  int bins[8];
#pragma unroll
  for (int j = 0; j < 8; ++j) {
    int b = (int)((v[j] - mn)*scale);
    bins[j] = b > 255 ? 255 : b;
    atomicAdd(&s_hist[wave][bins[j]], 1);
  }
  __builtin_amdgcn_wave_barrier();

  const int4 c = *(const int4*)&s_hist[wave][lane*4];
  const int lane_total = c.x + c.y + c.z + c.w;
  int sfx = lane_total;
#pragma unroll
  for (int off = 1; off < 64; off <<= 1) {
    const int src = lane + off;
    int y = __shfl(sfx, src < 64 ? src : lane);
    sfx += (src < 64) ? y : 0;
  }
  const int beyond = sfx - lane_total;
  const int s3 = c.w + beyond;
  const int s2 = c.z + s3;
  const int s1 = c.y + s2;
  const int s0 = c.x + s1;
  int Bl = -1, abv = 0;
  if (s0 >= KSEL && s1 < KSEL) { Bl = lane*4 + 0; abv = s1; }
  if (s1 >= KSEL && s2 < KSEL) { Bl = lane*4 + 1; abv = s2; }
  if (s2 >= KSEL && s3 < KSEL) { Bl = lane*4 + 2; abv = s3; }
  if (s3 >= KSEL && beyond < KSEL) { Bl = lane*4 + 3; abv = beyond; }
  if (Bl >= 0) { s_B[wave] = Bl; s_above[wave] = abv; }
  __builtin_amdgcn_wave_barrier();
  const int B = s_B[wave];
  const int rem = KSEL - s_above[wave];

#pragma unroll
  for (int j = 0; j < 8; ++j) {
    if (bins[j] == B) {
      const unsigned int u = __float_as_uint(v[j]);
      const unsigned int vk = (u & 0x80000000u) ? ~u : (u | 0x80000000u);
      const int p = atomicAdd(&s_nlist[wave], 1);
      if (p < 256)
        s_list[wave][p] = ((unsigned long long)vk << 32) | (unsigned int)~(j*64 + lane);
    }
  }
  __builtin_amdgcn_wave_barrier();

  const int nl = s_nlist[wave] < 256 ? s_nlist[wave] : 256;
  unsigned long long T = ~0ull;
  for (int r = 0; r < rem; ++r) {
    unsigned long long best = 0; int pos = -1;
    for (int i = lane; i < nl; i += 64)
      if (s_list[wave][i] > best) { best = s_list[wave][i]; pos = i; }
#pragma unroll
    for (int off = 32; off > 0; off >>= 1) {
      const unsigned long long ob = __shfl_xor(best, off);
      const int op = __shfl_xor(pos, off);
      if (ob > best) { best = ob; pos = op; }
    }
    if (lane == 0) s_list[wave][pos] = 0;
    T = best;
    __builtin_amdgcn_wave_barrier();
  }

  float e[8];
  float esum = 0.f;
#pragma unroll
  for (int j = 0; j < 8; ++j) {
    bool sel = bins[j] > B;
    if (!sel && bins[j] == B) {
      const unsigned int u = __float_as_uint(v[j]);
      const unsigned int vk = (u & 0x80000000u) ? ~u : (u | 0x80000000u);
      const unsigned long long key =
          ((unsigned long long)vk << 32) | (unsigned int)~(j*64 + lane);
      sel = key >= T;
    }
    e[j] = sel ? expf(v[j] - mx) : 0.f;
    esum += e[j];
  }
#pragma unroll
  for (int off = 32; off > 0; off >>= 1) esum += __shfl_xor(esum, off);
  const float ginv = gate[token]/esum;
#pragma unroll
  for (int j = 0; j < 8; ++j)
    Wm[(size_t)token*MS + j*64 + lane] = f2bf(e[j]*ginv);
}

// ---------------------------------------------------------------------------
// K9: FUSED output GEMM (BK=64, swizzled): out = ctx@Wot^T + bo + Wm'@mvT^T.
// ---------------------------------------------------------------------------
__global__ __launch_bounds__(256) void gemm_fused_out_kernel(
    const unsigned short* __restrict__ A,   // ctxb [NTOK][HDIM]
    const unsigned short* __restrict__ Bt,  // Wot  [HDIM][HDIM]
    const unsigned short* __restrict__ Wm,  // [NTOK][MS] gate-scaled bf16
    const unsigned short* __restrict__ mvT, // [HDIM][MS]
    const float* __restrict__ bias, float* __restrict__ out) {
  __shared__ __align__(16) unsigned short As[128*64];
  __shared__ __align__(16) unsigned short Bs[128*64];
  const int tid = threadIdx.x;
  const int lane = tid & 63, wave = tid >> 6;
  const int wr = wave >> 1, wc = wave & 1;
  const int wg = blockIdx.x;
  const int swz = (wg & 7)*64 + (wg >> 3);
  const int bx = swz & 7, by = swz >> 3;
  const int row0 = by << 7, col0 = bx << 7;

  f32x4 acc[4][4];
#pragma unroll
  for (int m = 0; m < 4; ++m)
#pragma unroll
    for (int n = 0; n < 4; ++n) acc[m][n] = (f32x4)(0.f);

  const int srow = tid >> 3;
  const int gchk = (tid & 7) ^ (srow & 7);
  const int fr = lane & 15;
  const int fg = lane >> 4;
  const int ca = ((0*4 + fg) ^ (fr & 7)) * 8;
  const int cb = ((1*4 + fg) ^ (fr & 7)) * 8;

  {
    const unsigned short* gA = A  + (size_t)(row0 + srow)*HDIM;
    const unsigned short* gB = Bt + (size_t)(col0 + srow)*HDIM;
    for (int k0 = 0; k0 < HDIM; k0 += 64) {
      STAGE64(gA, k0, HDIM, As);
      STAGE64(gB, k0, HDIM, Bs);
      __syncthreads();
#pragma unroll
      for (int kh = 0; kh < 2; ++kh) {
        const int cc = kh ? cb : ca;
        short8 af[4], bf[4];
#pragma unroll
        for (int m = 0; m < 4; ++m)
          af[m] = *(const short8*)&As[(wr*64 + m*16 + fr)*64 + cc];
#pragma unroll
        for (int n = 0; n < 4; ++n)
          bf[n] = *(const short8*)&Bs[(wc*64 + n*16 + fr)*64 + cc];
#pragma unroll
        for (int m = 0; m < 4; ++m)
#pragma unroll
          for (int n = 0; n < 4; ++n)
            acc[m][n] = __builtin_amdgcn_mfma_f32_16x16x32_bf16(af[m], bf[n], acc[m][n], 0, 0, 0);
      }
      __syncthreads();
    }
  }
  {
    const unsigned short* gA = Wm  + (size_t)(row0 + srow)*MS;
    const unsigned short* gB = mvT + (size_t)(col0 + srow)*MS;
    for (int k0 = 0; k0 < MS; k0 += 64) {
      STAGE64(gA, k0, MS, As);
      STAGE64(gB, k0, MS, Bs);
      __syncthreads();
#pragma unroll
      for (int kh = 0; kh < 2; ++kh) {
        const int cc = kh ? cb : ca;
        short8 af[4], bf[4];
#pragma unroll
        for (int m = 0; m < 4; ++m)
          af[m] = *(const short8*)&As[(wr*64 + m*16 + fr)*64 + cc];
#pragma unroll
        for (int n = 0; n < 4; ++n)
          bf[n] = *(const short8*)&Bs[(wc*64 + n*16 + fr)*64 + cc];
#pragma unroll
        for (int m = 0; m < 4; ++m)
#pragma unroll
          for (int n = 0; n < 4; ++n)
            acc[m][n] = __builtin_amdgcn_mfma_f32_16x16x32_bf16(af[m], bf[n], acc[m][n], 0, 0, 0);
      }
      __syncthreads();
    }
  }

#pragma unroll
  for (int m = 0; m < 4; ++m) {
#pragma unroll
    for (int n = 0; n < 4; ++n) {
      const int col = col0 + wc*64 + n*16 + fr;
      const float bb = bias[col];
#pragma unroll
      for (int r = 0; r < 4; ++r) {
        const int row = row0 + wr*64 + m*16 + fg*4 + r;
        out[(size_t)row*HDIM + col] = acc[m][n][r] + bb;
      }
    }
  }
}

// ---------------------------------------------------------------------------
extern "C" void kernel_launch(void* const* d_in, const int* in_sizes, int n_in,
                              void* d_out, int out_size, void* d_ws, size_t ws_size,
                              hipStream_t stream) {
  const float* hs = (const float*)d_in[0];
  const float* Wq = (const float*)d_in[1];
  const float* bq = (const float*)d_in[2];
  const float* Wk = (const float*)d_in[3];
  const float* bk = (const float*)d_in[4];
  const float* Wv = (const float*)d_in[5];
  const float* bv = (const float*)d_in[6];
  const float* Wo = (const float*)d_in[7];
  const float* bo = (const float*)d_in[8];
  const float* mk = (const float*)d_in[9];
  const float* mv = (const float*)d_in[10];
  const float* gw = (const float*)d_in[11];
  const float* gb = (const float*)d_in[12];
  float* out = (float*)d_out;

  // Workspace (peak ~71.2 MB). No aliases: qb eliminated by the fusion.
  char* ws = (char*)d_ws;
  unsigned short* hsb  = (unsigned short*)(ws);                       // 16 MiB
  unsigned short* ctxb = (unsigned short*)(ws + ((size_t)16 << 20));  // 16 MiB
  float*          msc  = (float*)(ws + ((size_t)32 << 20));           // 16 MiB
  unsigned short* Wm   = (unsigned short*)(ws + ((size_t)48 << 20));  // 8 MiB
  unsigned short* Wkvt = (unsigned short*)(ws + ((size_t)56 << 20));  // 4 MiB
  unsigned short* Wcat = (unsigned short*)(ws + ((size_t)60 << 20));  // 3 MiB
  unsigned short* Wot  = (unsigned short*)(ws + ((size_t)63 << 20));  // 2 MiB
  unsigned short* mvT  = (unsigned short*)(ws + ((size_t)65 << 20));  // 1 MiB
  unsigned short* kbb  = (unsigned short*)(ws + ((size_t)66 << 20));  // 256 KiB
  unsigned short* vbbT = (unsigned short*)(ws + ((size_t)66 << 20) + ((size_t)256 << 10)); // 256 KiB
  unsigned short* g    = (unsigned short*)(ws + ((size_t)66 << 20) + ((size_t)512 << 10)); // 256 KiB
  float*          part = (float*)(ws + ((size_t)67 << 20));           // 4 MiB
  float*          imp  = (float*)(ws + ((size_t)71 << 20));           // 32 KiB
  float*          gate = (float*)(ws + ((size_t)71 << 20) + ((size_t)32 << 10));
  int*            cnt  = (int*)  (ws + ((size_t)71 << 20) + ((size_t)64 << 10)); // 32 KiB
  int*            lmi  = (int*)  (ws + ((size_t)71 << 20) + ((size_t)96 << 10)); // 4 KiB

  imp_gate_kernel<<<dim3(NTOK/4), 256, 0, stream>>>(hs, gw, gb, imp, gate, hsb);
  hipMemsetAsync(cnt, 0, NB*NS*sizeof(int), stream);
  lm_count_kernel<<<dim3(NS/256, 4, NB), 256, 0, stream>>>(imp, cnt);
  lm_sel_kernel<<<dim3(NS/256, NB), 256, 0, stream>>>(cnt, lmi);
  prep_kernel<<<dim3(32, 32, 5), 256, 0, stream>>>(
      Wk, Wv, Wq, Wo, mk, mv, Wkvt, Wcat, Wot, mvT);
  // K/V projection of landmark rows via MFMA GEMM (split-K=4)
  lm_gather_kernel<<<dim3(NB*LM), 256, 0, stream>>>(hsb, lmi, g);
  kvproj_gemm_kernel<<<dim3(16, 4), 256, 0, stream>>>(g, Wkvt, part);
  kv_reduce2_kernel<<<dim3(8, 128), 256, 0, stream>>>(part, bk, bv, kbb, vbbT);
  // fused Q-projection + landmark attention + memory scores
  gemm_qattn_kernel<<<dim3(768), 256, 0, stream>>>(hsb, Wcat, bq, kbb, vbbT, ctxb, msc);
  // memory-bank selection -> gate-scaled dense weight rows
  sel_kernel<<<dim3(NTOK/4), 256, 0, stream>>>(msc, gate, Wm);
  // single fused output GEMM: out = ctx@Wot^T + bo + Wm'@mvT^T
  gemm_fused_out_kernel<<<dim3(512), 256, 0, stream>>>(ctxb, Wot, Wm, mvT, bo, out);
}